// Round 1
// 1018.218 us; speedup vs baseline: 1.2883x; 1.2883x over previous
//
#include <hip/hip_runtime.h>
#include <hip/hip_bf16.h>
#include <type_traits>

// HGConv layer: micro (per-relation GAT) + macro (semantic attention) + gated residual.
// I/O: float32 (verified round 6). Internals: bf16 matrices, f32 accumulation.
// Round 8: edge stage scatter->gather via on-device CSR.
// Round 9: scan_off was 3x96us on ONE CU (1000 barriers); replaced with wave-shuffle
// scan (26 barriers, 3 blocks parallel) + batched hist/scatter/zero across relations.

#define N_AUTHOR 50000
#define N_PAPER  50000
#define NEDGE    400000
#define KDIM     256
#define NHEAD    8
#define SLOPE    0.2f

// CSR slab layout (ints): off@0 (50001 used, pad to 50004), woff@50004 (50000),
// gsrc@100004 (400000). Stride 500008 keeps woff 16B-aligned for int4 loads.
#define CSR_STRIDE 500008
#define CSR_WOFF   50004
#define CSR_GSRC   100004

using bf16 = __hip_bfloat16;
typedef __attribute__((ext_vector_type(8))) short short8;
typedef __attribute__((ext_vector_type(4))) float float4e;

__device__ __forceinline__ float us2f(unsigned short u) {
    return __uint_as_float(((unsigned int)u) << 16);
}
__device__ __forceinline__ float fin(float v) {   // 0 if NaN/Inf
    return (((__float_as_uint(v) >> 23) & 0xFF) != 0xFF) ? v : 0.f;
}
__device__ __forceinline__ unsigned short f2bu(float f) {
    f = fin(f);
    bf16 h = __float2bfloat16(f);
    return *reinterpret_cast<unsigned short*>(&h);
}
__device__ __forceinline__ int clampi(int v, int hi) {
    return v < 0 ? 0 : (v >= hi ? hi - 1 : v);
}

__global__ void fill_marker(float* __restrict__ out, int total, float c)
{
    int i = blockIdx.x * blockDim.x + threadIdx.x;
    if (i < total) out[i] = c;
}

// ---------------------------------------------------------------------------
// W[256k][256n] f32  ->  BT[256n][256k] bf16  (pre-transpose for MFMA B-frags)
// ---------------------------------------------------------------------------
__global__ void prep_bt(const float* __restrict__ W, bf16* __restrict__ BT)
{
    int n = blockIdx.x, k = threadIdx.x;
    reinterpret_cast<unsigned short*>(BT)[n * KDIM + k] = f2bu(W[k * KDIM + n]);
}

// ---------------------------------------------------------------------------
// MFMA GEMM: C[M x 256] = A[M x 256] @ B (BT = B^T bf16 [n][k]), f32 acc.
// 128x128 tile, BK=32, 256 threads = 4 waves (2x2 of 64x64), 4x4 frags/wave.
// MODE 0: C(bf16) = acc
// MODE 1: C(bf16) = sc_w[n,h]*rfw + sc_c[n,h]*acc      (paper fusion epilogue)
// MODE 2: C(f32)  = sig(g)*other(bf16) + (1-sig(g))*(acc + bias)  (residual)
// ---------------------------------------------------------------------------
template<int MODE, typename TA>
__global__ __launch_bounds__(256) void mfma_gemm(
    const TA* __restrict__ A, const bf16* __restrict__ BT, int M,
    void* __restrict__ Cout,
    const float* __restrict__ bias, const bf16* __restrict__ other,
    const float* __restrict__ gate,
    const bf16* __restrict__ rfw, const float* __restrict__ sc_w,
    const float* __restrict__ sc_c)
{
    __shared__ short As[128 * 40];   // [row][k], pad 32->40
    __shared__ short Bs[128 * 40];   // [n][k]
    const int tid = threadIdx.x;
    const int lane = tid & 63, wave = tid >> 6;
    const int wm = wave >> 1, wn = wave & 1;
    const int rowBase = blockIdx.y * 128;
    const int colBase = blockIdx.x * 128;

    float4e acc[4][4];
    #pragma unroll
    for (int i = 0; i < 4; ++i)
        #pragma unroll
        for (int j = 0; j < 4; ++j) {
            float4e z = {0.f, 0.f, 0.f, 0.f};
            acc[i][j] = z;
        }

    const int srow = tid >> 2;          // 0..63
    const int sq = (tid & 3) << 3;      // 0,8,16,24

    for (int kt = 0; kt < KDIM; kt += 32) {
        #pragma unroll
        for (int p = 0; p < 2; ++p) {
            int r = srow + p * 64;
            int gr = rowBase + r;
            short8 v = {0, 0, 0, 0, 0, 0, 0, 0};
            if (gr < M) {
                if constexpr (std::is_same<TA, float>::value) {
                    const float* ap = A + (size_t)gr * KDIM + kt + sq;
                    float4 x = *reinterpret_cast<const float4*>(ap);
                    float4 y = *reinterpret_cast<const float4*>(ap + 4);
                    v[0] = (short)f2bu(x.x); v[1] = (short)f2bu(x.y);
                    v[2] = (short)f2bu(x.z); v[3] = (short)f2bu(x.w);
                    v[4] = (short)f2bu(y.x); v[5] = (short)f2bu(y.y);
                    v[6] = (short)f2bu(y.z); v[7] = (short)f2bu(y.w);
                } else {
                    v = *reinterpret_cast<const short8*>(
                        reinterpret_cast<const short*>(A) + (size_t)gr * KDIM + kt + sq);
                }
            }
            *reinterpret_cast<short8*>(&As[r * 40 + sq]) = v;
        }
        #pragma unroll
        for (int p = 0; p < 2; ++p) {
            int n = srow + p * 64;
            short8 v = *reinterpret_cast<const short8*>(
                reinterpret_cast<const short*>(BT) + (size_t)(colBase + n) * KDIM + kt + sq);
            *reinterpret_cast<short8*>(&Bs[n * 40 + sq]) = v;
        }
        __syncthreads();

        short8 af[4], bg[4];
        #pragma unroll
        for (int i = 0; i < 4; ++i)
            af[i] = *reinterpret_cast<const short8*>(
                &As[(wm * 64 + i * 16 + (lane & 15)) * 40 + ((lane >> 4) << 3)]);
        #pragma unroll
        for (int j = 0; j < 4; ++j)
            bg[j] = *reinterpret_cast<const short8*>(
                &Bs[(wn * 64 + j * 16 + (lane & 15)) * 40 + ((lane >> 4) << 3)]);
        #pragma unroll
        for (int i = 0; i < 4; ++i)
            #pragma unroll
            for (int j = 0; j < 4; ++j)
                acc[i][j] = __builtin_amdgcn_mfma_f32_16x16x32_bf16(
                    af[i], bg[j], acc[i][j], 0, 0, 0);
        __syncthreads();
    }

    float al = 0.f;
    if constexpr (MODE == 2) al = 1.f / (1.f + expf(-gate[0]));

    #pragma unroll
    for (int i = 0; i < 4; ++i) {
        int r0 = rowBase + wm * 64 + i * 16 + ((lane >> 4) << 2);
        #pragma unroll
        for (int j = 0; j < 4; ++j) {
            int col = colBase + wn * 64 + j * 16 + (lane & 15);
            #pragma unroll
            for (int reg = 0; reg < 4; ++reg) {
                int row = r0 + reg;
                if (row < M) {
                    size_t idx = (size_t)row * KDIM + col;
                    float v = acc[i][j][reg];
                    if constexpr (MODE == 0) {
                        reinterpret_cast<unsigned short*>(Cout)[idx] = f2bu(v);
                    } else if constexpr (MODE == 1) {
                        int h = col >> 5;
                        size_t si = (size_t)row * NHEAD + h;
                        float f = sc_w[si] * us2f(reinterpret_cast<const unsigned short*>(rfw)[idx])
                                + sc_c[si] * v;
                        reinterpret_cast<unsigned short*>(Cout)[idx] = f2bu(f);
                    } else {
                        float of = us2f(reinterpret_cast<const unsigned short*>(other)[idx]);
                        reinterpret_cast<float*>(Cout)[idx] =
                            fin(al * of + (1.f - al) * (v + bias[col]));
                    }
                }
            }
        }
    }
}

// ---------------------------------------------------------------------------
// Per-node per-head attention dot (micro)
// ---------------------------------------------------------------------------
__global__ void head_dot(const bf16* __restrict__ proj, const float* __restrict__ attn,
                         int off, int N, float* __restrict__ out)
{
    int gid = blockIdx.x * blockDim.x + threadIdx.x;
    if (gid >= N * NHEAD) return;
    int n = gid >> 3, k = gid & 7;
    const unsigned short* p =
        reinterpret_cast<const unsigned short*>(proj) + (size_t)n * KDIM + k * 32;
    const float* a = attn + k * 64 + off;
    float s = 0.f;
    #pragma unroll
    for (int d0 = 0; d0 < 32; d0 += 4) {
        ushort4 pv = *reinterpret_cast<const ushort4*>(p + d0);
        float4 av = *reinterpret_cast<const float4*>(a + d0);
        s += us2f(pv.x) * av.x + us2f(pv.y) * av.y
           + us2f(pv.z) * av.z + us2f(pv.w) * av.w;
    }
    out[gid] = fin(s);
}

// ---------------------------------------------------------------------------
// CSR build, batched over the 3 relations (blockIdx.y = relation).
// ---------------------------------------------------------------------------
__global__ void zero_woff(int* __restrict__ csr)
{
    int i = blockIdx.x * blockDim.x + threadIdx.x;
    if (i < N_PAPER) csr[blockIdx.y * CSR_STRIDE + CSR_WOFF + i] = 0;
}

__global__ void edge_hist3(const int* __restrict__ d0, const int* __restrict__ d1,
                           const int* __restrict__ d2, int* __restrict__ csr, int E)
{
    int e = blockIdx.x * blockDim.x + threadIdx.x;
    if (e >= E) return;
    int r = blockIdx.y;
    const int* d = r == 0 ? d0 : (r == 1 ? d1 : d2);
    atomicAdd(&csr[r * CSR_STRIDE + CSR_WOFF + clampi(d[e], N_PAPER)], 1);
}

// Exclusive scan of the 3 count arrays (one block per relation).
// 1024 threads x 4 elems = 4096/chunk, 13 chunks. Wave-shuffle inclusive scan
// (no barriers within wave) + 16-entry LDS cross-wave combine: 2 barriers/chunk
// vs the old Hillis-Steele's ~20/chunk x 49 chunks.
__global__ __launch_bounds__(1024) void scan_off3(int* __restrict__ csr)
{
    int* off = csr + blockIdx.x * CSR_STRIDE;
    int* cnt = off + CSR_WOFF;           // hist counts; rewritten as woff copy
    __shared__ int wtot[16];
    const int tid = threadIdx.x;
    const int lane = tid & 63, wv = tid >> 6;
    int carry = 0;
    for (int base = 0; base < N_PAPER; base += 4096) {
        int i = base + tid * 4;
        int v0 = 0, v1 = 0, v2 = 0, v3 = 0;
        if (i + 3 < N_PAPER) {
            int4 q = *reinterpret_cast<const int4*>(cnt + i);
            v0 = q.x; v1 = q.y; v2 = q.z; v3 = q.w;
        } else {
            if (i     < N_PAPER) v0 = cnt[i];
            if (i + 1 < N_PAPER) v1 = cnt[i + 1];
            if (i + 2 < N_PAPER) v2 = cnt[i + 2];
        }
        int s1 = v0 + v1, s2 = s1 + v2, s3 = s2 + v3;
        int x = s3;                       // wave64 inclusive scan of thread sums
        #pragma unroll
        for (int o = 1; o < 64; o <<= 1) {
            int t = __shfl_up(x, o, 64);
            if (lane >= o) x += t;
        }
        if (lane == 63) wtot[wv] = x;
        __syncthreads();
        int wexc = 0, ctot = 0;
        #pragma unroll
        for (int w = 0; w < 16; ++w) {
            int t = wtot[w];
            ctot += t;
            if (w < wv) wexc += t;
        }
        int texc = carry + wexc + (x - s3);   // exclusive prefix of elem i
        if (i     < N_PAPER) { off[i]     = texc;      cnt[i]     = texc;      }
        if (i + 1 < N_PAPER) { off[i + 1] = texc + v0; cnt[i + 1] = texc + v0; }
        if (i + 2 < N_PAPER) { off[i + 2] = texc + s1; cnt[i + 2] = texc + s1; }
        if (i + 3 < N_PAPER) { off[i + 3] = texc + s2; cnt[i + 3] = texc + s2; }
        carry += ctot;                    // uniform across threads
        __syncthreads();                  // wtot reads done before next chunk
    }
    if (tid == 0) off[N_PAPER] = carry;
}

__global__ void edge_scatter3(const int* __restrict__ s0, const int* __restrict__ s1,
                              const int* __restrict__ s2,
                              const int* __restrict__ d0, const int* __restrict__ d1,
                              const int* __restrict__ d2,
                              int* __restrict__ csr, int E)
{
    int e = blockIdx.x * blockDim.x + threadIdx.x;
    if (e >= E) return;
    int r = blockIdx.y;
    const int* s = r == 0 ? s0 : (r == 1 ? s1 : s2);
    const int* d = r == 0 ? d0 : (r == 1 ? d1 : d2);
    int* slab = csr + r * CSR_STRIDE;
    int pos = atomicAdd(&slab[CSR_WOFF + clampi(d[e], N_PAPER)], 1);
    slab[CSR_GSRC + pos] = clampi(s[e], N_PAPER);
}

// ---------------------------------------------------------------------------
// GAT gather: one wave per dst node; lane covers 4 cols, head = lane>>3.
// Single pass (linearity): ft = relu( (sum_e ex_e * feat[src_e]) / sum_e ex_e ).
// No atomics; fused softmax + aggregate + relu + bf16 cast.
// ---------------------------------------------------------------------------
__global__ __launch_bounds__(256) void gat_gather(
    const int* __restrict__ off, const int* __restrict__ gsrc,
    const float* __restrict__ el, const float* __restrict__ er,
    const bf16* __restrict__ feat, bf16* __restrict__ out, int N)
{
    int d = blockIdx.x * 4 + (threadIdx.x >> 6);
    if (d >= N) return;
    int lane = threadIdx.x & 63;
    int h = lane >> 3;
    int col = lane * 4;
    float erd = er[d * NHEAD + h];
    int e0 = off[d], e1 = off[d + 1];
    float denom = 0.f, a0 = 0.f, a1 = 0.f, a2 = 0.f, a3 = 0.f;
    for (int e = e0; e < e1; ++e) {
        int s = gsrc[e];
        float v = el[s * NHEAD + h] + erd;
        v = v > 0.f ? v : SLOPE * v;
        float ex = expf(fminf(v, 30.f));
        denom += ex;
        ushort4 fv = *reinterpret_cast<const ushort4*>(
            reinterpret_cast<const unsigned short*>(feat) + (size_t)s * KDIM + col);
        a0 = fmaf(us2f(fv.x), ex, a0); a1 = fmaf(us2f(fv.y), ex, a1);
        a2 = fmaf(us2f(fv.z), ex, a2); a3 = fmaf(us2f(fv.w), ex, a3);
    }
    float inv = 1.f / fmaxf(denom, 1e-20f);
    ushort4 o;
    o.x = f2bu(fmaxf(a0 * inv, 0.f)); o.y = f2bu(fmaxf(a1 * inv, 0.f));
    o.z = f2bu(fmaxf(a2 * inv, 0.f)); o.w = f2bu(fmaxf(a3 * inv, 0.f));
    *reinterpret_cast<ushort4*>(
        reinterpret_cast<unsigned short*>(out) + (size_t)d * KDIM + col) = o;
}

// ---------------------------------------------------------------------------
// Macro score vectors + skinny dots + softmax (node_paper never materialized)
// ---------------------------------------------------------------------------
__global__ void prep_v(const float* __restrict__ Ww, const float* __restrict__ Wc,
                       const float* __restrict__ Wn, const float* __restrict__ attn,
                       float* __restrict__ vbuf)
{
    int id = blockIdx.x * blockDim.x + threadIdx.x;
    if (id >= 3 * 2048) return;
    int which = id >> 11;
    int rem = id & 2047;
    int h = rem >> 8, k = rem & 255;
    const float* Wsrc = which == 0 ? Ww : (which == 1 ? Wc : Wn);
    int aoff = which == 2 ? 0 : 32;
    float s = 0.f;
    #pragma unroll 8
    for (int d = 0; d < 32; ++d)
        s += Wsrc[(size_t)k * KDIM + h * 32 + d] * attn[h * 64 + aoff + d];
    vbuf[which * 2048 + h * 256 + k] = fin(s);
}

template<typename T>
__global__ void macro_dot(const T* __restrict__ A, const float* __restrict__ v0,
                          float* __restrict__ out, int N)
{
    int id = blockIdx.x * blockDim.x + threadIdx.x;
    if (id >= N * NHEAD) return;
    int n = id >> 3, h = id & 7;
    const float* vh = v0 + h * 256;
    float s = 0.f;
    if constexpr (std::is_same<T, float>::value) {
        const float* row = A + (size_t)n * KDIM;
        for (int k = 0; k < KDIM; k += 4) {
            float4 a = *reinterpret_cast<const float4*>(row + k);
            float4 b = *reinterpret_cast<const float4*>(vh + k);
            s += a.x * b.x + a.y * b.y + a.z * b.z + a.w * b.w;
        }
    } else {
        const unsigned short* row =
            reinterpret_cast<const unsigned short*>(A) + (size_t)n * KDIM;
        for (int k = 0; k < KDIM; k += 4) {
            ushort4 a = *reinterpret_cast<const ushort4*>(row + k);
            float4 b = *reinterpret_cast<const float4*>(vh + k);
            s += us2f(a.x) * b.x + us2f(a.y) * b.y + us2f(a.z) * b.z + us2f(a.w) * b.w;
        }
    }
    out[id] = fin(s);
}

__global__ void score_kernel(const float* __restrict__ dotL, const float* __restrict__ dotW,
                             const float* __restrict__ dotC,
                             float* __restrict__ ow, float* __restrict__ oc, int total)
{
    int i = blockIdx.x * blockDim.x + threadIdx.x;
    if (i >= total) return;
    float sw = dotL[i] + dotW[i]; sw = sw > 0.f ? sw : SLOPE * sw;
    float sc = dotL[i] + dotC[i]; sc = sc > 0.f ? sc : SLOPE * sc;
    float m = fmaxf(sw, sc);
    float ew = expf(sw - m), ec = expf(sc - m);
    float inv = 1.f / (ew + ec);
    ow[i] = fin(ew * inv);
    oc[i] = fin(ec * inv);
}

// ---------------------------------------------------------------------------
extern "C" void kernel_launch(void* const* d_in, const int* in_sizes, int n_in,
                              void* d_out, int out_size, void* d_ws, size_t ws_size,
                              hipStream_t stream)
{
    static const int expected[24] = {
        12800000, 12800000, 65536, 65536, 512, 512, 65536, 65536,
        65536, 65536, 65536, 512, 65536, 256, 65536, 256, 1, 1,
        400000, 400000, 400000, 400000, 400000, 400000};
    float marker = 0.f;
    if (n_in != 24) marker = 500.f;
    else {
        for (int i = 0; i < 24; ++i)
            if (in_sizes[i] != expected[i]) { marker = 200.f + 8.f * i; break; }
    }
    if (marker == 0.f && out_size != 25600000) marker = 600.f + (float)(out_size / 1000000);
    if (marker == 0.f && ws_size < 51200000ull) marker = 1000.f + (float)(ws_size / 1000000ull);
    if (marker != 0.f) {
        fill_marker<<<(out_size + 255) / 256, 256, 0, stream>>>((float*)d_out, out_size, marker);
        return;
    }

    const float* feats_a  = (const float*)d_in[0];
    const float* feats_p  = (const float*)d_in[1];
    const float* W_mic_a  = (const float*)d_in[2];
    const float* W_mic_p  = (const float*)d_in[3];
    const float* attn_a   = (const float*)d_in[4];
    const float* attn_p   = (const float*)d_in[5];
    const float* W_node_p = (const float*)d_in[7];
    const float* W_rel_w  = (const float*)d_in[8];
    const float* W_rel_wb = (const float*)d_in[9];
    const float* W_rel_c  = (const float*)d_in[10];
    const float* attn_mac = (const float*)d_in[11];
    const float* W_res_a  = (const float*)d_in[12];
    const float* b_res_a  = (const float*)d_in[13];
    const float* W_res_p  = (const float*)d_in[14];
    const float* b_res_p  = (const float*)d_in[15];
    const float* rw_a     = (const float*)d_in[16];
    const float* rw_p     = (const float*)d_in[17];
    const int* w_src  = (const int*)d_in[18];
    const int* w_dst  = (const int*)d_in[19];
    const int* wb_src = (const int*)d_in[20];
    const int* wb_dst = (const int*)d_in[21];
    const int* c_src  = (const int*)d_in[22];
    const int* c_dst  = (const int*)d_in[23];

    const int NB = N_PAPER * KDIM;            // 12.8M elems
    // ---- d_out (f32, 102.4MB): [author 51.2MB][paper 51.2MB] ----
    float* Oa_f = (float*)d_out;
    float* Op_f = Oa_f + NB;
    bf16* Oa_b = (bf16*)d_out;                // P_a -> r_written_by (author lower)
    bf16* Op_b = (bf16*)Op_f;                 // P_p -> rf_writes    (paper lower)
    char* au_up = (char*)d_out + 25600000;    // author upper 25.6MB
    bf16*  Cslot = (bf16*)au_up;              // r_cites
    bf16*  BTa0  = (bf16*)au_up;              // later: W_res_p BT (Cslot dead)
    bf16*  BTa1  = BTa0 + 65536;              //        W_rel_wb BT
    char* pu = (char*)d_out + 76800000;       // paper upper 25.6MB
    float* dotW = (float*)pu;
    float* dotC = dotW + 400000;
    float* dotL = dotW + 800000;
    float* sc_w = dotW + 1200000;
    float* sc_c = dotW + 1600000;
    float* vbuf = dotW + 2000000;             // 6144 f32
    bf16* BT0 = (bf16*)(pu + 10000000);       // early BT slots (128KB each)
    bf16* BT1 = BT0 + 65536;
    bf16* BT2 = BT1 + 65536;
    bf16* BT3 = BT2 + 65536;
    // ---- d_ws (51.2e6 B): [A_ws 25.6MB][X 25.6MB] ----
    bf16* A_ws = (bf16*)d_ws;                 // r_writes -> fused_paper
    bf16* BTw  = (bf16*)d_ws;                 // W_res_a BT (after fused dead)
    char* Xb   = (char*)d_ws + 25600000;
    float* el_w  = (float*)Xb;                // 5 x 400,000 f32 (8MB)
    float* er_w  = el_w + 400000;
    float* el_p  = el_w + 800000;
    float* er_wb = el_w + 1200000;
    float* er_c  = el_w + 1600000;
    int*  csr    = (int*)(el_w + 2000000);    // 3 x 500008 ints (~6MB), 16B-aligned
    bf16* Xslot  = (bf16*)Xb;                 // later: rf_written_by (25.6MB)

    dim3 mg(2, (N_PAPER + 127) / 128);
    int hdB = (N_PAPER * NHEAD + 255) / 256;
    int eB  = (NEDGE + 255) / 256;
    int gB  = (N_PAPER + 3) / 4;

    // ---- 1: micro projections (MFMA) ----
    prep_bt<<<256, 256, 0, stream>>>(W_mic_a, BT0);
    prep_bt<<<256, 256, 0, stream>>>(W_mic_p, BT1);
    mfma_gemm<0, float><<<mg, 256, 0, stream>>>(feats_a, BT0, N_AUTHOR, Oa_b,
        nullptr, nullptr, nullptr, nullptr, nullptr, nullptr);
    mfma_gemm<0, float><<<mg, 256, 0, stream>>>(feats_p, BT1, N_PAPER, Op_b,
        nullptr, nullptr, nullptr, nullptr, nullptr, nullptr);

    // ---- 2: micro attention dots ----
    head_dot<<<hdB, 256, 0, stream>>>(Oa_b, attn_a, 0,  N_AUTHOR, el_w);
    head_dot<<<hdB, 256, 0, stream>>>(Op_b, attn_a, 32, N_PAPER,  er_w);
    head_dot<<<hdB, 256, 0, stream>>>(Op_b, attn_p, 0,  N_PAPER,  el_p);
    head_dot<<<hdB, 256, 0, stream>>>(Oa_b, attn_p, 32, N_AUTHOR, er_wb);
    head_dot<<<hdB, 256, 0, stream>>>(Op_b, attn_p, 32, N_PAPER,  er_c);

    // ---- 3: relations via CSR gather, CSR build batched across relations.
    // r0 writes: feat P_a(Oa_b) -> A_ws
    // r1 written_by: feat P_p(Op_b) -> Oa_b (P_a dead after r0 gather)
    // r2 cites: feat P_p(Op_b) -> Cslot (distinct buffer; gather forbids in-place)
    zero_woff<<<dim3((N_PAPER + 255) / 256, 3), 256, 0, stream>>>(csr);
    edge_hist3<<<dim3(eB, 3), 256, 0, stream>>>(w_dst, wb_dst, c_dst, csr, NEDGE);
    scan_off3<<<3, 1024, 0, stream>>>(csr);
    edge_scatter3<<<dim3(eB, 3), 256, 0, stream>>>(w_src, wb_src, c_src,
                                                   w_dst, wb_dst, c_dst, csr, NEDGE);
    {
        const float* rel_el[3] = {el_w, el_p, el_p};
        const float* rel_er[3] = {er_w, er_wb, er_c};
        const bf16* rfeat[3]   = {Oa_b, Op_b, Op_b};
        bf16* rout[3]          = {A_ws, Oa_b, Cslot};
        for (int r = 0; r < 3; ++r) {
            int* off  = csr + r * CSR_STRIDE;
            int* gsrc = off + CSR_GSRC;
            gat_gather<<<gB, 256, 0, stream>>>(off, gsrc, rel_el[r], rel_er[r],
                                               rfeat[r], rout[r], N_PAPER);
        }
    }
    // A_ws=r_writes, Oa_b=r_written_by, Cslot=r_cites; P_p (Op_b) dead.

    // ---- 4: macro scores via vector algebra ----
    prep_v<<<24, 256, 0, stream>>>(W_rel_w, W_rel_c, W_node_p, attn_mac, vbuf);
    macro_dot<bf16><<<hdB, 256, 0, stream>>>(A_ws,  vbuf,        dotW, N_PAPER);
    macro_dot<bf16><<<hdB, 256, 0, stream>>>(Cslot, vbuf + 2048, dotC, N_PAPER);
    macro_dot<float><<<hdB, 256, 0, stream>>>(feats_p, vbuf + 4096, dotL, N_PAPER);
    score_kernel<<<hdB, 256, 0, stream>>>(dotL, dotW, dotC, sc_w, sc_c, N_PAPER * NHEAD);

    // ---- 5: rf_writes = r_writes(A_ws) @ W_rel_w -> Op_b (P_p dead) ----
    prep_bt<<<256, 256, 0, stream>>>(W_rel_w, BT2);
    mfma_gemm<0, bf16><<<mg, 256, 0, stream>>>(A_ws, BT2, N_PAPER, Op_b,
        nullptr, nullptr, nullptr, nullptr, nullptr, nullptr);
    // ---- 6: fused = sc_w*rf_writes(Op_b) + sc_c*(r_cites(Cslot) @ W_rel_c) -> A_ws ----
    prep_bt<<<256, 256, 0, stream>>>(W_rel_c, BT3);
    mfma_gemm<1, bf16><<<mg, 256, 0, stream>>>(Cslot, BT3, N_PAPER, A_ws,
        nullptr, nullptr, nullptr, Op_b, sc_w, sc_c);
    // ---- 7: paper gated residual -> Op_f FINAL (BT in au_up; Cslot dead) ----
    prep_bt<<<256, 256, 0, stream>>>(W_res_p, BTa0);
    mfma_gemm<2, float><<<mg, 256, 0, stream>>>(feats_p, BTa0, N_PAPER, Op_f,
        b_res_p, A_ws, rw_p, nullptr, nullptr, nullptr);
    // ---- 8: rf_written_by = r_written_by(Oa_b) @ W_rel_wb -> Xslot (CSR dead) ----
    prep_bt<<<256, 256, 0, stream>>>(W_rel_wb, BTa1);
    mfma_gemm<0, bf16><<<mg, 256, 0, stream>>>(Oa_b, BTa1, N_AUTHOR, Xslot,
        nullptr, nullptr, nullptr, nullptr, nullptr, nullptr);
    // ---- 9: author gated residual -> Oa_f FINAL (BT in A_ws; fused dead) ----
    prep_bt<<<256, 256, 0, stream>>>(W_res_a, BTw);
    mfma_gemm<2, float><<<mg, 256, 0, stream>>>(feats_a, BTw, N_AUTHOR, Oa_f,
        b_res_a, Xslot, rw_a, nullptr, nullptr, nullptr);
}

// Round 2
// 947.550 us; speedup vs baseline: 1.3844x; 1.0746x over previous
//
#include <hip/hip_runtime.h>
#include <hip/hip_bf16.h>
#include <type_traits>

// HGConv layer: micro (per-relation GAT) + macro (semantic attention) + gated residual.
// I/O: float32 (verified round 6). Internals: bf16 matrices, f32 accumulation.
// Round 8: edge stage scatter->gather via on-device CSR.
// Round 9: wave-shuffle scan (was 3x96us on one CU).
// Round 10: edge_scatter3 had 66MB WRITE_SIZE (14x amplification from random 4B
// stores). Replaced hist/scan/scatter with bucketed CSR build: coarse 512-dst
// buckets -> bucket-major packed temp (coalesced) -> per-bucket LDS hist+scan+
// scatter -> coalesced off[] and gsrc[] writes. No global per-dst atomics.

#define N_AUTHOR 50000
#define N_PAPER  50000
#define NEDGE    400000
#define KDIM     256
#define NHEAD    8
#define SLOPE    0.2f

#define BUCK_W   512                    // dsts per bucket (shift 9)
#define NBUCK    98                     // ceil(50000/512)
#define SBUF_CAP 6144                   // LDS staging cap (span ~4096+-64)

// CSR slab (ints): off@0 (50001 used, pad 50004), gsrc@50004 (400000).
#define CSR_STRIDE 450004
#define CSR_GSRC   50004

using bf16 = __hip_bfloat16;
typedef __attribute__((ext_vector_type(8))) short short8;
typedef __attribute__((ext_vector_type(4))) float float4e;

__device__ __forceinline__ float us2f(unsigned short u) {
    return __uint_as_float(((unsigned int)u) << 16);
}
__device__ __forceinline__ float fin(float v) {   // 0 if NaN/Inf
    return (((__float_as_uint(v) >> 23) & 0xFF) != 0xFF) ? v : 0.f;
}
__device__ __forceinline__ unsigned short f2bu(float f) {
    f = fin(f);
    bf16 h = __float2bfloat16(f);
    return *reinterpret_cast<unsigned short*>(&h);
}
__device__ __forceinline__ int clampi(int v, int hi) {
    return v < 0 ? 0 : (v >= hi ? hi - 1 : v);
}

__global__ void fill_marker(float* __restrict__ out, int total, float c)
{
    int i = blockIdx.x * blockDim.x + threadIdx.x;
    if (i < total) out[i] = c;
}

// ---------------------------------------------------------------------------
// W[256k][256n] f32  ->  BT[256n][256k] bf16  (pre-transpose for MFMA B-frags)
// ---------------------------------------------------------------------------
__global__ void prep_bt(const float* __restrict__ W, bf16* __restrict__ BT)
{
    int n = blockIdx.x, k = threadIdx.x;
    reinterpret_cast<unsigned short*>(BT)[n * KDIM + k] = f2bu(W[k * KDIM + n]);
}

// ---------------------------------------------------------------------------
// MFMA GEMM: C[M x 256] = A[M x 256] @ B (BT = B^T bf16 [n][k]), f32 acc.
// 128x128 tile, BK=32, 256 threads = 4 waves (2x2 of 64x64), 4x4 frags/wave.
// MODE 0: C(bf16) = acc
// MODE 1: C(bf16) = sc_w[n,h]*rfw + sc_c[n,h]*acc      (paper fusion epilogue)
// MODE 2: C(f32)  = sig(g)*other(bf16) + (1-sig(g))*(acc + bias)  (residual)
// ---------------------------------------------------------------------------
template<int MODE, typename TA>
__global__ __launch_bounds__(256) void mfma_gemm(
    const TA* __restrict__ A, const bf16* __restrict__ BT, int M,
    void* __restrict__ Cout,
    const float* __restrict__ bias, const bf16* __restrict__ other,
    const float* __restrict__ gate,
    const bf16* __restrict__ rfw, const float* __restrict__ sc_w,
    const float* __restrict__ sc_c)
{
    __shared__ short As[128 * 40];   // [row][k], pad 32->40
    __shared__ short Bs[128 * 40];   // [n][k]
    const int tid = threadIdx.x;
    const int lane = tid & 63, wave = tid >> 6;
    const int wm = wave >> 1, wn = wave & 1;
    const int rowBase = blockIdx.y * 128;
    const int colBase = blockIdx.x * 128;

    float4e acc[4][4];
    #pragma unroll
    for (int i = 0; i < 4; ++i)
        #pragma unroll
        for (int j = 0; j < 4; ++j) {
            float4e z = {0.f, 0.f, 0.f, 0.f};
            acc[i][j] = z;
        }

    const int srow = tid >> 2;          // 0..63
    const int sq = (tid & 3) << 3;      // 0,8,16,24

    for (int kt = 0; kt < KDIM; kt += 32) {
        #pragma unroll
        for (int p = 0; p < 2; ++p) {
            int r = srow + p * 64;
            int gr = rowBase + r;
            short8 v = {0, 0, 0, 0, 0, 0, 0, 0};
            if (gr < M) {
                if constexpr (std::is_same<TA, float>::value) {
                    const float* ap = A + (size_t)gr * KDIM + kt + sq;
                    float4 x = *reinterpret_cast<const float4*>(ap);
                    float4 y = *reinterpret_cast<const float4*>(ap + 4);
                    v[0] = (short)f2bu(x.x); v[1] = (short)f2bu(x.y);
                    v[2] = (short)f2bu(x.z); v[3] = (short)f2bu(x.w);
                    v[4] = (short)f2bu(y.x); v[5] = (short)f2bu(y.y);
                    v[6] = (short)f2bu(y.z); v[7] = (short)f2bu(y.w);
                } else {
                    v = *reinterpret_cast<const short8*>(
                        reinterpret_cast<const short*>(A) + (size_t)gr * KDIM + kt + sq);
                }
            }
            *reinterpret_cast<short8*>(&As[r * 40 + sq]) = v;
        }
        #pragma unroll
        for (int p = 0; p < 2; ++p) {
            int n = srow + p * 64;
            short8 v = *reinterpret_cast<const short8*>(
                reinterpret_cast<const short*>(BT) + (size_t)(colBase + n) * KDIM + kt + sq);
            *reinterpret_cast<short8*>(&Bs[n * 40 + sq]) = v;
        }
        __syncthreads();

        short8 af[4], bg[4];
        #pragma unroll
        for (int i = 0; i < 4; ++i)
            af[i] = *reinterpret_cast<const short8*>(
                &As[(wm * 64 + i * 16 + (lane & 15)) * 40 + ((lane >> 4) << 3)]);
        #pragma unroll
        for (int j = 0; j < 4; ++j)
            bg[j] = *reinterpret_cast<const short8*>(
                &Bs[(wn * 64 + j * 16 + (lane & 15)) * 40 + ((lane >> 4) << 3)]);
        #pragma unroll
        for (int i = 0; i < 4; ++i)
            #pragma unroll
            for (int j = 0; j < 4; ++j)
                acc[i][j] = __builtin_amdgcn_mfma_f32_16x16x32_bf16(
                    af[i], bg[j], acc[i][j], 0, 0, 0);
        __syncthreads();
    }

    float al = 0.f;
    if constexpr (MODE == 2) al = 1.f / (1.f + expf(-gate[0]));

    #pragma unroll
    for (int i = 0; i < 4; ++i) {
        int r0 = rowBase + wm * 64 + i * 16 + ((lane >> 4) << 2);
        #pragma unroll
        for (int j = 0; j < 4; ++j) {
            int col = colBase + wn * 64 + j * 16 + (lane & 15);
            #pragma unroll
            for (int reg = 0; reg < 4; ++reg) {
                int row = r0 + reg;
                if (row < M) {
                    size_t idx = (size_t)row * KDIM + col;
                    float v = acc[i][j][reg];
                    if constexpr (MODE == 0) {
                        reinterpret_cast<unsigned short*>(Cout)[idx] = f2bu(v);
                    } else if constexpr (MODE == 1) {
                        int h = col >> 5;
                        size_t si = (size_t)row * NHEAD + h;
                        float f = sc_w[si] * us2f(reinterpret_cast<const unsigned short*>(rfw)[idx])
                                + sc_c[si] * v;
                        reinterpret_cast<unsigned short*>(Cout)[idx] = f2bu(f);
                    } else {
                        float of = us2f(reinterpret_cast<const unsigned short*>(other)[idx]);
                        reinterpret_cast<float*>(Cout)[idx] =
                            fin(al * of + (1.f - al) * (v + bias[col]));
                    }
                }
            }
        }
    }
}

// ---------------------------------------------------------------------------
// Per-node per-head attention dot (micro)
// ---------------------------------------------------------------------------
__global__ void head_dot(const bf16* __restrict__ proj, const float* __restrict__ attn,
                         int off, int N, float* __restrict__ out)
{
    int gid = blockIdx.x * blockDim.x + threadIdx.x;
    if (gid >= N * NHEAD) return;
    int n = gid >> 3, k = gid & 7;
    const unsigned short* p =
        reinterpret_cast<const unsigned short*>(proj) + (size_t)n * KDIM + k * 32;
    const float* a = attn + k * 64 + off;
    float s = 0.f;
    #pragma unroll
    for (int d0 = 0; d0 < 32; d0 += 4) {
        ushort4 pv = *reinterpret_cast<const ushort4*>(p + d0);
        float4 av = *reinterpret_cast<const float4*>(a + d0);
        s += us2f(pv.x) * av.x + us2f(pv.y) * av.y
           + us2f(pv.z) * av.z + us2f(pv.w) * av.w;
    }
    out[gid] = fin(s);
}

// ---------------------------------------------------------------------------
// Bucketed CSR build (relation = blockIdx.y).
// meta layout (ints): gbcnt[3][NBUCK] @0, bbase[3][NBUCK+1] @294, grank[3][NBUCK] @591
// ---------------------------------------------------------------------------
__global__ void zero_meta(int* __restrict__ meta)
{
    int i = threadIdx.x + blockIdx.x * blockDim.x;
    if (i < 3 * NBUCK) meta[i] = 0;                       // gbcnt
    if (i < 3 * NBUCK) meta[591 + i] = 0;                 // grank
}

__global__ __launch_bounds__(256) void bucket_count(
    const int* __restrict__ d0, const int* __restrict__ d1,
    const int* __restrict__ d2, int* __restrict__ meta, int E)
{
    __shared__ int cnt[NBUCK];
    for (int i = threadIdx.x; i < NBUCK; i += 256) cnt[i] = 0;
    __syncthreads();
    int r = blockIdx.y;
    const int* d = r == 0 ? d0 : (r == 1 ? d1 : d2);
    for (int e = blockIdx.x * 256 + threadIdx.x; e < E; e += gridDim.x * 256)
        atomicAdd(&cnt[clampi(d[e], N_PAPER) >> 9], 1);
    __syncthreads();
    for (int i = threadIdx.x; i < NBUCK; i += 256)
        if (cnt[i]) atomicAdd(&meta[r * NBUCK + i], cnt[i]);
}

// 3 waves, one per relation: shuffle-scan NBUCK bucket counts -> bases.
__global__ void bucket_scan(int* __restrict__ meta)
{
    int r = threadIdx.x >> 6, lane = threadIdx.x & 63;
    if (r >= 3) return;
    const int* gbcnt = meta + r * NBUCK;
    int* bbase = meta + 294 + r * (NBUCK + 1);
    int carry = 0;
    for (int base = 0; base < NBUCK; base += 64) {
        int i = base + lane;
        int v = (i < NBUCK) ? gbcnt[i] : 0;
        int x = v;
        #pragma unroll
        for (int o = 1; o < 64; o <<= 1) {
            int t = __shfl_up(x, o, 64);
            if (lane >= o) x += t;
        }
        if (i < NBUCK) bbase[i] = carry + x - v;
        carry += __shfl(x, 63, 64);
    }
    if (lane == 0) bbase[NBUCK] = carry;
}

// Scatter edges into bucket-major temp T, packed (src<<9)|dlocal (25 bits).
// 64 fixed chunks/relation; per-(block,bucket) runs ~64 edges = 256B contiguous.
__global__ __launch_bounds__(256) void bucket_scatter(
    const int* __restrict__ s0, const int* __restrict__ s1,
    const int* __restrict__ s2,
    const int* __restrict__ d0, const int* __restrict__ d1,
    const int* __restrict__ d2,
    int* __restrict__ meta, int* __restrict__ T, int E)
{
    __shared__ int cnt[NBUCK];
    __shared__ int base[NBUCK];
    int r = blockIdx.y;
    const int* s = r == 0 ? s0 : (r == 1 ? s1 : s2);
    const int* d = r == 0 ? d0 : (r == 1 ? d1 : d2);
    const int* bbase = meta + 294 + r * (NBUCK + 1);
    int* grank = meta + 591 + r * NBUCK;
    int* Tr = T + r * NEDGE;

    for (int i = threadIdx.x; i < NBUCK; i += 256) cnt[i] = 0;
    __syncthreads();

    const int CH = (E + gridDim.x - 1) / gridDim.x;
    int e0 = blockIdx.x * CH;
    int e1 = min(e0 + CH, E);
    for (int e = e0 + threadIdx.x; e < e1; e += 256)
        atomicAdd(&cnt[clampi(d[e], N_PAPER) >> 9], 1);
    __syncthreads();
    if (threadIdx.x < NBUCK) {
        int c = cnt[threadIdx.x];
        base[threadIdx.x] = c ? bbase[threadIdx.x] + atomicAdd(&grank[threadIdx.x], c) : 0;
        cnt[threadIdx.x] = 0;            // reuse as local rank
    }
    __syncthreads();
    for (int e = e0 + threadIdx.x; e < e1; e += 256) {
        int dc = clampi(d[e], N_PAPER);
        int b = dc >> 9, dl = dc & 511;
        int l = atomicAdd(&cnt[b], 1);
        Tr[base[b] + l] = (clampi(s[e], N_PAPER) << 9) | dl;
    }
}

// Per (bucket, relation): LDS per-dst hist + scan -> off[] (coalesced), then
// LDS scatter + coalesced gsrc stream-out. Replaces global hist/scan/scatter.
__global__ __launch_bounds__(256) void csr_build(
    const int* __restrict__ meta, const int* __restrict__ T,
    int* __restrict__ csr)
{
    __shared__ int cnt[512];
    __shared__ int loc[512];
    __shared__ int sbuf[SBUF_CAP];
    __shared__ int wtot[4];
    int b = blockIdx.x, r = blockIdx.y;
    const int* bbase = meta + 294 + r * (NBUCK + 1);
    const int* Tr = T + r * NEDGE;
    int* off = csr + r * CSR_STRIDE;
    int* gsrc = off + CSR_GSRC;
    const int tid = threadIdx.x, lane = tid & 63, wv = tid >> 6;

    int dstbase = b << 9;
    int nd = min(512, N_PAPER - dstbase);
    int cbase = bbase[b], cend = bbase[b + 1];
    int span = cend - cbase;

    cnt[2 * tid] = 0; cnt[2 * tid + 1] = 0;
    __syncthreads();
    for (int t = tid; t < span; t += 256)
        atomicAdd(&cnt[Tr[cbase + t] & 511], 1);
    __syncthreads();

    // exclusive scan of cnt[0..512) (2 elems/thread, wave shuffle + LDS combine)
    int v0 = cnt[2 * tid], v1 = cnt[2 * tid + 1];
    int sthr = v0 + v1;
    int x = sthr;
    #pragma unroll
    for (int o = 1; o < 64; o <<= 1) {
        int t = __shfl_up(x, o, 64);
        if (lane >= o) x += t;
    }
    if (lane == 63) wtot[wv] = x;
    __syncthreads();
    int wexc = 0;
    #pragma unroll
    for (int w = 0; w < 4; ++w)
        if (w < wv) wexc += wtot[w];
    int exc = wexc + x - sthr;
    loc[2 * tid] = exc;
    loc[2 * tid + 1] = exc + v0;
    int i0 = 2 * tid, i1 = 2 * tid + 1;
    if (i0 < nd) off[dstbase + i0] = cbase + exc;
    if (i1 < nd) off[dstbase + i1] = cbase + exc + v0;
    if (b == NBUCK - 1 && tid == 0) off[N_PAPER] = cend;
    cnt[i0] = 0; cnt[i1] = 0;            // reuse as per-dst rank
    __syncthreads();

    if (span <= SBUF_CAP) {
        for (int t = tid; t < span; t += 256) {
            int v = Tr[cbase + t];
            int dl = v & 511;
            int pos = loc[dl] + atomicAdd(&cnt[dl], 1);
            sbuf[pos] = v >> 9;
        }
        __syncthreads();
        for (int t = tid; t < span; t += 256)
            gsrc[cbase + t] = sbuf[t];
    } else {                              // never expected; correctness fallback
        for (int t = tid; t < span; t += 256) {
            int v = Tr[cbase + t];
            int dl = v & 511;
            int pos = loc[dl] + atomicAdd(&cnt[dl], 1);
            gsrc[cbase + pos] = v >> 9;
        }
    }
}

// ---------------------------------------------------------------------------
// GAT gather: one wave per dst node; lane covers 4 cols, head = lane>>3.
// Single pass (linearity): ft = relu( (sum_e ex_e * feat[src_e]) / sum_e ex_e ).
// No atomics; fused softmax + aggregate + relu + bf16 cast.
// ---------------------------------------------------------------------------
__global__ __launch_bounds__(256) void gat_gather(
    const int* __restrict__ off, const int* __restrict__ gsrc,
    const float* __restrict__ el, const float* __restrict__ er,
    const bf16* __restrict__ feat, bf16* __restrict__ out, int N)
{
    int d = blockIdx.x * 4 + (threadIdx.x >> 6);
    if (d >= N) return;
    int lane = threadIdx.x & 63;
    int h = lane >> 3;
    int col = lane * 4;
    float erd = er[d * NHEAD + h];
    int e0 = off[d], e1 = off[d + 1];
    float denom = 0.f, a0 = 0.f, a1 = 0.f, a2 = 0.f, a3 = 0.f;
    for (int e = e0; e < e1; ++e) {
        int s = gsrc[e];
        float v = el[s * NHEAD + h] + erd;
        v = v > 0.f ? v : SLOPE * v;
        float ex = expf(fminf(v, 30.f));
        denom += ex;
        ushort4 fv = *reinterpret_cast<const ushort4*>(
            reinterpret_cast<const unsigned short*>(feat) + (size_t)s * KDIM + col);
        a0 = fmaf(us2f(fv.x), ex, a0); a1 = fmaf(us2f(fv.y), ex, a1);
        a2 = fmaf(us2f(fv.z), ex, a2); a3 = fmaf(us2f(fv.w), ex, a3);
    }
    float inv = 1.f / fmaxf(denom, 1e-20f);
    ushort4 o;
    o.x = f2bu(fmaxf(a0 * inv, 0.f)); o.y = f2bu(fmaxf(a1 * inv, 0.f));
    o.z = f2bu(fmaxf(a2 * inv, 0.f)); o.w = f2bu(fmaxf(a3 * inv, 0.f));
    *reinterpret_cast<ushort4*>(
        reinterpret_cast<unsigned short*>(out) + (size_t)d * KDIM + col) = o;
}

// ---------------------------------------------------------------------------
// Macro score vectors + skinny dots + softmax (node_paper never materialized)
// ---------------------------------------------------------------------------
__global__ void prep_v(const float* __restrict__ Ww, const float* __restrict__ Wc,
                       const float* __restrict__ Wn, const float* __restrict__ attn,
                       float* __restrict__ vbuf)
{
    int id = blockIdx.x * blockDim.x + threadIdx.x;
    if (id >= 3 * 2048) return;
    int which = id >> 11;
    int rem = id & 2047;
    int h = rem >> 8, k = rem & 255;
    const float* Wsrc = which == 0 ? Ww : (which == 1 ? Wc : Wn);
    int aoff = which == 2 ? 0 : 32;
    float s = 0.f;
    #pragma unroll 8
    for (int d = 0; d < 32; ++d)
        s += Wsrc[(size_t)k * KDIM + h * 32 + d] * attn[h * 64 + aoff + d];
    vbuf[which * 2048 + h * 256 + k] = fin(s);
}

template<typename T>
__global__ void macro_dot(const T* __restrict__ A, const float* __restrict__ v0,
                          float* __restrict__ out, int N)
{
    int id = blockIdx.x * blockDim.x + threadIdx.x;
    if (id >= N * NHEAD) return;
    int n = id >> 3, h = id & 7;
    const float* vh = v0 + h * 256;
    float s = 0.f;
    if constexpr (std::is_same<T, float>::value) {
        const float* row = A + (size_t)n * KDIM;
        for (int k = 0; k < KDIM; k += 4) {
            float4 a = *reinterpret_cast<const float4*>(row + k);
            float4 b = *reinterpret_cast<const float4*>(vh + k);
            s += a.x * b.x + a.y * b.y + a.z * b.z + a.w * b.w;
        }
    } else {
        const unsigned short* row =
            reinterpret_cast<const unsigned short*>(A) + (size_t)n * KDIM;
        for (int k = 0; k < KDIM; k += 4) {
            ushort4 a = *reinterpret_cast<const ushort4*>(row + k);
            float4 b = *reinterpret_cast<const float4*>(vh + k);
            s += us2f(a.x) * b.x + us2f(a.y) * b.y + us2f(a.z) * b.z + us2f(a.w) * b.w;
        }
    }
    out[id] = fin(s);
}

__global__ void score_kernel(const float* __restrict__ dotL, const float* __restrict__ dotW,
                             const float* __restrict__ dotC,
                             float* __restrict__ ow, float* __restrict__ oc, int total)
{
    int i = blockIdx.x * blockDim.x + threadIdx.x;
    if (i >= total) return;
    float sw = dotL[i] + dotW[i]; sw = sw > 0.f ? sw : SLOPE * sw;
    float sc = dotL[i] + dotC[i]; sc = sc > 0.f ? sc : SLOPE * sc;
    float m = fmaxf(sw, sc);
    float ew = expf(sw - m), ec = expf(sc - m);
    float inv = 1.f / (ew + ec);
    ow[i] = fin(ew * inv);
    oc[i] = fin(ec * inv);
}

// ---------------------------------------------------------------------------
extern "C" void kernel_launch(void* const* d_in, const int* in_sizes, int n_in,
                              void* d_out, int out_size, void* d_ws, size_t ws_size,
                              hipStream_t stream)
{
    static const int expected[24] = {
        12800000, 12800000, 65536, 65536, 512, 512, 65536, 65536,
        65536, 65536, 65536, 512, 65536, 256, 65536, 256, 1, 1,
        400000, 400000, 400000, 400000, 400000, 400000};
    float marker = 0.f;
    if (n_in != 24) marker = 500.f;
    else {
        for (int i = 0; i < 24; ++i)
            if (in_sizes[i] != expected[i]) { marker = 200.f + 8.f * i; break; }
    }
    if (marker == 0.f && out_size != 25600000) marker = 600.f + (float)(out_size / 1000000);
    if (marker == 0.f && ws_size < 51200000ull) marker = 1000.f + (float)(ws_size / 1000000ull);
    if (marker != 0.f) {
        fill_marker<<<(out_size + 255) / 256, 256, 0, stream>>>((float*)d_out, out_size, marker);
        return;
    }

    const float* feats_a  = (const float*)d_in[0];
    const float* feats_p  = (const float*)d_in[1];
    const float* W_mic_a  = (const float*)d_in[2];
    const float* W_mic_p  = (const float*)d_in[3];
    const float* attn_a   = (const float*)d_in[4];
    const float* attn_p   = (const float*)d_in[5];
    const float* W_node_p = (const float*)d_in[7];
    const float* W_rel_w  = (const float*)d_in[8];
    const float* W_rel_wb = (const float*)d_in[9];
    const float* W_rel_c  = (const float*)d_in[10];
    const float* attn_mac = (const float*)d_in[11];
    const float* W_res_a  = (const float*)d_in[12];
    const float* b_res_a  = (const float*)d_in[13];
    const float* W_res_p  = (const float*)d_in[14];
    const float* b_res_p  = (const float*)d_in[15];
    const float* rw_a     = (const float*)d_in[16];
    const float* rw_p     = (const float*)d_in[17];
    const int* w_src  = (const int*)d_in[18];
    const int* w_dst  = (const int*)d_in[19];
    const int* wb_src = (const int*)d_in[20];
    const int* wb_dst = (const int*)d_in[21];
    const int* c_src  = (const int*)d_in[22];
    const int* c_dst  = (const int*)d_in[23];

    const int NB = N_PAPER * KDIM;            // 12.8M elems
    // ---- d_out (f32, 102.4MB): [author 51.2MB][paper 51.2MB] ----
    float* Oa_f = (float*)d_out;
    float* Op_f = Oa_f + NB;
    bf16* Oa_b = (bf16*)d_out;                // P_a -> r_written_by (author lower)
    bf16* Op_b = (bf16*)Op_f;                 // P_p -> rf_writes    (paper lower)
    char* au_up = (char*)d_out + 25600000;    // author upper 25.6MB
    bf16*  Cslot = (bf16*)au_up;              // r_cites
    bf16*  BTa0  = (bf16*)au_up;              // later: W_res_p BT (Cslot dead)
    bf16*  BTa1  = BTa0 + 65536;              //        W_rel_wb BT
    char* pu = (char*)d_out + 76800000;       // paper upper 25.6MB
    float* dotW = (float*)pu;
    float* dotC = dotW + 400000;
    float* dotL = dotW + 800000;
    float* sc_w = dotW + 1200000;
    float* sc_c = dotW + 1600000;
    float* vbuf = dotW + 2000000;             // 6144 f32
    bf16* BT0 = (bf16*)(pu + 10000000);       // early BT slots (128KB each)
    bf16* BT1 = BT0 + 65536;
    bf16* BT2 = BT1 + 65536;
    bf16* BT3 = BT2 + 65536;
    // ---- d_ws (51.2e6 B): [A_ws 25.6MB][X 25.6MB] ----
    bf16* A_ws = (bf16*)d_ws;                 // r_writes -> fused_paper
    bf16* BTw  = (bf16*)d_ws;                 // W_res_a BT (after fused dead)
    char* Xb   = (char*)d_ws + 25600000;
    float* el_w  = (float*)Xb;                // 5 x 400,000 f32 (8MB)
    float* er_w  = el_w + 400000;
    float* el_p  = el_w + 800000;
    float* er_wb = el_w + 1200000;
    float* er_c  = el_w + 1600000;
    int*  csr    = (int*)(el_w + 2000000);    // 3 x 450004 ints, 16B-aligned
    int*  Tbuf   = csr + 3 * CSR_STRIDE;      // 3 x 400000 ints (bucket-major temp)
    int*  meta   = Tbuf + 3 * NEDGE;          // 885 ints (gbcnt/bbase/grank)
    bf16* Xslot  = (bf16*)Xb;                 // later: rf_written_by (25.6MB)

    dim3 mg(2, (N_PAPER + 127) / 128);
    int hdB = (N_PAPER * NHEAD + 255) / 256;
    int gB  = (N_PAPER + 3) / 4;

    // ---- 1: micro projections (MFMA) ----
    prep_bt<<<256, 256, 0, stream>>>(W_mic_a, BT0);
    prep_bt<<<256, 256, 0, stream>>>(W_mic_p, BT1);
    mfma_gemm<0, float><<<mg, 256, 0, stream>>>(feats_a, BT0, N_AUTHOR, Oa_b,
        nullptr, nullptr, nullptr, nullptr, nullptr, nullptr);
    mfma_gemm<0, float><<<mg, 256, 0, stream>>>(feats_p, BT1, N_PAPER, Op_b,
        nullptr, nullptr, nullptr, nullptr, nullptr, nullptr);

    // ---- 2: micro attention dots ----
    head_dot<<<hdB, 256, 0, stream>>>(Oa_b, attn_a, 0,  N_AUTHOR, el_w);
    head_dot<<<hdB, 256, 0, stream>>>(Op_b, attn_a, 32, N_PAPER,  er_w);
    head_dot<<<hdB, 256, 0, stream>>>(Op_b, attn_p, 0,  N_PAPER,  el_p);
    head_dot<<<hdB, 256, 0, stream>>>(Oa_b, attn_p, 32, N_AUTHOR, er_wb);
    head_dot<<<hdB, 256, 0, stream>>>(Op_b, attn_p, 32, N_PAPER,  er_c);

    // ---- 3: bucketed CSR build + GAT gathers.
    // r0 writes: feat P_a(Oa_b) -> A_ws
    // r1 written_by: feat P_p(Op_b) -> Oa_b (P_a dead after r0 gather)
    // r2 cites: feat P_p(Op_b) -> Cslot (distinct buffer; gather forbids in-place)
    zero_meta<<<2, 256, 0, stream>>>(meta);
    bucket_count<<<dim3(64, 3), 256, 0, stream>>>(w_dst, wb_dst, c_dst, meta, NEDGE);
    bucket_scan<<<1, 192, 0, stream>>>(meta);
    bucket_scatter<<<dim3(64, 3), 256, 0, stream>>>(w_src, wb_src, c_src,
                                                    w_dst, wb_dst, c_dst,
                                                    meta, Tbuf, NEDGE);
    csr_build<<<dim3(NBUCK, 3), 256, 0, stream>>>(meta, Tbuf, csr);
    {
        const float* rel_el[3] = {el_w, el_p, el_p};
        const float* rel_er[3] = {er_w, er_wb, er_c};
        const bf16* rfeat[3]   = {Oa_b, Op_b, Op_b};
        bf16* rout[3]          = {A_ws, Oa_b, Cslot};
        for (int r = 0; r < 3; ++r) {
            int* off  = csr + r * CSR_STRIDE;
            int* gsrc = off + CSR_GSRC;
            gat_gather<<<gB, 256, 0, stream>>>(off, gsrc, rel_el[r], rel_er[r],
                                               rfeat[r], rout[r], N_PAPER);
        }
    }
    // A_ws=r_writes, Oa_b=r_written_by, Cslot=r_cites; P_p (Op_b) dead.

    // ---- 4: macro scores via vector algebra ----
    prep_v<<<24, 256, 0, stream>>>(W_rel_w, W_rel_c, W_node_p, attn_mac, vbuf);
    macro_dot<bf16><<<hdB, 256, 0, stream>>>(A_ws,  vbuf,        dotW, N_PAPER);
    macro_dot<bf16><<<hdB, 256, 0, stream>>>(Cslot, vbuf + 2048, dotC, N_PAPER);
    macro_dot<float><<<hdB, 256, 0, stream>>>(feats_p, vbuf + 4096, dotL, N_PAPER);
    score_kernel<<<hdB, 256, 0, stream>>>(dotL, dotW, dotC, sc_w, sc_c, N_PAPER * NHEAD);

    // ---- 5: rf_writes = r_writes(A_ws) @ W_rel_w -> Op_b (P_p dead) ----
    prep_bt<<<256, 256, 0, stream>>>(W_rel_w, BT2);
    mfma_gemm<0, bf16><<<mg, 256, 0, stream>>>(A_ws, BT2, N_PAPER, Op_b,
        nullptr, nullptr, nullptr, nullptr, nullptr, nullptr);
    // ---- 6: fused = sc_w*rf_writes(Op_b) + sc_c*(r_cites(Cslot) @ W_rel_c) -> A_ws ----
    prep_bt<<<256, 256, 0, stream>>>(W_rel_c, BT3);
    mfma_gemm<1, bf16><<<mg, 256, 0, stream>>>(Cslot, BT3, N_PAPER, A_ws,
        nullptr, nullptr, nullptr, Op_b, sc_w, sc_c);
    // ---- 7: paper gated residual -> Op_f FINAL (BT in au_up; Cslot dead) ----
    prep_bt<<<256, 256, 0, stream>>>(W_res_p, BTa0);
    mfma_gemm<2, float><<<mg, 256, 0, stream>>>(feats_p, BTa0, N_PAPER, Op_f,
        b_res_p, A_ws, rw_p, nullptr, nullptr, nullptr);
    // ---- 8: rf_written_by = r_written_by(Oa_b) @ W_rel_wb -> Xslot (CSR dead) ----
    prep_bt<<<256, 256, 0, stream>>>(W_rel_wb, BTa1);
    mfma_gemm<0, bf16><<<mg, 256, 0, stream>>>(Oa_b, BTa1, N_AUTHOR, Xslot,
        nullptr, nullptr, nullptr, nullptr, nullptr, nullptr);
    // ---- 9: author gated residual -> Oa_f FINAL (BT in A_ws; fused dead) ----
    prep_bt<<<256, 256, 0, stream>>>(W_res_a, BTw);
    mfma_gemm<2, float><<<mg, 256, 0, stream>>>(feats_a, BTw, N_AUTHOR, Oa_f,
        b_res_a, Xslot, rw_a, nullptr, nullptr, nullptr);
}

// Round 3
// 845.293 us; speedup vs baseline: 1.5519x; 1.1210x over previous
//
#include <hip/hip_runtime.h>
#include <hip/hip_bf16.h>
#include <type_traits>

// HGConv layer: micro (per-relation GAT) + macro (semantic attention) + gated residual.
// I/O: float32 (verified round 6). Internals: bf16 matrices, f32 accumulation.
// Round 8: edge stage scatter->gather via on-device CSR.
// Round 9: wave-shuffle scan (was 3x96us on one CU).
// Round 10: bucketed CSR build (edge_scatter3 had 14x write amplification).
// Round 11: macro_dot was 3x64.5us latency-bound (8 threads re-walk each row,
// 64-iter serial loops, VALUBusy 5.8%). Fused into macro_fused: one wave per row,
// row read once (3 vector loads), shuffle-tree head reduce, relation softmax
// in-kernel (dotW/dotC/dotL buffers + score_kernel removed). head_dot 5->2
// launches by multi-dot fusion per projection read.

#define N_AUTHOR 50000
#define N_PAPER  50000
#define NEDGE    400000
#define KDIM     256
#define NHEAD    8
#define SLOPE    0.2f

#define BUCK_W   512                    // dsts per bucket (shift 9)
#define NBUCK    98                     // ceil(50000/512)
#define SBUF_CAP 6144                   // LDS staging cap (span ~4096+-64)

// CSR slab (ints): off@0 (50001 used, pad 50004), gsrc@50004 (400000).
#define CSR_STRIDE 450004
#define CSR_GSRC   50004

using bf16 = __hip_bfloat16;
typedef __attribute__((ext_vector_type(8))) short short8;
typedef __attribute__((ext_vector_type(4))) float float4e;

__device__ __forceinline__ float us2f(unsigned short u) {
    return __uint_as_float(((unsigned int)u) << 16);
}
__device__ __forceinline__ float fin(float v) {   // 0 if NaN/Inf
    return (((__float_as_uint(v) >> 23) & 0xFF) != 0xFF) ? v : 0.f;
}
__device__ __forceinline__ unsigned short f2bu(float f) {
    f = fin(f);
    bf16 h = __float2bfloat16(f);
    return *reinterpret_cast<unsigned short*>(&h);
}
__device__ __forceinline__ int clampi(int v, int hi) {
    return v < 0 ? 0 : (v >= hi ? hi - 1 : v);
}

__global__ void fill_marker(float* __restrict__ out, int total, float c)
{
    int i = blockIdx.x * blockDim.x + threadIdx.x;
    if (i < total) out[i] = c;
}

// ---------------------------------------------------------------------------
// W[256k][256n] f32  ->  BT[256n][256k] bf16  (pre-transpose for MFMA B-frags)
// ---------------------------------------------------------------------------
__global__ void prep_bt(const float* __restrict__ W, bf16* __restrict__ BT)
{
    int n = blockIdx.x, k = threadIdx.x;
    reinterpret_cast<unsigned short*>(BT)[n * KDIM + k] = f2bu(W[k * KDIM + n]);
}

// ---------------------------------------------------------------------------
// MFMA GEMM: C[M x 256] = A[M x 256] @ B (BT = B^T bf16 [n][k]), f32 acc.
// 128x128 tile, BK=32, 256 threads = 4 waves (2x2 of 64x64), 4x4 frags/wave.
// MODE 0: C(bf16) = acc
// MODE 1: C(bf16) = sc_w[n,h]*rfw + sc_c[n,h]*acc      (paper fusion epilogue)
// MODE 2: C(f32)  = sig(g)*other(bf16) + (1-sig(g))*(acc + bias)  (residual)
// ---------------------------------------------------------------------------
template<int MODE, typename TA>
__global__ __launch_bounds__(256) void mfma_gemm(
    const TA* __restrict__ A, const bf16* __restrict__ BT, int M,
    void* __restrict__ Cout,
    const float* __restrict__ bias, const bf16* __restrict__ other,
    const float* __restrict__ gate,
    const bf16* __restrict__ rfw, const float* __restrict__ sc_w,
    const float* __restrict__ sc_c)
{
    __shared__ short As[128 * 40];   // [row][k], pad 32->40
    __shared__ short Bs[128 * 40];   // [n][k]
    const int tid = threadIdx.x;
    const int lane = tid & 63, wave = tid >> 6;
    const int wm = wave >> 1, wn = wave & 1;
    const int rowBase = blockIdx.y * 128;
    const int colBase = blockIdx.x * 128;

    float4e acc[4][4];
    #pragma unroll
    for (int i = 0; i < 4; ++i)
        #pragma unroll
        for (int j = 0; j < 4; ++j) {
            float4e z = {0.f, 0.f, 0.f, 0.f};
            acc[i][j] = z;
        }

    const int srow = tid >> 2;          // 0..63
    const int sq = (tid & 3) << 3;      // 0,8,16,24

    for (int kt = 0; kt < KDIM; kt += 32) {
        #pragma unroll
        for (int p = 0; p < 2; ++p) {
            int r = srow + p * 64;
            int gr = rowBase + r;
            short8 v = {0, 0, 0, 0, 0, 0, 0, 0};
            if (gr < M) {
                if constexpr (std::is_same<TA, float>::value) {
                    const float* ap = A + (size_t)gr * KDIM + kt + sq;
                    float4 x = *reinterpret_cast<const float4*>(ap);
                    float4 y = *reinterpret_cast<const float4*>(ap + 4);
                    v[0] = (short)f2bu(x.x); v[1] = (short)f2bu(x.y);
                    v[2] = (short)f2bu(x.z); v[3] = (short)f2bu(x.w);
                    v[4] = (short)f2bu(y.x); v[5] = (short)f2bu(y.y);
                    v[6] = (short)f2bu(y.z); v[7] = (short)f2bu(y.w);
                } else {
                    v = *reinterpret_cast<const short8*>(
                        reinterpret_cast<const short*>(A) + (size_t)gr * KDIM + kt + sq);
                }
            }
            *reinterpret_cast<short8*>(&As[r * 40 + sq]) = v;
        }
        #pragma unroll
        for (int p = 0; p < 2; ++p) {
            int n = srow + p * 64;
            short8 v = *reinterpret_cast<const short8*>(
                reinterpret_cast<const short*>(BT) + (size_t)(colBase + n) * KDIM + kt + sq);
            *reinterpret_cast<short8*>(&Bs[n * 40 + sq]) = v;
        }
        __syncthreads();

        short8 af[4], bg[4];
        #pragma unroll
        for (int i = 0; i < 4; ++i)
            af[i] = *reinterpret_cast<const short8*>(
                &As[(wm * 64 + i * 16 + (lane & 15)) * 40 + ((lane >> 4) << 3)]);
        #pragma unroll
        for (int j = 0; j < 4; ++j)
            bg[j] = *reinterpret_cast<const short8*>(
                &Bs[(wn * 64 + j * 16 + (lane & 15)) * 40 + ((lane >> 4) << 3)]);
        #pragma unroll
        for (int i = 0; i < 4; ++i)
            #pragma unroll
            for (int j = 0; j < 4; ++j)
                acc[i][j] = __builtin_amdgcn_mfma_f32_16x16x32_bf16(
                    af[i], bg[j], acc[i][j], 0, 0, 0);
        __syncthreads();
    }

    float al = 0.f;
    if constexpr (MODE == 2) al = 1.f / (1.f + expf(-gate[0]));

    #pragma unroll
    for (int i = 0; i < 4; ++i) {
        int r0 = rowBase + wm * 64 + i * 16 + ((lane >> 4) << 2);
        #pragma unroll
        for (int j = 0; j < 4; ++j) {
            int col = colBase + wn * 64 + j * 16 + (lane & 15);
            #pragma unroll
            for (int reg = 0; reg < 4; ++reg) {
                int row = r0 + reg;
                if (row < M) {
                    size_t idx = (size_t)row * KDIM + col;
                    float v = acc[i][j][reg];
                    if constexpr (MODE == 0) {
                        reinterpret_cast<unsigned short*>(Cout)[idx] = f2bu(v);
                    } else if constexpr (MODE == 1) {
                        int h = col >> 5;
                        size_t si = (size_t)row * NHEAD + h;
                        float f = sc_w[si] * us2f(reinterpret_cast<const unsigned short*>(rfw)[idx])
                                + sc_c[si] * v;
                        reinterpret_cast<unsigned short*>(Cout)[idx] = f2bu(f);
                    } else {
                        float of = us2f(reinterpret_cast<const unsigned short*>(other)[idx]);
                        reinterpret_cast<float*>(Cout)[idx] =
                            fin(al * of + (1.f - al) * (v + bias[col]));
                    }
                }
            }
        }
    }
}

// ---------------------------------------------------------------------------
// Per-node per-head attention dots (micro): one projection-row read, 2-3 dots.
// ---------------------------------------------------------------------------
__global__ void head_dot2(const bf16* __restrict__ proj,
                          const float* __restrict__ aA, int offA, float* __restrict__ oA,
                          const float* __restrict__ aB, int offB, float* __restrict__ oB,
                          int N)
{
    int gid = blockIdx.x * blockDim.x + threadIdx.x;
    if (gid >= N * NHEAD) return;
    int n = gid >> 3, k = gid & 7;
    const unsigned short* p =
        reinterpret_cast<const unsigned short*>(proj) + (size_t)n * KDIM + k * 32;
    const float* a = aA + k * 64 + offA;
    const float* b = aB + k * 64 + offB;
    float sA = 0.f, sB = 0.f;
    #pragma unroll
    for (int d0 = 0; d0 < 32; d0 += 4) {
        ushort4 pv = *reinterpret_cast<const ushort4*>(p + d0);
        float4 av = *reinterpret_cast<const float4*>(a + d0);
        float4 bv = *reinterpret_cast<const float4*>(b + d0);
        float f0 = us2f(pv.x), f1 = us2f(pv.y), f2 = us2f(pv.z), f3 = us2f(pv.w);
        sA += f0 * av.x + f1 * av.y + f2 * av.z + f3 * av.w;
        sB += f0 * bv.x + f1 * bv.y + f2 * bv.z + f3 * bv.w;
    }
    oA[gid] = fin(sA);
    oB[gid] = fin(sB);
}

__global__ void head_dot3(const bf16* __restrict__ proj,
                          const float* __restrict__ aA, int offA, float* __restrict__ oA,
                          const float* __restrict__ aB, int offB, float* __restrict__ oB,
                          const float* __restrict__ aC, int offC, float* __restrict__ oC,
                          int N)
{
    int gid = blockIdx.x * blockDim.x + threadIdx.x;
    if (gid >= N * NHEAD) return;
    int n = gid >> 3, k = gid & 7;
    const unsigned short* p =
        reinterpret_cast<const unsigned short*>(proj) + (size_t)n * KDIM + k * 32;
    const float* a = aA + k * 64 + offA;
    const float* b = aB + k * 64 + offB;
    const float* c = aC + k * 64 + offC;
    float sA = 0.f, sB = 0.f, sC = 0.f;
    #pragma unroll
    for (int d0 = 0; d0 < 32; d0 += 4) {
        ushort4 pv = *reinterpret_cast<const ushort4*>(p + d0);
        float4 av = *reinterpret_cast<const float4*>(a + d0);
        float4 bv = *reinterpret_cast<const float4*>(b + d0);
        float4 cv = *reinterpret_cast<const float4*>(c + d0);
        float f0 = us2f(pv.x), f1 = us2f(pv.y), f2 = us2f(pv.z), f3 = us2f(pv.w);
        sA += f0 * av.x + f1 * av.y + f2 * av.z + f3 * av.w;
        sB += f0 * bv.x + f1 * bv.y + f2 * bv.z + f3 * bv.w;
        sC += f0 * cv.x + f1 * cv.y + f2 * cv.z + f3 * cv.w;
    }
    oA[gid] = fin(sA);
    oB[gid] = fin(sB);
    oC[gid] = fin(sC);
}

// ---------------------------------------------------------------------------
// Bucketed CSR build (relation = blockIdx.y).
// meta layout (ints): gbcnt[3][NBUCK] @0, bbase[3][NBUCK+1] @294, grank[3][NBUCK] @591
// ---------------------------------------------------------------------------
__global__ void zero_meta(int* __restrict__ meta)
{
    int i = threadIdx.x + blockIdx.x * blockDim.x;
    if (i < 3 * NBUCK) meta[i] = 0;                       // gbcnt
    if (i < 3 * NBUCK) meta[591 + i] = 0;                 // grank
}

__global__ __launch_bounds__(256) void bucket_count(
    const int* __restrict__ d0, const int* __restrict__ d1,
    const int* __restrict__ d2, int* __restrict__ meta, int E)
{
    __shared__ int cnt[NBUCK];
    for (int i = threadIdx.x; i < NBUCK; i += 256) cnt[i] = 0;
    __syncthreads();
    int r = blockIdx.y;
    const int* d = r == 0 ? d0 : (r == 1 ? d1 : d2);
    for (int e = blockIdx.x * 256 + threadIdx.x; e < E; e += gridDim.x * 256)
        atomicAdd(&cnt[clampi(d[e], N_PAPER) >> 9], 1);
    __syncthreads();
    for (int i = threadIdx.x; i < NBUCK; i += 256)
        if (cnt[i]) atomicAdd(&meta[r * NBUCK + i], cnt[i]);
}

// 3 waves, one per relation: shuffle-scan NBUCK bucket counts -> bases.
__global__ void bucket_scan(int* __restrict__ meta)
{
    int r = threadIdx.x >> 6, lane = threadIdx.x & 63;
    if (r >= 3) return;
    const int* gbcnt = meta + r * NBUCK;
    int* bbase = meta + 294 + r * (NBUCK + 1);
    int carry = 0;
    for (int base = 0; base < NBUCK; base += 64) {
        int i = base + lane;
        int v = (i < NBUCK) ? gbcnt[i] : 0;
        int x = v;
        #pragma unroll
        for (int o = 1; o < 64; o <<= 1) {
            int t = __shfl_up(x, o, 64);
            if (lane >= o) x += t;
        }
        if (i < NBUCK) bbase[i] = carry + x - v;
        carry += __shfl(x, 63, 64);
    }
    if (lane == 0) bbase[NBUCK] = carry;
}

// Scatter edges into bucket-major temp T, packed (src<<9)|dlocal (25 bits).
// 64 fixed chunks/relation; per-(block,bucket) runs ~64 edges = 256B contiguous.
__global__ __launch_bounds__(256) void bucket_scatter(
    const int* __restrict__ s0, const int* __restrict__ s1,
    const int* __restrict__ s2,
    const int* __restrict__ d0, const int* __restrict__ d1,
    const int* __restrict__ d2,
    int* __restrict__ meta, int* __restrict__ T, int E)
{
    __shared__ int cnt[NBUCK];
    __shared__ int base[NBUCK];
    int r = blockIdx.y;
    const int* s = r == 0 ? s0 : (r == 1 ? s1 : s2);
    const int* d = r == 0 ? d0 : (r == 1 ? d1 : d2);
    const int* bbase = meta + 294 + r * (NBUCK + 1);
    int* grank = meta + 591 + r * NBUCK;
    int* Tr = T + r * NEDGE;

    for (int i = threadIdx.x; i < NBUCK; i += 256) cnt[i] = 0;
    __syncthreads();

    const int CH = (E + gridDim.x - 1) / gridDim.x;
    int e0 = blockIdx.x * CH;
    int e1 = min(e0 + CH, E);
    for (int e = e0 + threadIdx.x; e < e1; e += 256)
        atomicAdd(&cnt[clampi(d[e], N_PAPER) >> 9], 1);
    __syncthreads();
    if (threadIdx.x < NBUCK) {
        int c = cnt[threadIdx.x];
        base[threadIdx.x] = c ? bbase[threadIdx.x] + atomicAdd(&grank[threadIdx.x], c) : 0;
        cnt[threadIdx.x] = 0;            // reuse as local rank
    }
    __syncthreads();
    for (int e = e0 + threadIdx.x; e < e1; e += 256) {
        int dc = clampi(d[e], N_PAPER);
        int b = dc >> 9, dl = dc & 511;
        int l = atomicAdd(&cnt[b], 1);
        Tr[base[b] + l] = (clampi(s[e], N_PAPER) << 9) | dl;
    }
}

// Per (bucket, relation): LDS per-dst hist + scan -> off[] (coalesced), then
// LDS scatter + coalesced gsrc stream-out. Replaces global hist/scan/scatter.
__global__ __launch_bounds__(256) void csr_build(
    const int* __restrict__ meta, const int* __restrict__ T,
    int* __restrict__ csr)
{
    __shared__ int cnt[512];
    __shared__ int loc[512];
    __shared__ int sbuf[SBUF_CAP];
    __shared__ int wtot[4];
    int b = blockIdx.x, r = blockIdx.y;
    const int* bbase = meta + 294 + r * (NBUCK + 1);
    const int* Tr = T + r * NEDGE;
    int* off = csr + r * CSR_STRIDE;
    int* gsrc = off + CSR_GSRC;
    const int tid = threadIdx.x, lane = tid & 63, wv = tid >> 6;

    int dstbase = b << 9;
    int nd = min(512, N_PAPER - dstbase);
    int cbase = bbase[b], cend = bbase[b + 1];
    int span = cend - cbase;

    cnt[2 * tid] = 0; cnt[2 * tid + 1] = 0;
    __syncthreads();
    for (int t = tid; t < span; t += 256)
        atomicAdd(&cnt[Tr[cbase + t] & 511], 1);
    __syncthreads();

    // exclusive scan of cnt[0..512) (2 elems/thread, wave shuffle + LDS combine)
    int v0 = cnt[2 * tid], v1 = cnt[2 * tid + 1];
    int sthr = v0 + v1;
    int x = sthr;
    #pragma unroll
    for (int o = 1; o < 64; o <<= 1) {
        int t = __shfl_up(x, o, 64);
        if (lane >= o) x += t;
    }
    if (lane == 63) wtot[wv] = x;
    __syncthreads();
    int wexc = 0;
    #pragma unroll
    for (int w = 0; w < 4; ++w)
        if (w < wv) wexc += wtot[w];
    int exc = wexc + x - sthr;
    loc[2 * tid] = exc;
    loc[2 * tid + 1] = exc + v0;
    int i0 = 2 * tid, i1 = 2 * tid + 1;
    if (i0 < nd) off[dstbase + i0] = cbase + exc;
    if (i1 < nd) off[dstbase + i1] = cbase + exc + v0;
    if (b == NBUCK - 1 && tid == 0) off[N_PAPER] = cend;
    cnt[i0] = 0; cnt[i1] = 0;            // reuse as per-dst rank
    __syncthreads();

    if (span <= SBUF_CAP) {
        for (int t = tid; t < span; t += 256) {
            int v = Tr[cbase + t];
            int dl = v & 511;
            int pos = loc[dl] + atomicAdd(&cnt[dl], 1);
            sbuf[pos] = v >> 9;
        }
        __syncthreads();
        for (int t = tid; t < span; t += 256)
            gsrc[cbase + t] = sbuf[t];
    } else {                              // never expected; correctness fallback
        for (int t = tid; t < span; t += 256) {
            int v = Tr[cbase + t];
            int dl = v & 511;
            int pos = loc[dl] + atomicAdd(&cnt[dl], 1);
            gsrc[cbase + pos] = v >> 9;
        }
    }
}

// ---------------------------------------------------------------------------
// GAT gather: one wave per dst node; lane covers 4 cols, head = lane>>3.
// Single pass (linearity): ft = relu( (sum_e ex_e * feat[src_e]) / sum_e ex_e ).
// No atomics; fused softmax + aggregate + relu + bf16 cast.
// ---------------------------------------------------------------------------
__global__ __launch_bounds__(256) void gat_gather(
    const int* __restrict__ off, const int* __restrict__ gsrc,
    const float* __restrict__ el, const float* __restrict__ er,
    const bf16* __restrict__ feat, bf16* __restrict__ out, int N)
{
    int d = blockIdx.x * 4 + (threadIdx.x >> 6);
    if (d >= N) return;
    int lane = threadIdx.x & 63;
    int h = lane >> 3;
    int col = lane * 4;
    float erd = er[d * NHEAD + h];
    int e0 = off[d], e1 = off[d + 1];
    float denom = 0.f, a0 = 0.f, a1 = 0.f, a2 = 0.f, a3 = 0.f;
    for (int e = e0; e < e1; ++e) {
        int s = gsrc[e];
        float v = el[s * NHEAD + h] + erd;
        v = v > 0.f ? v : SLOPE * v;
        float ex = expf(fminf(v, 30.f));
        denom += ex;
        ushort4 fv = *reinterpret_cast<const ushort4*>(
            reinterpret_cast<const unsigned short*>(feat) + (size_t)s * KDIM + col);
        a0 = fmaf(us2f(fv.x), ex, a0); a1 = fmaf(us2f(fv.y), ex, a1);
        a2 = fmaf(us2f(fv.z), ex, a2); a3 = fmaf(us2f(fv.w), ex, a3);
    }
    float inv = 1.f / fmaxf(denom, 1e-20f);
    ushort4 o;
    o.x = f2bu(fmaxf(a0 * inv, 0.f)); o.y = f2bu(fmaxf(a1 * inv, 0.f));
    o.z = f2bu(fmaxf(a2 * inv, 0.f)); o.w = f2bu(fmaxf(a3 * inv, 0.f));
    *reinterpret_cast<ushort4*>(
        reinterpret_cast<unsigned short*>(out) + (size_t)d * KDIM + col) = o;
}

// ---------------------------------------------------------------------------
// Macro: prep_v score vectors, then fused per-row dots + relation softmax.
// ---------------------------------------------------------------------------
__global__ void prep_v(const float* __restrict__ Ww, const float* __restrict__ Wc,
                       const float* __restrict__ Wn, const float* __restrict__ attn,
                       float* __restrict__ vbuf)
{
    int id = blockIdx.x * blockDim.x + threadIdx.x;
    if (id >= 3 * 2048) return;
    int which = id >> 11;
    int rem = id & 2047;
    int h = rem >> 8, k = rem & 255;
    const float* Wsrc = which == 0 ? Ww : (which == 1 ? Wc : Wn);
    int aoff = which == 2 ? 0 : 32;
    float s = 0.f;
    #pragma unroll 8
    for (int d = 0; d < 32; ++d)
        s += Wsrc[(size_t)k * KDIM + h * 32 + d] * attn[h * 64 + aoff + d];
    vbuf[which * 2048 + h * 256 + k] = fin(s);
}

__device__ __forceinline__ float sel8(const float p[8], int j)
{
    float q = p[0];
    q = j == 1 ? p[1] : q; q = j == 2 ? p[2] : q; q = j == 3 ? p[3] : q;
    q = j == 4 ? p[4] : q; q = j == 5 ? p[5] : q; q = j == 6 ? p[6] : q;
    q = j == 7 ? p[7] : q;
    return q;
}

// 2-phase reduce: xor{1,2,4} per head, select head (lane&7), xor{8,16,32}.
// Every lane ends with the row total for head (lane&7).
__device__ __forceinline__ float head_reduce(float p[8], int lane)
{
    #pragma unroll
    for (int h = 0; h < 8; ++h) {
        p[h] += __shfl_xor(p[h], 1);
        p[h] += __shfl_xor(p[h], 2);
        p[h] += __shfl_xor(p[h], 4);
    }
    float q = sel8(p, lane & 7);
    q += __shfl_xor(q, 8);
    q += __shfl_xor(q, 16);
    q += __shfl_xor(q, 32);
    return q;
}

// One wave per paper row: read A_ws/Cslot rows (bf16) + feats_p row (f32) once,
// 8 head-dots each vs LDS-staged v-vectors, relation softmax in-register.
__global__ __launch_bounds__(256) void macro_fused(
    const bf16* __restrict__ Aw, const bf16* __restrict__ Ac,
    const float* __restrict__ Af, const float* __restrict__ vbuf,
    float* __restrict__ sc_w, float* __restrict__ sc_c, int N)
{
    __shared__ float vlds[6144];
    #pragma unroll
    for (int i = 0; i < 6; ++i) {
        int idx = (i * 256 + threadIdx.x) * 4;
        *reinterpret_cast<float4*>(&vlds[idx]) =
            *reinterpret_cast<const float4*>(&vbuf[idx]);
    }
    __syncthreads();
    int n = blockIdx.x * 4 + (threadIdx.x >> 6);
    if (n >= N) return;
    int lane = threadIdx.x & 63;
    int col = lane * 4;
    ushort4 awv = *reinterpret_cast<const ushort4*>(
        reinterpret_cast<const unsigned short*>(Aw) + (size_t)n * KDIM + col);
    ushort4 acv = *reinterpret_cast<const ushort4*>(
        reinterpret_cast<const unsigned short*>(Ac) + (size_t)n * KDIM + col);
    float4 afv = *reinterpret_cast<const float4*>(Af + (size_t)n * KDIM + col);
    float w0 = us2f(awv.x), w1 = us2f(awv.y), w2 = us2f(awv.z), w3 = us2f(awv.w);
    float c0 = us2f(acv.x), c1 = us2f(acv.y), c2 = us2f(acv.z), c3 = us2f(acv.w);
    float pW[8], pC[8], pL[8];
    #pragma unroll
    for (int h = 0; h < 8; ++h) {
        float4 vW = *reinterpret_cast<const float4*>(&vlds[h * 256 + col]);
        float4 vC = *reinterpret_cast<const float4*>(&vlds[2048 + h * 256 + col]);
        float4 vL = *reinterpret_cast<const float4*>(&vlds[4096 + h * 256 + col]);
        pW[h] = w0 * vW.x + w1 * vW.y + w2 * vW.z + w3 * vW.w;
        pC[h] = c0 * vC.x + c1 * vC.y + c2 * vC.z + c3 * vC.w;
        pL[h] = afv.x * vL.x + afv.y * vL.y + afv.z * vL.z + afv.w * vL.w;
    }
    float dW = fin(head_reduce(pW, lane));
    float dC = fin(head_reduce(pC, lane));
    float dL = fin(head_reduce(pL, lane));
    if (lane < 8) {
        float sw = dL + dW; sw = sw > 0.f ? sw : SLOPE * sw;
        float sc = dL + dC; sc = sc > 0.f ? sc : SLOPE * sc;
        float m = fmaxf(sw, sc);
        float ew = expf(sw - m), ec = expf(sc - m);
        float inv = 1.f / (ew + ec);
        sc_w[n * NHEAD + lane] = fin(ew * inv);
        sc_c[n * NHEAD + lane] = fin(ec * inv);
    }
}

// ---------------------------------------------------------------------------
extern "C" void kernel_launch(void* const* d_in, const int* in_sizes, int n_in,
                              void* d_out, int out_size, void* d_ws, size_t ws_size,
                              hipStream_t stream)
{
    static const int expected[24] = {
        12800000, 12800000, 65536, 65536, 512, 512, 65536, 65536,
        65536, 65536, 65536, 512, 65536, 256, 65536, 256, 1, 1,
        400000, 400000, 400000, 400000, 400000, 400000};
    float marker = 0.f;
    if (n_in != 24) marker = 500.f;
    else {
        for (int i = 0; i < 24; ++i)
            if (in_sizes[i] != expected[i]) { marker = 200.f + 8.f * i; break; }
    }
    if (marker == 0.f && out_size != 25600000) marker = 600.f + (float)(out_size / 1000000);
    if (marker == 0.f && ws_size < 51200000ull) marker = 1000.f + (float)(ws_size / 1000000ull);
    if (marker != 0.f) {
        fill_marker<<<(out_size + 255) / 256, 256, 0, stream>>>((float*)d_out, out_size, marker);
        return;
    }

    const float* feats_a  = (const float*)d_in[0];
    const float* feats_p  = (const float*)d_in[1];
    const float* W_mic_a  = (const float*)d_in[2];
    const float* W_mic_p  = (const float*)d_in[3];
    const float* attn_a   = (const float*)d_in[4];
    const float* attn_p   = (const float*)d_in[5];
    const float* W_node_p = (const float*)d_in[7];
    const float* W_rel_w  = (const float*)d_in[8];
    const float* W_rel_wb = (const float*)d_in[9];
    const float* W_rel_c  = (const float*)d_in[10];
    const float* attn_mac = (const float*)d_in[11];
    const float* W_res_a  = (const float*)d_in[12];
    const float* b_res_a  = (const float*)d_in[13];
    const float* W_res_p  = (const float*)d_in[14];
    const float* b_res_p  = (const float*)d_in[15];
    const float* rw_a     = (const float*)d_in[16];
    const float* rw_p     = (const float*)d_in[17];
    const int* w_src  = (const int*)d_in[18];
    const int* w_dst  = (const int*)d_in[19];
    const int* wb_src = (const int*)d_in[20];
    const int* wb_dst = (const int*)d_in[21];
    const int* c_src  = (const int*)d_in[22];
    const int* c_dst  = (const int*)d_in[23];

    const int NB = N_PAPER * KDIM;            // 12.8M elems
    // ---- d_out (f32, 102.4MB): [author 51.2MB][paper 51.2MB] ----
    float* Oa_f = (float*)d_out;
    float* Op_f = Oa_f + NB;
    bf16* Oa_b = (bf16*)d_out;                // P_a -> r_written_by (author lower)
    bf16* Op_b = (bf16*)Op_f;                 // P_p -> rf_writes    (paper lower)
    char* au_up = (char*)d_out + 25600000;    // author upper 25.6MB
    bf16*  Cslot = (bf16*)au_up;              // r_cites
    bf16*  BTa0  = (bf16*)au_up;              // later: W_res_p BT (Cslot dead)
    bf16*  BTa1  = BTa0 + 65536;              //        W_rel_wb BT
    char* pu = (char*)d_out + 76800000;       // paper upper 25.6MB
    float* sc_w = (float*)pu + 1200000;
    float* sc_c = (float*)pu + 1600000;
    float* vbuf = (float*)pu + 2000000;       // 6144 f32
    bf16* BT0 = (bf16*)(pu + 10000000);       // early BT slots (128KB each)
    bf16* BT1 = BT0 + 65536;
    bf16* BT2 = BT1 + 65536;
    bf16* BT3 = BT2 + 65536;
    // ---- d_ws (51.2e6 B): [A_ws 25.6MB][X 25.6MB] ----
    bf16* A_ws = (bf16*)d_ws;                 // r_writes -> fused_paper
    bf16* BTw  = (bf16*)d_ws;                 // W_res_a BT (after fused dead)
    char* Xb   = (char*)d_ws + 25600000;
    float* el_w  = (float*)Xb;                // 5 x 400,000 f32 (8MB)
    float* er_w  = el_w + 400000;
    float* el_p  = el_w + 800000;
    float* er_wb = el_w + 1200000;
    float* er_c  = el_w + 1600000;
    int*  csr    = (int*)(el_w + 2000000);    // 3 x 450004 ints, 16B-aligned
    int*  Tbuf   = csr + 3 * CSR_STRIDE;      // 3 x 400000 ints (bucket-major temp)
    int*  meta   = Tbuf + 3 * NEDGE;          // 885 ints (gbcnt/bbase/grank)
    bf16* Xslot  = (bf16*)Xb;                 // later: rf_written_by (25.6MB)

    dim3 mg(2, (N_PAPER + 127) / 128);
    int hdB = (N_PAPER * NHEAD + 255) / 256;
    int gB  = (N_PAPER + 3) / 4;

    // ---- 1: micro projections (MFMA) ----
    prep_bt<<<256, 256, 0, stream>>>(W_mic_a, BT0);
    prep_bt<<<256, 256, 0, stream>>>(W_mic_p, BT1);
    mfma_gemm<0, float><<<mg, 256, 0, stream>>>(feats_a, BT0, N_AUTHOR, Oa_b,
        nullptr, nullptr, nullptr, nullptr, nullptr, nullptr);
    mfma_gemm<0, float><<<mg, 256, 0, stream>>>(feats_p, BT1, N_PAPER, Op_b,
        nullptr, nullptr, nullptr, nullptr, nullptr, nullptr);

    // ---- 2: micro attention dots (fused per projection read) ----
    head_dot2<<<hdB, 256, 0, stream>>>(Oa_b, attn_a, 0, el_w,
                                       attn_p, 32, er_wb, N_AUTHOR);
    head_dot3<<<hdB, 256, 0, stream>>>(Op_b, attn_a, 32, er_w,
                                       attn_p, 0, el_p,
                                       attn_p, 32, er_c, N_PAPER);

    // ---- 3: bucketed CSR build + GAT gathers.
    // r0 writes: feat P_a(Oa_b) -> A_ws
    // r1 written_by: feat P_p(Op_b) -> Oa_b (P_a dead after r0 gather)
    // r2 cites: feat P_p(Op_b) -> Cslot (distinct buffer; gather forbids in-place)
    zero_meta<<<2, 256, 0, stream>>>(meta);
    bucket_count<<<dim3(64, 3), 256, 0, stream>>>(w_dst, wb_dst, c_dst, meta, NEDGE);
    bucket_scan<<<1, 192, 0, stream>>>(meta);
    bucket_scatter<<<dim3(64, 3), 256, 0, stream>>>(w_src, wb_src, c_src,
                                                    w_dst, wb_dst, c_dst,
                                                    meta, Tbuf, NEDGE);
    csr_build<<<dim3(NBUCK, 3), 256, 0, stream>>>(meta, Tbuf, csr);
    {
        const float* rel_el[3] = {el_w, el_p, el_p};
        const float* rel_er[3] = {er_w, er_wb, er_c};
        const bf16* rfeat[3]   = {Oa_b, Op_b, Op_b};
        bf16* rout[3]          = {A_ws, Oa_b, Cslot};
        for (int r = 0; r < 3; ++r) {
            int* off  = csr + r * CSR_STRIDE;
            int* gsrc = off + CSR_GSRC;
            gat_gather<<<gB, 256, 0, stream>>>(off, gsrc, rel_el[r], rel_er[r],
                                               rfeat[r], rout[r], N_PAPER);
        }
    }
    // A_ws=r_writes, Oa_b=r_written_by, Cslot=r_cites; P_p (Op_b) dead.

    // ---- 4: macro scores, fused (rows read once; softmax in-kernel) ----
    prep_v<<<24, 256, 0, stream>>>(W_rel_w, W_rel_c, W_node_p, attn_mac, vbuf);
    macro_fused<<<gB, 256, 0, stream>>>(A_ws, Cslot, feats_p, vbuf,
                                        sc_w, sc_c, N_PAPER);

    // ---- 5: rf_writes = r_writes(A_ws) @ W_rel_w -> Op_b (P_p dead) ----
    prep_bt<<<256, 256, 0, stream>>>(W_rel_w, BT2);
    mfma_gemm<0, bf16><<<mg, 256, 0, stream>>>(A_ws, BT2, N_PAPER, Op_b,
        nullptr, nullptr, nullptr, nullptr, nullptr, nullptr);
    // ---- 6: fused = sc_w*rf_writes(Op_b) + sc_c*(r_cites(Cslot) @ W_rel_c) -> A_ws ----
    prep_bt<<<256, 256, 0, stream>>>(W_rel_c, BT3);
    mfma_gemm<1, bf16><<<mg, 256, 0, stream>>>(Cslot, BT3, N_PAPER, A_ws,
        nullptr, nullptr, nullptr, Op_b, sc_w, sc_c);
    // ---- 7: paper gated residual -> Op_f FINAL (BT in au_up; Cslot dead) ----
    prep_bt<<<256, 256, 0, stream>>>(W_res_p, BTa0);
    mfma_gemm<2, float><<<mg, 256, 0, stream>>>(feats_p, BTa0, N_PAPER, Op_f,
        b_res_p, A_ws, rw_p, nullptr, nullptr, nullptr);
    // ---- 8: rf_written_by = r_written_by(Oa_b) @ W_rel_wb -> Xslot (CSR dead) ----
    prep_bt<<<256, 256, 0, stream>>>(W_rel_wb, BTa1);
    mfma_gemm<0, bf16><<<mg, 256, 0, stream>>>(Oa_b, BTa1, N_AUTHOR, Xslot,
        nullptr, nullptr, nullptr, nullptr, nullptr, nullptr);
    // ---- 9: author gated residual -> Oa_f FINAL (BT in A_ws; fused dead) ----
    prep_bt<<<256, 256, 0, stream>>>(W_res_a, BTw);
    mfma_gemm<2, float><<<mg, 256, 0, stream>>>(feats_a, BTw, N_AUTHOR, Oa_f,
        b_res_a, Xslot, rw_a, nullptr, nullptr, nullptr);
}

// Round 5
// 834.034 us; speedup vs baseline: 1.5729x; 1.0135x over previous
//
#include <hip/hip_runtime.h>
#include <hip/hip_bf16.h>
#include <type_traits>

// HGConv layer: micro (per-relation GAT) + macro (semantic attention) + gated residual.
// I/O: float32 (verified round 6). Internals: bf16 matrices, f32 accumulation.
// Round 8: edge stage scatter->gather via on-device CSR.
// Round 9: wave-shuffle scan (was 3x96us on one CU).
// Round 10: bucketed CSR build (edge_scatter3 had 14x write amplification).
// Round 11: macro_dot fused into macro_fused (one wave/row, shuffle-tree reduce).
// Round 12: macro_fused was 85us BW-bound: its 102MB read stream flushed 300MB
// of dirty L3 lines (WRITE_SIZE=302MB vs 3.2MB own writes). Killed the stream:
// dotW/dotC now computed in gat_gather's epilogue (row already in registers),
// dotL via nontemporal-load pass over feats_p (no L3 pollution), tiny
// score_kernel recombines. macro_fused removed.
// Round 13: fix nontemporal builtin type (ext_vector float4e, not HIP float4).

#define N_AUTHOR 50000
#define N_PAPER  50000
#define NEDGE    400000
#define KDIM     256
#define NHEAD    8
#define SLOPE    0.2f

#define BUCK_W   512                    // dsts per bucket (shift 9)
#define NBUCK    98                     // ceil(50000/512)
#define SBUF_CAP 6144                   // LDS staging cap (span ~4096+-64)

// CSR slab (ints): off@0 (50001 used, pad 50004), gsrc@50004 (400000).
#define CSR_STRIDE 450004
#define CSR_GSRC   50004

using bf16 = __hip_bfloat16;
typedef __attribute__((ext_vector_type(8))) short short8;
typedef __attribute__((ext_vector_type(4))) float float4e;

__device__ __forceinline__ float us2f(unsigned short u) {
    return __uint_as_float(((unsigned int)u) << 16);
}
__device__ __forceinline__ float fin(float v) {   // 0 if NaN/Inf
    return (((__float_as_uint(v) >> 23) & 0xFF) != 0xFF) ? v : 0.f;
}
__device__ __forceinline__ unsigned short f2bu(float f) {
    f = fin(f);
    bf16 h = __float2bfloat16(f);
    return *reinterpret_cast<unsigned short*>(&h);
}
__device__ __forceinline__ int clampi(int v, int hi) {
    return v < 0 ? 0 : (v >= hi ? hi - 1 : v);
}

__global__ void fill_marker(float* __restrict__ out, int total, float c)
{
    int i = blockIdx.x * blockDim.x + threadIdx.x;
    if (i < total) out[i] = c;
}

// ---------------------------------------------------------------------------
// Shuffle-tree head reduce: xor{1,2,4} per head (8-lane col group), select head
// (lane&7), xor{8,16,32} across groups. Every lane ends with head (lane&7)'s
// full row sum.
// ---------------------------------------------------------------------------
__device__ __forceinline__ float sel8(const float p[8], int j)
{
    float q = p[0];
    q = j == 1 ? p[1] : q; q = j == 2 ? p[2] : q; q = j == 3 ? p[3] : q;
    q = j == 4 ? p[4] : q; q = j == 5 ? p[5] : q; q = j == 6 ? p[6] : q;
    q = j == 7 ? p[7] : q;
    return q;
}

__device__ __forceinline__ float head_reduce(float p[8], int lane)
{
    #pragma unroll
    for (int h = 0; h < 8; ++h) {
        p[h] += __shfl_xor(p[h], 1);
        p[h] += __shfl_xor(p[h], 2);
        p[h] += __shfl_xor(p[h], 4);
    }
    float q = sel8(p, lane & 7);
    q += __shfl_xor(q, 8);
    q += __shfl_xor(q, 16);
    q += __shfl_xor(q, 32);
    return q;
}

// ---------------------------------------------------------------------------
// W[256k][256n] f32  ->  BT[256n][256k] bf16  (pre-transpose for MFMA B-frags)
// ---------------------------------------------------------------------------
__global__ void prep_bt(const float* __restrict__ W, bf16* __restrict__ BT)
{
    int n = blockIdx.x, k = threadIdx.x;
    reinterpret_cast<unsigned short*>(BT)[n * KDIM + k] = f2bu(W[k * KDIM + n]);
}

// ---------------------------------------------------------------------------
// MFMA GEMM: C[M x 256] = A[M x 256] @ B (BT = B^T bf16 [n][k]), f32 acc.
// 128x128 tile, BK=32, 256 threads = 4 waves (2x2 of 64x64), 4x4 frags/wave.
// MODE 0: C(bf16) = acc
// MODE 1: C(bf16) = sc_w[n,h]*rfw + sc_c[n,h]*acc      (paper fusion epilogue)
// MODE 2: C(f32)  = sig(g)*other(bf16) + (1-sig(g))*(acc + bias)  (residual)
// ---------------------------------------------------------------------------
template<int MODE, typename TA>
__global__ __launch_bounds__(256) void mfma_gemm(
    const TA* __restrict__ A, const bf16* __restrict__ BT, int M,
    void* __restrict__ Cout,
    const float* __restrict__ bias, const bf16* __restrict__ other,
    const float* __restrict__ gate,
    const bf16* __restrict__ rfw, const float* __restrict__ sc_w,
    const float* __restrict__ sc_c)
{
    __shared__ short As[128 * 40];   // [row][k], pad 32->40
    __shared__ short Bs[128 * 40];   // [n][k]
    const int tid = threadIdx.x;
    const int lane = tid & 63, wave = tid >> 6;
    const int wm = wave >> 1, wn = wave & 1;
    const int rowBase = blockIdx.y * 128;
    const int colBase = blockIdx.x * 128;

    float4e acc[4][4];
    #pragma unroll
    for (int i = 0; i < 4; ++i)
        #pragma unroll
        for (int j = 0; j < 4; ++j) {
            float4e z = {0.f, 0.f, 0.f, 0.f};
            acc[i][j] = z;
        }

    const int srow = tid >> 2;          // 0..63
    const int sq = (tid & 3) << 3;      // 0,8,16,24

    for (int kt = 0; kt < KDIM; kt += 32) {
        #pragma unroll
        for (int p = 0; p < 2; ++p) {
            int r = srow + p * 64;
            int gr = rowBase + r;
            short8 v = {0, 0, 0, 0, 0, 0, 0, 0};
            if (gr < M) {
                if constexpr (std::is_same<TA, float>::value) {
                    const float* ap = A + (size_t)gr * KDIM + kt + sq;
                    float4 x = *reinterpret_cast<const float4*>(ap);
                    float4 y = *reinterpret_cast<const float4*>(ap + 4);
                    v[0] = (short)f2bu(x.x); v[1] = (short)f2bu(x.y);
                    v[2] = (short)f2bu(x.z); v[3] = (short)f2bu(x.w);
                    v[4] = (short)f2bu(y.x); v[5] = (short)f2bu(y.y);
                    v[6] = (short)f2bu(y.z); v[7] = (short)f2bu(y.w);
                } else {
                    v = *reinterpret_cast<const short8*>(
                        reinterpret_cast<const short*>(A) + (size_t)gr * KDIM + kt + sq);
                }
            }
            *reinterpret_cast<short8*>(&As[r * 40 + sq]) = v;
        }
        #pragma unroll
        for (int p = 0; p < 2; ++p) {
            int n = srow + p * 64;
            short8 v = *reinterpret_cast<const short8*>(
                reinterpret_cast<const short*>(BT) + (size_t)(colBase + n) * KDIM + kt + sq);
            *reinterpret_cast<short8*>(&Bs[n * 40 + sq]) = v;
        }
        __syncthreads();

        short8 af[4], bg[4];
        #pragma unroll
        for (int i = 0; i < 4; ++i)
            af[i] = *reinterpret_cast<const short8*>(
                &As[(wm * 64 + i * 16 + (lane & 15)) * 40 + ((lane >> 4) << 3)]);
        #pragma unroll
        for (int j = 0; j < 4; ++j)
            bg[j] = *reinterpret_cast<const short8*>(
                &Bs[(wn * 64 + j * 16 + (lane & 15)) * 40 + ((lane >> 4) << 3)]);
        #pragma unroll
        for (int i = 0; i < 4; ++i)
            #pragma unroll
            for (int j = 0; j < 4; ++j)
                acc[i][j] = __builtin_amdgcn_mfma_f32_16x16x32_bf16(
                    af[i], bg[j], acc[i][j], 0, 0, 0);
        __syncthreads();
    }

    float al = 0.f;
    if constexpr (MODE == 2) al = 1.f / (1.f + expf(-gate[0]));

    #pragma unroll
    for (int i = 0; i < 4; ++i) {
        int r0 = rowBase + wm * 64 + i * 16 + ((lane >> 4) << 2);
        #pragma unroll
        for (int j = 0; j < 4; ++j) {
            int col = colBase + wn * 64 + j * 16 + (lane & 15);
            #pragma unroll
            for (int reg = 0; reg < 4; ++reg) {
                int row = r0 + reg;
                if (row < M) {
                    size_t idx = (size_t)row * KDIM + col;
                    float v = acc[i][j][reg];
                    if constexpr (MODE == 0) {
                        reinterpret_cast<unsigned short*>(Cout)[idx] = f2bu(v);
                    } else if constexpr (MODE == 1) {
                        int h = col >> 5;
                        size_t si = (size_t)row * NHEAD + h;
                        float f = sc_w[si] * us2f(reinterpret_cast<const unsigned short*>(rfw)[idx])
                                + sc_c[si] * v;
                        reinterpret_cast<unsigned short*>(Cout)[idx] = f2bu(f);
                    } else {
                        float of = us2f(reinterpret_cast<const unsigned short*>(other)[idx]);
                        reinterpret_cast<float*>(Cout)[idx] =
                            fin(al * of + (1.f - al) * (v + bias[col]));
                    }
                }
            }
        }
    }
}

// ---------------------------------------------------------------------------
// Per-node per-head attention dots (micro): one projection-row read, 2-3 dots.
// ---------------------------------------------------------------------------
__global__ void head_dot2(const bf16* __restrict__ proj,
                          const float* __restrict__ aA, int offA, float* __restrict__ oA,
                          const float* __restrict__ aB, int offB, float* __restrict__ oB,
                          int N)
{
    int gid = blockIdx.x * blockDim.x + threadIdx.x;
    if (gid >= N * NHEAD) return;
    int n = gid >> 3, k = gid & 7;
    const unsigned short* p =
        reinterpret_cast<const unsigned short*>(proj) + (size_t)n * KDIM + k * 32;
    const float* a = aA + k * 64 + offA;
    const float* b = aB + k * 64 + offB;
    float sA = 0.f, sB = 0.f;
    #pragma unroll
    for (int d0 = 0; d0 < 32; d0 += 4) {
        ushort4 pv = *reinterpret_cast<const ushort4*>(p + d0);
        float4 av = *reinterpret_cast<const float4*>(a + d0);
        float4 bv = *reinterpret_cast<const float4*>(b + d0);
        float f0 = us2f(pv.x), f1 = us2f(pv.y), f2 = us2f(pv.z), f3 = us2f(pv.w);
        sA += f0 * av.x + f1 * av.y + f2 * av.z + f3 * av.w;
        sB += f0 * bv.x + f1 * bv.y + f2 * bv.z + f3 * bv.w;
    }
    oA[gid] = fin(sA);
    oB[gid] = fin(sB);
}

__global__ void head_dot3(const bf16* __restrict__ proj,
                          const float* __restrict__ aA, int offA, float* __restrict__ oA,
                          const float* __restrict__ aB, int offB, float* __restrict__ oB,
                          const float* __restrict__ aC, int offC, float* __restrict__ oC,
                          int N)
{
    int gid = blockIdx.x * blockDim.x + threadIdx.x;
    if (gid >= N * NHEAD) return;
    int n = gid >> 3, k = gid & 7;
    const unsigned short* p =
        reinterpret_cast<const unsigned short*>(proj) + (size_t)n * KDIM + k * 32;
    const float* a = aA + k * 64 + offA;
    const float* b = aB + k * 64 + offB;
    const float* c = aC + k * 64 + offC;
    float sA = 0.f, sB = 0.f, sC = 0.f;
    #pragma unroll
    for (int d0 = 0; d0 < 32; d0 += 4) {
        ushort4 pv = *reinterpret_cast<const ushort4*>(p + d0);
        float4 av = *reinterpret_cast<const float4*>(a + d0);
        float4 bv = *reinterpret_cast<const float4*>(b + d0);
        float4 cv = *reinterpret_cast<const float4*>(c + d0);
        float f0 = us2f(pv.x), f1 = us2f(pv.y), f2 = us2f(pv.z), f3 = us2f(pv.w);
        sA += f0 * av.x + f1 * av.y + f2 * av.z + f3 * av.w;
        sB += f0 * bv.x + f1 * bv.y + f2 * bv.z + f3 * bv.w;
        sC += f0 * cv.x + f1 * cv.y + f2 * cv.z + f3 * cv.w;
    }
    oA[gid] = fin(sA);
    oB[gid] = fin(sB);
    oC[gid] = fin(sC);
}

// ---------------------------------------------------------------------------
// Bucketed CSR build (relation = blockIdx.y).
// meta layout (ints): gbcnt[3][NBUCK] @0, bbase[3][NBUCK+1] @294, grank[3][NBUCK] @591
// ---------------------------------------------------------------------------
__global__ void zero_meta(int* __restrict__ meta)
{
    int i = threadIdx.x + blockIdx.x * blockDim.x;
    if (i < 3 * NBUCK) meta[i] = 0;                       // gbcnt
    if (i < 3 * NBUCK) meta[591 + i] = 0;                 // grank
}

__global__ __launch_bounds__(256) void bucket_count(
    const int* __restrict__ d0, const int* __restrict__ d1,
    const int* __restrict__ d2, int* __restrict__ meta, int E)
{
    __shared__ int cnt[NBUCK];
    for (int i = threadIdx.x; i < NBUCK; i += 256) cnt[i] = 0;
    __syncthreads();
    int r = blockIdx.y;
    const int* d = r == 0 ? d0 : (r == 1 ? d1 : d2);
    for (int e = blockIdx.x * 256 + threadIdx.x; e < E; e += gridDim.x * 256)
        atomicAdd(&cnt[clampi(d[e], N_PAPER) >> 9], 1);
    __syncthreads();
    for (int i = threadIdx.x; i < NBUCK; i += 256)
        if (cnt[i]) atomicAdd(&meta[r * NBUCK + i], cnt[i]);
}

// 3 waves, one per relation: shuffle-scan NBUCK bucket counts -> bases.
__global__ void bucket_scan(int* __restrict__ meta)
{
    int r = threadIdx.x >> 6, lane = threadIdx.x & 63;
    if (r >= 3) return;
    const int* gbcnt = meta + r * NBUCK;
    int* bbase = meta + 294 + r * (NBUCK + 1);
    int carry = 0;
    for (int base = 0; base < NBUCK; base += 64) {
        int i = base + lane;
        int v = (i < NBUCK) ? gbcnt[i] : 0;
        int x = v;
        #pragma unroll
        for (int o = 1; o < 64; o <<= 1) {
            int t = __shfl_up(x, o, 64);
            if (lane >= o) x += t;
        }
        if (i < NBUCK) bbase[i] = carry + x - v;
        carry += __shfl(x, 63, 64);
    }
    if (lane == 0) bbase[NBUCK] = carry;
}

// Scatter edges into bucket-major temp T, packed (src<<9)|dlocal (25 bits).
// 64 fixed chunks/relation; per-(block,bucket) runs ~64 edges = 256B contiguous.
__global__ __launch_bounds__(256) void bucket_scatter(
    const int* __restrict__ s0, const int* __restrict__ s1,
    const int* __restrict__ s2,
    const int* __restrict__ d0, const int* __restrict__ d1,
    const int* __restrict__ d2,
    int* __restrict__ meta, int* __restrict__ T, int E)
{
    __shared__ int cnt[NBUCK];
    __shared__ int base[NBUCK];
    int r = blockIdx.y;
    const int* s = r == 0 ? s0 : (r == 1 ? s1 : s2);
    const int* d = r == 0 ? d0 : (r == 1 ? d1 : d2);
    const int* bbase = meta + 294 + r * (NBUCK + 1);
    int* grank = meta + 591 + r * NBUCK;
    int* Tr = T + r * NEDGE;

    for (int i = threadIdx.x; i < NBUCK; i += 256) cnt[i] = 0;
    __syncthreads();

    const int CH = (E + gridDim.x - 1) / gridDim.x;
    int e0 = blockIdx.x * CH;
    int e1 = min(e0 + CH, E);
    for (int e = e0 + threadIdx.x; e < e1; e += 256)
        atomicAdd(&cnt[clampi(d[e], N_PAPER) >> 9], 1);
    __syncthreads();
    if (threadIdx.x < NBUCK) {
        int c = cnt[threadIdx.x];
        base[threadIdx.x] = c ? bbase[threadIdx.x] + atomicAdd(&grank[threadIdx.x], c) : 0;
        cnt[threadIdx.x] = 0;            // reuse as local rank
    }
    __syncthreads();
    for (int e = e0 + threadIdx.x; e < e1; e += 256) {
        int dc = clampi(d[e], N_PAPER);
        int b = dc >> 9, dl = dc & 511;
        int l = atomicAdd(&cnt[b], 1);
        Tr[base[b] + l] = (clampi(s[e], N_PAPER) << 9) | dl;
    }
}

// Per (bucket, relation): LDS per-dst hist + scan -> off[] (coalesced), then
// LDS scatter + coalesced gsrc stream-out. Replaces global hist/scan/scatter.
__global__ __launch_bounds__(256) void csr_build(
    const int* __restrict__ meta, const int* __restrict__ T,
    int* __restrict__ csr)
{
    __shared__ int cnt[512];
    __shared__ int loc[512];
    __shared__ int sbuf[SBUF_CAP];
    __shared__ int wtot[4];
    int b = blockIdx.x, r = blockIdx.y;
    const int* bbase = meta + 294 + r * (NBUCK + 1);
    const int* Tr = T + r * NEDGE;
    int* off = csr + r * CSR_STRIDE;
    int* gsrc = off + CSR_GSRC;
    const int tid = threadIdx.x, lane = tid & 63, wv = tid >> 6;

    int dstbase = b << 9;
    int nd = min(512, N_PAPER - dstbase);
    int cbase = bbase[b], cend = bbase[b + 1];
    int span = cend - cbase;

    cnt[2 * tid] = 0; cnt[2 * tid + 1] = 0;
    __syncthreads();
    for (int t = tid; t < span; t += 256)
        atomicAdd(&cnt[Tr[cbase + t] & 511], 1);
    __syncthreads();

    // exclusive scan of cnt[0..512) (2 elems/thread, wave shuffle + LDS combine)
    int v0 = cnt[2 * tid], v1 = cnt[2 * tid + 1];
    int sthr = v0 + v1;
    int x = sthr;
    #pragma unroll
    for (int o = 1; o < 64; o <<= 1) {
        int t = __shfl_up(x, o, 64);
        if (lane >= o) x += t;
    }
    if (lane == 63) wtot[wv] = x;
    __syncthreads();
    int wexc = 0;
    #pragma unroll
    for (int w = 0; w < 4; ++w)
        if (w < wv) wexc += wtot[w];
    int exc = wexc + x - sthr;
    loc[2 * tid] = exc;
    loc[2 * tid + 1] = exc + v0;
    int i0 = 2 * tid, i1 = 2 * tid + 1;
    if (i0 < nd) off[dstbase + i0] = cbase + exc;
    if (i1 < nd) off[dstbase + i1] = cbase + exc + v0;
    if (b == NBUCK - 1 && tid == 0) off[N_PAPER] = cend;
    cnt[i0] = 0; cnt[i1] = 0;            // reuse as per-dst rank
    __syncthreads();

    if (span <= SBUF_CAP) {
        for (int t = tid; t < span; t += 256) {
            int v = Tr[cbase + t];
            int dl = v & 511;
            int pos = loc[dl] + atomicAdd(&cnt[dl], 1);
            sbuf[pos] = v >> 9;
        }
        __syncthreads();
        for (int t = tid; t < span; t += 256)
            gsrc[cbase + t] = sbuf[t];
    } else {                              // never expected; correctness fallback
        for (int t = tid; t < span; t += 256) {
            int v = Tr[cbase + t];
            int dl = v & 511;
            int pos = loc[dl] + atomicAdd(&cnt[dl], 1);
            gsrc[cbase + pos] = v >> 9;
        }
    }
}

// ---------------------------------------------------------------------------
// GAT gather: one wave per dst node; lane covers 4 cols, head = lane>>3.
// Single pass (linearity): ft = relu( (sum_e ex_e * feat[src_e]) / sum_e ex_e ).
// No atomics; fused softmax + aggregate + relu + bf16 cast.
// Optional epilogue (dv != null): macro head-dot of the relu'd output row vs
// LDS-staged v-vectors (row already in registers -> no extra HBM stream).
// ---------------------------------------------------------------------------
__global__ __launch_bounds__(256) void gat_gather(
    const int* __restrict__ off, const int* __restrict__ gsrc,
    const float* __restrict__ el, const float* __restrict__ er,
    const bf16* __restrict__ feat, bf16* __restrict__ out,
    const float* __restrict__ dv, float* __restrict__ dout, int N)
{
    __shared__ float vlds[2048];
    if (dv) {
        #pragma unroll
        for (int i = 0; i < 2; ++i) {
            int idx = (i * 256 + threadIdx.x) * 4;
            *reinterpret_cast<float4*>(&vlds[idx]) =
                *reinterpret_cast<const float4*>(&dv[idx]);
        }
        __syncthreads();
    }
    int d = blockIdx.x * 4 + (threadIdx.x >> 6);
    if (d >= N) return;
    int lane = threadIdx.x & 63;
    int h = lane >> 3;
    int col = lane * 4;
    float erd = er[d * NHEAD + h];
    int e0 = off[d], e1 = off[d + 1];
    float denom = 0.f, a0 = 0.f, a1 = 0.f, a2 = 0.f, a3 = 0.f;
    for (int e = e0; e < e1; ++e) {
        int s = gsrc[e];
        float v = el[s * NHEAD + h] + erd;
        v = v > 0.f ? v : SLOPE * v;
        float ex = expf(fminf(v, 30.f));
        denom += ex;
        ushort4 fv = *reinterpret_cast<const ushort4*>(
            reinterpret_cast<const unsigned short*>(feat) + (size_t)s * KDIM + col);
        a0 = fmaf(us2f(fv.x), ex, a0); a1 = fmaf(us2f(fv.y), ex, a1);
        a2 = fmaf(us2f(fv.z), ex, a2); a3 = fmaf(us2f(fv.w), ex, a3);
    }
    float inv = 1.f / fmaxf(denom, 1e-20f);
    float o0 = fmaxf(a0 * inv, 0.f), o1 = fmaxf(a1 * inv, 0.f);
    float o2 = fmaxf(a2 * inv, 0.f), o3 = fmaxf(a3 * inv, 0.f);
    ushort4 o;
    o.x = f2bu(o0); o.y = f2bu(o1); o.z = f2bu(o2); o.w = f2bu(o3);
    *reinterpret_cast<ushort4*>(
        reinterpret_cast<unsigned short*>(out) + (size_t)d * KDIM + col) = o;
    if (dv) {
        float p[8];
        #pragma unroll
        for (int hh = 0; hh < 8; ++hh) {
            float4 vv = *reinterpret_cast<const float4*>(&vlds[hh * 256 + col]);
            p[hh] = o0 * vv.x + o1 * vv.y + o2 * vv.z + o3 * vv.w;
        }
        float q = head_reduce(p, lane);
        if (lane < 8) dout[d * NHEAD + lane] = fin(q);
    }
}

// ---------------------------------------------------------------------------
// Macro score vectors + dotL pass + relation softmax
// ---------------------------------------------------------------------------
__global__ void prep_v(const float* __restrict__ Ww, const float* __restrict__ Wc,
                       const float* __restrict__ Wn, const float* __restrict__ attn,
                       float* __restrict__ vbuf)
{
    int id = blockIdx.x * blockDim.x + threadIdx.x;
    if (id >= 3 * 2048) return;
    int which = id >> 11;
    int rem = id & 2047;
    int h = rem >> 8, k = rem & 255;
    const float* Wsrc = which == 0 ? Ww : (which == 1 ? Wc : Wn);
    int aoff = which == 2 ? 0 : 32;
    float s = 0.f;
    #pragma unroll 8
    for (int d = 0; d < 32; ++d)
        s += Wsrc[(size_t)k * KDIM + h * 32 + d] * attn[h * 64 + aoff + d];
    vbuf[which * 2048 + h * 256 + k] = fin(s);
}

// One wave per paper row: dotL[n,h] = feats_p[n,:] . vL[h,:].
// Nontemporal loads: pure 51MB stream, don't evict dirty L3 lines.
__global__ __launch_bounds__(256) void macro_dotL(
    const float* __restrict__ Af, const float* __restrict__ vL,
    float* __restrict__ dout, int N)
{
    __shared__ float vlds[2048];
    #pragma unroll
    for (int i = 0; i < 2; ++i) {
        int idx = (i * 256 + threadIdx.x) * 4;
        *reinterpret_cast<float4*>(&vlds[idx]) =
            *reinterpret_cast<const float4*>(&vL[idx]);
    }
    __syncthreads();
    int n = blockIdx.x * 4 + (threadIdx.x >> 6);
    if (n >= N) return;
    int lane = threadIdx.x & 63;
    int col = lane * 4;
    float4e afv = __builtin_nontemporal_load(
        reinterpret_cast<const float4e*>(Af + (size_t)n * KDIM + col));
    float p[8];
    #pragma unroll
    for (int h = 0; h < 8; ++h) {
        float4 vv = *reinterpret_cast<const float4*>(&vlds[h * 256 + col]);
        p[h] = afv.x * vv.x + afv.y * vv.y + afv.z * vv.z + afv.w * vv.w;
    }
    float q = head_reduce(p, lane);
    if (lane < 8) dout[n * NHEAD + lane] = fin(q);
}

__global__ void score_kernel(const float* __restrict__ dotL, const float* __restrict__ dotW,
                             const float* __restrict__ dotC,
                             float* __restrict__ ow, float* __restrict__ oc, int total)
{
    int i = blockIdx.x * blockDim.x + threadIdx.x;
    if (i >= total) return;
    float sw = dotL[i] + dotW[i]; sw = sw > 0.f ? sw : SLOPE * sw;
    float sc = dotL[i] + dotC[i]; sc = sc > 0.f ? sc : SLOPE * sc;
    float m = fmaxf(sw, sc);
    float ew = expf(sw - m), ec = expf(sc - m);
    float inv = 1.f / (ew + ec);
    ow[i] = fin(ew * inv);
    oc[i] = fin(ec * inv);
}

// ---------------------------------------------------------------------------
extern "C" void kernel_launch(void* const* d_in, const int* in_sizes, int n_in,
                              void* d_out, int out_size, void* d_ws, size_t ws_size,
                              hipStream_t stream)
{
    static const int expected[24] = {
        12800000, 12800000, 65536, 65536, 512, 512, 65536, 65536,
        65536, 65536, 65536, 512, 65536, 256, 65536, 256, 1, 1,
        400000, 400000, 400000, 400000, 400000, 400000};
    float marker = 0.f;
    if (n_in != 24) marker = 500.f;
    else {
        for (int i = 0; i < 24; ++i)
            if (in_sizes[i] != expected[i]) { marker = 200.f + 8.f * i; break; }
    }
    if (marker == 0.f && out_size != 25600000) marker = 600.f + (float)(out_size / 1000000);
    if (marker == 0.f && ws_size < 51200000ull) marker = 1000.f + (float)(ws_size / 1000000ull);
    if (marker != 0.f) {
        fill_marker<<<(out_size + 255) / 256, 256, 0, stream>>>((float*)d_out, out_size, marker);
        return;
    }

    const float* feats_a  = (const float*)d_in[0];
    const float* feats_p  = (const float*)d_in[1];
    const float* W_mic_a  = (const float*)d_in[2];
    const float* W_mic_p  = (const float*)d_in[3];
    const float* attn_a   = (const float*)d_in[4];
    const float* attn_p   = (const float*)d_in[5];
    const float* W_node_p = (const float*)d_in[7];
    const float* W_rel_w  = (const float*)d_in[8];
    const float* W_rel_wb = (const float*)d_in[9];
    const float* W_rel_c  = (const float*)d_in[10];
    const float* attn_mac = (const float*)d_in[11];
    const float* W_res_a  = (const float*)d_in[12];
    const float* b_res_a  = (const float*)d_in[13];
    const float* W_res_p  = (const float*)d_in[14];
    const float* b_res_p  = (const float*)d_in[15];
    const float* rw_a     = (const float*)d_in[16];
    const float* rw_p     = (const float*)d_in[17];
    const int* w_src  = (const int*)d_in[18];
    const int* w_dst  = (const int*)d_in[19];
    const int* wb_src = (const int*)d_in[20];
    const int* wb_dst = (const int*)d_in[21];
    const int* c_src  = (const int*)d_in[22];
    const int* c_dst  = (const int*)d_in[23];

    const int NB = N_PAPER * KDIM;            // 12.8M elems
    // ---- d_out (f32, 102.4MB): [author 51.2MB][paper 51.2MB] ----
    float* Oa_f = (float*)d_out;
    float* Op_f = Oa_f + NB;
    bf16* Oa_b = (bf16*)d_out;                // P_a -> r_written_by (author lower)
    bf16* Op_b = (bf16*)Op_f;                 // P_p -> rf_writes    (paper lower)
    char* au_up = (char*)d_out + 25600000;    // author upper 25.6MB
    bf16*  Cslot = (bf16*)au_up;              // r_cites
    bf16*  BTa0  = (bf16*)au_up;              // later: W_res_p BT (Cslot dead)
    bf16*  BTa1  = BTa0 + 65536;              //        W_rel_wb BT
    char* pu = (char*)d_out + 76800000;       // paper upper 25.6MB
    float* dotW = (float*)pu;
    float* dotC = dotW + 400000;
    float* dotL = dotW + 800000;
    float* sc_w = dotW + 1200000;
    float* sc_c = dotW + 1600000;
    float* vbuf = dotW + 2000000;             // 6144 f32
    bf16* BT0 = (bf16*)(pu + 10000000);       // early BT slots (128KB each)
    bf16* BT1 = BT0 + 65536;
    bf16* BT2 = BT1 + 65536;
    bf16* BT3 = BT2 + 65536;
    // ---- d_ws (51.2e6 B): [A_ws 25.6MB][X 25.6MB] ----
    bf16* A_ws = (bf16*)d_ws;                 // r_writes -> fused_paper
    bf16* BTw  = (bf16*)d_ws;                 // W_res_a BT (after fused dead)
    char* Xb   = (char*)d_ws + 25600000;
    float* el_w  = (float*)Xb;                // 5 x 400,000 f32 (8MB)
    float* er_w  = el_w + 400000;
    float* el_p  = el_w + 800000;
    float* er_wb = el_w + 1200000;
    float* er_c  = el_w + 1600000;
    int*  csr    = (int*)(el_w + 2000000);    // 3 x 450004 ints, 16B-aligned
    int*  Tbuf   = csr + 3 * CSR_STRIDE;      // 3 x 400000 ints (bucket-major temp)
    int*  meta   = Tbuf + 3 * NEDGE;          // 885 ints (gbcnt/bbase/grank)
    bf16* Xslot  = (bf16*)Xb;                 // later: rf_written_by (25.6MB)

    dim3 mg(2, (N_PAPER + 127) / 128);
    int hdB = (N_PAPER * NHEAD + 255) / 256;
    int gB  = (N_PAPER + 3) / 4;

    // ---- 1: micro projections (MFMA) ----
    prep_bt<<<256, 256, 0, stream>>>(W_mic_a, BT0);
    prep_bt<<<256, 256, 0, stream>>>(W_mic_p, BT1);
    mfma_gemm<0, float><<<mg, 256, 0, stream>>>(feats_a, BT0, N_AUTHOR, Oa_b,
        nullptr, nullptr, nullptr, nullptr, nullptr, nullptr);
    mfma_gemm<0, float><<<mg, 256, 0, stream>>>(feats_p, BT1, N_PAPER, Op_b,
        nullptr, nullptr, nullptr, nullptr, nullptr, nullptr);

    // ---- 2: micro attention dots (fused per projection read) ----
    head_dot2<<<hdB, 256, 0, stream>>>(Oa_b, attn_a, 0, el_w,
                                       attn_p, 32, er_wb, N_AUTHOR);
    head_dot3<<<hdB, 256, 0, stream>>>(Op_b, attn_a, 32, er_w,
                                       attn_p, 0, el_p,
                                       attn_p, 32, er_c, N_PAPER);

    // ---- 3: bucketed CSR build + GAT gathers (dot epilogues for r0/r2).
    // r0 writes: feat P_a(Oa_b) -> A_ws        (+ dotW epilogue)
    // r1 written_by: feat P_p(Op_b) -> Oa_b (P_a dead after r0 gather)
    // r2 cites: feat P_p(Op_b) -> Cslot        (+ dotC epilogue)
    zero_meta<<<2, 256, 0, stream>>>(meta);
    bucket_count<<<dim3(64, 3), 256, 0, stream>>>(w_dst, wb_dst, c_dst, meta, NEDGE);
    bucket_scan<<<1, 192, 0, stream>>>(meta);
    bucket_scatter<<<dim3(64, 3), 256, 0, stream>>>(w_src, wb_src, c_src,
                                                    w_dst, wb_dst, c_dst,
                                                    meta, Tbuf, NEDGE);
    csr_build<<<dim3(NBUCK, 3), 256, 0, stream>>>(meta, Tbuf, csr);
    prep_v<<<24, 256, 0, stream>>>(W_rel_w, W_rel_c, W_node_p, attn_mac, vbuf);
    {
        const float* rel_el[3] = {el_w, el_p, el_p};
        const float* rel_er[3] = {er_w, er_wb, er_c};
        const bf16* rfeat[3]   = {Oa_b, Op_b, Op_b};
        bf16* rout[3]          = {A_ws, Oa_b, Cslot};
        const float* rdv[3]    = {vbuf, nullptr, vbuf + 2048};
        float* rdo[3]          = {dotW, nullptr, dotC};
        for (int r = 0; r < 3; ++r) {
            int* off  = csr + r * CSR_STRIDE;
            int* gsrc = off + CSR_GSRC;
            gat_gather<<<gB, 256, 0, stream>>>(off, gsrc, rel_el[r], rel_er[r],
                                               rfeat[r], rout[r],
                                               rdv[r], rdo[r], N_PAPER);
        }
    }
    // A_ws=r_writes, Oa_b=r_written_by, Cslot=r_cites; P_p (Op_b) dead.

    // ---- 4: dotL (nontemporal feats_p stream) + relation softmax ----
    macro_dotL<<<gB, 256, 0, stream>>>(feats_p, vbuf + 4096, dotL, N_PAPER);
    score_kernel<<<hdB, 256, 0, stream>>>(dotL, dotW, dotC, sc_w, sc_c, N_PAPER * NHEAD);

    // ---- 5: rf_writes = r_writes(A_ws) @ W_rel_w -> Op_b (P_p dead) ----
    prep_bt<<<256, 256, 0, stream>>>(W_rel_w, BT2);
    mfma_gemm<0, bf16><<<mg, 256, 0, stream>>>(A_ws, BT2, N_PAPER, Op_b,
        nullptr, nullptr, nullptr, nullptr, nullptr, nullptr);
    // ---- 6: fused = sc_w*rf_writes(Op_b) + sc_c*(r_cites(Cslot) @ W_rel_c) -> A_ws ----
    prep_bt<<<256, 256, 0, stream>>>(W_rel_c, BT3);
    mfma_gemm<1, bf16><<<mg, 256, 0, stream>>>(Cslot, BT3, N_PAPER, A_ws,
        nullptr, nullptr, nullptr, Op_b, sc_w, sc_c);
    // ---- 7: paper gated residual -> Op_f FINAL (BT in au_up; Cslot dead) ----
    prep_bt<<<256, 256, 0, stream>>>(W_res_p, BTa0);
    mfma_gemm<2, float><<<mg, 256, 0, stream>>>(feats_p, BTa0, N_PAPER, Op_f,
        b_res_p, A_ws, rw_p, nullptr, nullptr, nullptr);
    // ---- 8: rf_written_by = r_written_by(Oa_b) @ W_rel_wb -> Xslot (CSR dead) ----
    prep_bt<<<256, 256, 0, stream>>>(W_rel_wb, BTa1);
    mfma_gemm<0, bf16><<<mg, 256, 0, stream>>>(Oa_b, BTa1, N_AUTHOR, Xslot,
        nullptr, nullptr, nullptr, nullptr, nullptr, nullptr);
    // ---- 9: author gated residual -> Oa_f FINAL (BT in A_ws; fused dead) ----
    prep_bt<<<256, 256, 0, stream>>>(W_res_a, BTw);
    mfma_gemm<2, float><<<mg, 256, 0, stream>>>(feats_a, BTw, N_AUTHOR, Oa_f,
        b_res_a, Xslot, rw_a, nullptr, nullptr, nullptr);
}

// Round 6
// 812.226 us; speedup vs baseline: 1.6151x; 1.0268x over previous
//
#include <hip/hip_runtime.h>
#include <hip/hip_bf16.h>
#include <type_traits>

// HGConv layer: micro (per-relation GAT) + macro (semantic attention) + gated residual.
// I/O: float32 (verified round 6). Internals: bf16 matrices, f32 accumulation.
// Round 8: edge stage scatter->gather via on-device CSR.
// Round 9: wave-shuffle scan (was 3x96us on one CU).
// Round 10: bucketed CSR build (edge_scatter3 had 14x write amplification).
// Round 11: macro_dot fused into macro_fused (one wave/row, shuffle-tree reduce).
// Round 12: killed macro_fused's 102MB stream (dot epilogues + nt dotL pass).
// Round 14: gat_gather was latency-bound (serial per-edge chain gsrc->el->exp->
// feat, 8 redundant expf/head). Now 8-edge chunks: lane=(edge,head) metadata
// phase (1 gsrc load + 1 el load + 1 expf for 64 (e,h) pairs), then shfl
// broadcast + 8 independent feat gathers -> 8x memory-level parallelism.

#define N_AUTHOR 50000
#define N_PAPER  50000
#define NEDGE    400000
#define KDIM     256
#define NHEAD    8
#define SLOPE    0.2f

#define BUCK_W   512                    // dsts per bucket (shift 9)
#define NBUCK    98                     // ceil(50000/512)
#define SBUF_CAP 6144                   // LDS staging cap (span ~4096+-64)

// CSR slab (ints): off@0 (50001 used, pad 50004), gsrc@50004 (400000).
#define CSR_STRIDE 450004
#define CSR_GSRC   50004

using bf16 = __hip_bfloat16;
typedef __attribute__((ext_vector_type(8))) short short8;
typedef __attribute__((ext_vector_type(4))) float float4e;

__device__ __forceinline__ float us2f(unsigned short u) {
    return __uint_as_float(((unsigned int)u) << 16);
}
__device__ __forceinline__ float fin(float v) {   // 0 if NaN/Inf
    return (((__float_as_uint(v) >> 23) & 0xFF) != 0xFF) ? v : 0.f;
}
__device__ __forceinline__ unsigned short f2bu(float f) {
    f = fin(f);
    bf16 h = __float2bfloat16(f);
    return *reinterpret_cast<unsigned short*>(&h);
}
__device__ __forceinline__ int clampi(int v, int hi) {
    return v < 0 ? 0 : (v >= hi ? hi - 1 : v);
}

__global__ void fill_marker(float* __restrict__ out, int total, float c)
{
    int i = blockIdx.x * blockDim.x + threadIdx.x;
    if (i < total) out[i] = c;
}

// ---------------------------------------------------------------------------
// Shuffle-tree head reduce: xor{1,2,4} per head (8-lane col group), select head
// (lane&7), xor{8,16,32} across groups. Every lane ends with head (lane&7)'s
// full row sum.
// ---------------------------------------------------------------------------
__device__ __forceinline__ float sel8(const float p[8], int j)
{
    float q = p[0];
    q = j == 1 ? p[1] : q; q = j == 2 ? p[2] : q; q = j == 3 ? p[3] : q;
    q = j == 4 ? p[4] : q; q = j == 5 ? p[5] : q; q = j == 6 ? p[6] : q;
    q = j == 7 ? p[7] : q;
    return q;
}

__device__ __forceinline__ float head_reduce(float p[8], int lane)
{
    #pragma unroll
    for (int h = 0; h < 8; ++h) {
        p[h] += __shfl_xor(p[h], 1);
        p[h] += __shfl_xor(p[h], 2);
        p[h] += __shfl_xor(p[h], 4);
    }
    float q = sel8(p, lane & 7);
    q += __shfl_xor(q, 8);
    q += __shfl_xor(q, 16);
    q += __shfl_xor(q, 32);
    return q;
}

// ---------------------------------------------------------------------------
// W[256k][256n] f32  ->  BT[256n][256k] bf16  (pre-transpose for MFMA B-frags)
// ---------------------------------------------------------------------------
__global__ void prep_bt(const float* __restrict__ W, bf16* __restrict__ BT)
{
    int n = blockIdx.x, k = threadIdx.x;
    reinterpret_cast<unsigned short*>(BT)[n * KDIM + k] = f2bu(W[k * KDIM + n]);
}

// ---------------------------------------------------------------------------
// MFMA GEMM: C[M x 256] = A[M x 256] @ B (BT = B^T bf16 [n][k]), f32 acc.
// 128x128 tile, BK=32, 256 threads = 4 waves (2x2 of 64x64), 4x4 frags/wave.
// MODE 0: C(bf16) = acc
// MODE 1: C(bf16) = sc_w[n,h]*rfw + sc_c[n,h]*acc      (paper fusion epilogue)
// MODE 2: C(f32)  = sig(g)*other(bf16) + (1-sig(g))*(acc + bias)  (residual)
// ---------------------------------------------------------------------------
template<int MODE, typename TA>
__global__ __launch_bounds__(256) void mfma_gemm(
    const TA* __restrict__ A, const bf16* __restrict__ BT, int M,
    void* __restrict__ Cout,
    const float* __restrict__ bias, const bf16* __restrict__ other,
    const float* __restrict__ gate,
    const bf16* __restrict__ rfw, const float* __restrict__ sc_w,
    const float* __restrict__ sc_c)
{
    __shared__ short As[128 * 40];   // [row][k], pad 32->40
    __shared__ short Bs[128 * 40];   // [n][k]
    const int tid = threadIdx.x;
    const int lane = tid & 63, wave = tid >> 6;
    const int wm = wave >> 1, wn = wave & 1;
    const int rowBase = blockIdx.y * 128;
    const int colBase = blockIdx.x * 128;

    float4e acc[4][4];
    #pragma unroll
    for (int i = 0; i < 4; ++i)
        #pragma unroll
        for (int j = 0; j < 4; ++j) {
            float4e z = {0.f, 0.f, 0.f, 0.f};
            acc[i][j] = z;
        }

    const int srow = tid >> 2;          // 0..63
    const int sq = (tid & 3) << 3;      // 0,8,16,24

    for (int kt = 0; kt < KDIM; kt += 32) {
        #pragma unroll
        for (int p = 0; p < 2; ++p) {
            int r = srow + p * 64;
            int gr = rowBase + r;
            short8 v = {0, 0, 0, 0, 0, 0, 0, 0};
            if (gr < M) {
                if constexpr (std::is_same<TA, float>::value) {
                    const float* ap = A + (size_t)gr * KDIM + kt + sq;
                    float4 x = *reinterpret_cast<const float4*>(ap);
                    float4 y = *reinterpret_cast<const float4*>(ap + 4);
                    v[0] = (short)f2bu(x.x); v[1] = (short)f2bu(x.y);
                    v[2] = (short)f2bu(x.z); v[3] = (short)f2bu(x.w);
                    v[4] = (short)f2bu(y.x); v[5] = (short)f2bu(y.y);
                    v[6] = (short)f2bu(y.z); v[7] = (short)f2bu(y.w);
                } else {
                    v = *reinterpret_cast<const short8*>(
                        reinterpret_cast<const short*>(A) + (size_t)gr * KDIM + kt + sq);
                }
            }
            *reinterpret_cast<short8*>(&As[r * 40 + sq]) = v;
        }
        #pragma unroll
        for (int p = 0; p < 2; ++p) {
            int n = srow + p * 64;
            short8 v = *reinterpret_cast<const short8*>(
                reinterpret_cast<const short*>(BT) + (size_t)(colBase + n) * KDIM + kt + sq);
            *reinterpret_cast<short8*>(&Bs[n * 40 + sq]) = v;
        }
        __syncthreads();

        short8 af[4], bg[4];
        #pragma unroll
        for (int i = 0; i < 4; ++i)
            af[i] = *reinterpret_cast<const short8*>(
                &As[(wm * 64 + i * 16 + (lane & 15)) * 40 + ((lane >> 4) << 3)]);
        #pragma unroll
        for (int j = 0; j < 4; ++j)
            bg[j] = *reinterpret_cast<const short8*>(
                &Bs[(wn * 64 + j * 16 + (lane & 15)) * 40 + ((lane >> 4) << 3)]);
        #pragma unroll
        for (int i = 0; i < 4; ++i)
            #pragma unroll
            for (int j = 0; j < 4; ++j)
                acc[i][j] = __builtin_amdgcn_mfma_f32_16x16x32_bf16(
                    af[i], bg[j], acc[i][j], 0, 0, 0);
        __syncthreads();
    }

    float al = 0.f;
    if constexpr (MODE == 2) al = 1.f / (1.f + expf(-gate[0]));

    #pragma unroll
    for (int i = 0; i < 4; ++i) {
        int r0 = rowBase + wm * 64 + i * 16 + ((lane >> 4) << 2);
        #pragma unroll
        for (int j = 0; j < 4; ++j) {
            int col = colBase + wn * 64 + j * 16 + (lane & 15);
            #pragma unroll
            for (int reg = 0; reg < 4; ++reg) {
                int row = r0 + reg;
                if (row < M) {
                    size_t idx = (size_t)row * KDIM + col;
                    float v = acc[i][j][reg];
                    if constexpr (MODE == 0) {
                        reinterpret_cast<unsigned short*>(Cout)[idx] = f2bu(v);
                    } else if constexpr (MODE == 1) {
                        int h = col >> 5;
                        size_t si = (size_t)row * NHEAD + h;
                        float f = sc_w[si] * us2f(reinterpret_cast<const unsigned short*>(rfw)[idx])
                                + sc_c[si] * v;
                        reinterpret_cast<unsigned short*>(Cout)[idx] = f2bu(f);
                    } else {
                        float of = us2f(reinterpret_cast<const unsigned short*>(other)[idx]);
                        reinterpret_cast<float*>(Cout)[idx] =
                            fin(al * of + (1.f - al) * (v + bias[col]));
                    }
                }
            }
        }
    }
}

// ---------------------------------------------------------------------------
// Per-node per-head attention dots (micro): one projection-row read, 2-3 dots.
// ---------------------------------------------------------------------------
__global__ void head_dot2(const bf16* __restrict__ proj,
                          const float* __restrict__ aA, int offA, float* __restrict__ oA,
                          const float* __restrict__ aB, int offB, float* __restrict__ oB,
                          int N)
{
    int gid = blockIdx.x * blockDim.x + threadIdx.x;
    if (gid >= N * NHEAD) return;
    int n = gid >> 3, k = gid & 7;
    const unsigned short* p =
        reinterpret_cast<const unsigned short*>(proj) + (size_t)n * KDIM + k * 32;
    const float* a = aA + k * 64 + offA;
    const float* b = aB + k * 64 + offB;
    float sA = 0.f, sB = 0.f;
    #pragma unroll
    for (int d0 = 0; d0 < 32; d0 += 4) {
        ushort4 pv = *reinterpret_cast<const ushort4*>(p + d0);
        float4 av = *reinterpret_cast<const float4*>(a + d0);
        float4 bv = *reinterpret_cast<const float4*>(b + d0);
        float f0 = us2f(pv.x), f1 = us2f(pv.y), f2 = us2f(pv.z), f3 = us2f(pv.w);
        sA += f0 * av.x + f1 * av.y + f2 * av.z + f3 * av.w;
        sB += f0 * bv.x + f1 * bv.y + f2 * bv.z + f3 * bv.w;
    }
    oA[gid] = fin(sA);
    oB[gid] = fin(sB);
}

__global__ void head_dot3(const bf16* __restrict__ proj,
                          const float* __restrict__ aA, int offA, float* __restrict__ oA,
                          const float* __restrict__ aB, int offB, float* __restrict__ oB,
                          const float* __restrict__ aC, int offC, float* __restrict__ oC,
                          int N)
{
    int gid = blockIdx.x * blockDim.x + threadIdx.x;
    if (gid >= N * NHEAD) return;
    int n = gid >> 3, k = gid & 7;
    const unsigned short* p =
        reinterpret_cast<const unsigned short*>(proj) + (size_t)n * KDIM + k * 32;
    const float* a = aA + k * 64 + offA;
    const float* b = aB + k * 64 + offB;
    const float* c = aC + k * 64 + offC;
    float sA = 0.f, sB = 0.f, sC = 0.f;
    #pragma unroll
    for (int d0 = 0; d0 < 32; d0 += 4) {
        ushort4 pv = *reinterpret_cast<const ushort4*>(p + d0);
        float4 av = *reinterpret_cast<const float4*>(a + d0);
        float4 bv = *reinterpret_cast<const float4*>(b + d0);
        float4 cv = *reinterpret_cast<const float4*>(c + d0);
        float f0 = us2f(pv.x), f1 = us2f(pv.y), f2 = us2f(pv.z), f3 = us2f(pv.w);
        sA += f0 * av.x + f1 * av.y + f2 * av.z + f3 * av.w;
        sB += f0 * bv.x + f1 * bv.y + f2 * bv.z + f3 * bv.w;
        sC += f0 * cv.x + f1 * cv.y + f2 * cv.z + f3 * cv.w;
    }
    oA[gid] = fin(sA);
    oB[gid] = fin(sB);
    oC[gid] = fin(sC);
}

// ---------------------------------------------------------------------------
// Bucketed CSR build (relation = blockIdx.y).
// meta layout (ints): gbcnt[3][NBUCK] @0, bbase[3][NBUCK+1] @294, grank[3][NBUCK] @591
// ---------------------------------------------------------------------------
__global__ void zero_meta(int* __restrict__ meta)
{
    int i = threadIdx.x + blockIdx.x * blockDim.x;
    if (i < 3 * NBUCK) meta[i] = 0;                       // gbcnt
    if (i < 3 * NBUCK) meta[591 + i] = 0;                 // grank
}

__global__ __launch_bounds__(256) void bucket_count(
    const int* __restrict__ d0, const int* __restrict__ d1,
    const int* __restrict__ d2, int* __restrict__ meta, int E)
{
    __shared__ int cnt[NBUCK];
    for (int i = threadIdx.x; i < NBUCK; i += 256) cnt[i] = 0;
    __syncthreads();
    int r = blockIdx.y;
    const int* d = r == 0 ? d0 : (r == 1 ? d1 : d2);
    for (int e = blockIdx.x * 256 + threadIdx.x; e < E; e += gridDim.x * 256)
        atomicAdd(&cnt[clampi(d[e], N_PAPER) >> 9], 1);
    __syncthreads();
    for (int i = threadIdx.x; i < NBUCK; i += 256)
        if (cnt[i]) atomicAdd(&meta[r * NBUCK + i], cnt[i]);
}

// 3 waves, one per relation: shuffle-scan NBUCK bucket counts -> bases.
__global__ void bucket_scan(int* __restrict__ meta)
{
    int r = threadIdx.x >> 6, lane = threadIdx.x & 63;
    if (r >= 3) return;
    const int* gbcnt = meta + r * NBUCK;
    int* bbase = meta + 294 + r * (NBUCK + 1);
    int carry = 0;
    for (int base = 0; base < NBUCK; base += 64) {
        int i = base + lane;
        int v = (i < NBUCK) ? gbcnt[i] : 0;
        int x = v;
        #pragma unroll
        for (int o = 1; o < 64; o <<= 1) {
            int t = __shfl_up(x, o, 64);
            if (lane >= o) x += t;
        }
        if (i < NBUCK) bbase[i] = carry + x - v;
        carry += __shfl(x, 63, 64);
    }
    if (lane == 0) bbase[NBUCK] = carry;
}

// Scatter edges into bucket-major temp T, packed (src<<9)|dlocal (25 bits).
// 64 fixed chunks/relation; per-(block,bucket) runs ~64 edges = 256B contiguous.
__global__ __launch_bounds__(256) void bucket_scatter(
    const int* __restrict__ s0, const int* __restrict__ s1,
    const int* __restrict__ s2,
    const int* __restrict__ d0, const int* __restrict__ d1,
    const int* __restrict__ d2,
    int* __restrict__ meta, int* __restrict__ T, int E)
{
    __shared__ int cnt[NBUCK];
    __shared__ int base[NBUCK];
    int r = blockIdx.y;
    const int* s = r == 0 ? s0 : (r == 1 ? s1 : s2);
    const int* d = r == 0 ? d0 : (r == 1 ? d1 : d2);
    const int* bbase = meta + 294 + r * (NBUCK + 1);
    int* grank = meta + 591 + r * NBUCK;
    int* Tr = T + r * NEDGE;

    for (int i = threadIdx.x; i < NBUCK; i += 256) cnt[i] = 0;
    __syncthreads();

    const int CH = (E + gridDim.x - 1) / gridDim.x;
    int e0 = blockIdx.x * CH;
    int e1 = min(e0 + CH, E);
    for (int e = e0 + threadIdx.x; e < e1; e += 256)
        atomicAdd(&cnt[clampi(d[e], N_PAPER) >> 9], 1);
    __syncthreads();
    if (threadIdx.x < NBUCK) {
        int c = cnt[threadIdx.x];
        base[threadIdx.x] = c ? bbase[threadIdx.x] + atomicAdd(&grank[threadIdx.x], c) : 0;
        cnt[threadIdx.x] = 0;            // reuse as local rank
    }
    __syncthreads();
    for (int e = e0 + threadIdx.x; e < e1; e += 256) {
        int dc = clampi(d[e], N_PAPER);
        int b = dc >> 9, dl = dc & 511;
        int l = atomicAdd(&cnt[b], 1);
        Tr[base[b] + l] = (clampi(s[e], N_PAPER) << 9) | dl;
    }
}

// Per (bucket, relation): LDS per-dst hist + scan -> off[] (coalesced), then
// LDS scatter + coalesced gsrc stream-out. Replaces global hist/scan/scatter.
__global__ __launch_bounds__(256) void csr_build(
    const int* __restrict__ meta, const int* __restrict__ T,
    int* __restrict__ csr)
{
    __shared__ int cnt[512];
    __shared__ int loc[512];
    __shared__ int sbuf[SBUF_CAP];
    __shared__ int wtot[4];
    int b = blockIdx.x, r = blockIdx.y;
    const int* bbase = meta + 294 + r * (NBUCK + 1);
    const int* Tr = T + r * NEDGE;
    int* off = csr + r * CSR_STRIDE;
    int* gsrc = off + CSR_GSRC;
    const int tid = threadIdx.x, lane = tid & 63, wv = tid >> 6;

    int dstbase = b << 9;
    int nd = min(512, N_PAPER - dstbase);
    int cbase = bbase[b], cend = bbase[b + 1];
    int span = cend - cbase;

    cnt[2 * tid] = 0; cnt[2 * tid + 1] = 0;
    __syncthreads();
    for (int t = tid; t < span; t += 256)
        atomicAdd(&cnt[Tr[cbase + t] & 511], 1);
    __syncthreads();

    // exclusive scan of cnt[0..512) (2 elems/thread, wave shuffle + LDS combine)
    int v0 = cnt[2 * tid], v1 = cnt[2 * tid + 1];
    int sthr = v0 + v1;
    int x = sthr;
    #pragma unroll
    for (int o = 1; o < 64; o <<= 1) {
        int t = __shfl_up(x, o, 64);
        if (lane >= o) x += t;
    }
    if (lane == 63) wtot[wv] = x;
    __syncthreads();
    int wexc = 0;
    #pragma unroll
    for (int w = 0; w < 4; ++w)
        if (w < wv) wexc += wtot[w];
    int exc = wexc + x - sthr;
    loc[2 * tid] = exc;
    loc[2 * tid + 1] = exc + v0;
    int i0 = 2 * tid, i1 = 2 * tid + 1;
    if (i0 < nd) off[dstbase + i0] = cbase + exc;
    if (i1 < nd) off[dstbase + i1] = cbase + exc + v0;
    if (b == NBUCK - 1 && tid == 0) off[N_PAPER] = cend;
    cnt[i0] = 0; cnt[i1] = 0;            // reuse as per-dst rank
    __syncthreads();

    if (span <= SBUF_CAP) {
        for (int t = tid; t < span; t += 256) {
            int v = Tr[cbase + t];
            int dl = v & 511;
            int pos = loc[dl] + atomicAdd(&cnt[dl], 1);
            sbuf[pos] = v >> 9;
        }
        __syncthreads();
        for (int t = tid; t < span; t += 256)
            gsrc[cbase + t] = sbuf[t];
    } else {                              // never expected; correctness fallback
        for (int t = tid; t < span; t += 256) {
            int v = Tr[cbase + t];
            int dl = v & 511;
            int pos = loc[dl] + atomicAdd(&cnt[dl], 1);
            gsrc[cbase + pos] = v >> 9;
        }
    }
}

// ---------------------------------------------------------------------------
// GAT gather: one wave per dst node; lane covers 4 cols, head = lane>>3.
// 8-edge chunks: metadata phase lane=(edge ep=lane>>3, head hM=lane&7) loads
// gsrc/el and computes exp for all 64 (e,h) pairs in 3 instructions, then the
// aggregation phase shfl-broadcasts and issues 8 independent feat gathers.
// Optional epilogue (dv != null): macro head-dot of the relu'd output row.
// ---------------------------------------------------------------------------
__global__ __launch_bounds__(256) void gat_gather(
    const int* __restrict__ off, const int* __restrict__ gsrc,
    const float* __restrict__ el, const float* __restrict__ er,
    const bf16* __restrict__ feat, bf16* __restrict__ out,
    const float* __restrict__ dv, float* __restrict__ dout, int N)
{
    __shared__ float vlds[2048];
    if (dv) {
        #pragma unroll
        for (int i = 0; i < 2; ++i) {
            int idx = (i * 256 + threadIdx.x) * 4;
            *reinterpret_cast<float4*>(&vlds[idx]) =
                *reinterpret_cast<const float4*>(&dv[idx]);
        }
        __syncthreads();
    }
    int d = blockIdx.x * 4 + (threadIdx.x >> 6);
    if (d >= N) return;
    int lane = threadIdx.x & 63;
    int hL = lane >> 3;                  // head for aggregation cols
    int col = lane * 4;
    int ep = lane >> 3, hM = lane & 7;   // metadata mapping: lane = ep*8+hM
    float erdM = er[d * NHEAD + hM];
    int e0 = off[d], e1 = off[d + 1];
    float denom = 0.f, a0 = 0.f, a1 = 0.f, a2 = 0.f, a3 = 0.f;
    for (int e = e0; e < e1; e += 8) {
        int nc = e1 - e; nc = nc > 8 ? 8 : nc;
        int sM = 0; float exM = 0.f;
        if (ep < nc) {
            sM = gsrc[e + ep];
            float v = el[sM * NHEAD + hM] + erdM;
            v = v > 0.f ? v : SLOPE * v;
            exM = expf(fminf(v, 30.f));
        }
        #pragma unroll
        for (int q = 0; q < 8; ++q) {
            if (q < nc) {
                float ex = __shfl(exM, q * 8 + hL);
                int s = __shfl(sM, q * 8);
                denom += ex;
                ushort4 fv = *reinterpret_cast<const ushort4*>(
                    reinterpret_cast<const unsigned short*>(feat) + (size_t)s * KDIM + col);
                a0 = fmaf(us2f(fv.x), ex, a0); a1 = fmaf(us2f(fv.y), ex, a1);
                a2 = fmaf(us2f(fv.z), ex, a2); a3 = fmaf(us2f(fv.w), ex, a3);
            }
        }
    }
    float inv = 1.f / fmaxf(denom, 1e-20f);
    float o0 = fmaxf(a0 * inv, 0.f), o1 = fmaxf(a1 * inv, 0.f);
    float o2 = fmaxf(a2 * inv, 0.f), o3 = fmaxf(a3 * inv, 0.f);
    ushort4 o;
    o.x = f2bu(o0); o.y = f2bu(o1); o.z = f2bu(o2); o.w = f2bu(o3);
    *reinterpret_cast<ushort4*>(
        reinterpret_cast<unsigned short*>(out) + (size_t)d * KDIM + col) = o;
    if (dv) {
        float p[8];
        #pragma unroll
        for (int hh = 0; hh < 8; ++hh) {
            float4 vv = *reinterpret_cast<const float4*>(&vlds[hh * 256 + col]);
            p[hh] = o0 * vv.x + o1 * vv.y + o2 * vv.z + o3 * vv.w;
        }
        float q = head_reduce(p, lane);
        if (lane < 8) dout[d * NHEAD + lane] = fin(q);
    }
}

// ---------------------------------------------------------------------------
// Macro score vectors + dotL pass + relation softmax
// ---------------------------------------------------------------------------
__global__ void prep_v(const float* __restrict__ Ww, const float* __restrict__ Wc,
                       const float* __restrict__ Wn, const float* __restrict__ attn,
                       float* __restrict__ vbuf)
{
    int id = blockIdx.x * blockDim.x + threadIdx.x;
    if (id >= 3 * 2048) return;
    int which = id >> 11;
    int rem = id & 2047;
    int h = rem >> 8, k = rem & 255;
    const float* Wsrc = which == 0 ? Ww : (which == 1 ? Wc : Wn);
    int aoff = which == 2 ? 0 : 32;
    float s = 0.f;
    #pragma unroll 8
    for (int d = 0; d < 32; ++d)
        s += Wsrc[(size_t)k * KDIM + h * 32 + d] * attn[h * 64 + aoff + d];
    vbuf[which * 2048 + h * 256 + k] = fin(s);
}

// One wave per paper row: dotL[n,h] = feats_p[n,:] . vL[h,:].
// Nontemporal loads: pure 51MB stream, don't evict dirty L3 lines.
__global__ __launch_bounds__(256) void macro_dotL(
    const float* __restrict__ Af, const float* __restrict__ vL,
    float* __restrict__ dout, int N)
{
    __shared__ float vlds[2048];
    #pragma unroll
    for (int i = 0; i < 2; ++i) {
        int idx = (i * 256 + threadIdx.x) * 4;
        *reinterpret_cast<float4*>(&vlds[idx]) =
            *reinterpret_cast<const float4*>(&vL[idx]);
    }
    __syncthreads();
    int n = blockIdx.x * 4 + (threadIdx.x >> 6);
    if (n >= N) return;
    int lane = threadIdx.x & 63;
    int col = lane * 4;
    float4e afv = __builtin_nontemporal_load(
        reinterpret_cast<const float4e*>(Af + (size_t)n * KDIM + col));
    float p[8];
    #pragma unroll
    for (int h = 0; h < 8; ++h) {
        float4 vv = *reinterpret_cast<const float4*>(&vlds[h * 256 + col]);
        p[h] = afv.x * vv.x + afv.y * vv.y + afv.z * vv.z + afv.w * vv.w;
    }
    float q = head_reduce(p, lane);
    if (lane < 8) dout[n * NHEAD + lane] = fin(q);
}

__global__ void score_kernel(const float* __restrict__ dotL, const float* __restrict__ dotW,
                             const float* __restrict__ dotC,
                             float* __restrict__ ow, float* __restrict__ oc, int total)
{
    int i = blockIdx.x * blockDim.x + threadIdx.x;
    if (i >= total) return;
    float sw = dotL[i] + dotW[i]; sw = sw > 0.f ? sw : SLOPE * sw;
    float sc = dotL[i] + dotC[i]; sc = sc > 0.f ? sc : SLOPE * sc;
    float m = fmaxf(sw, sc);
    float ew = expf(sw - m), ec = expf(sc - m);
    float inv = 1.f / (ew + ec);
    ow[i] = fin(ew * inv);
    oc[i] = fin(ec * inv);
}

// ---------------------------------------------------------------------------
extern "C" void kernel_launch(void* const* d_in, const int* in_sizes, int n_in,
                              void* d_out, int out_size, void* d_ws, size_t ws_size,
                              hipStream_t stream)
{
    static const int expected[24] = {
        12800000, 12800000, 65536, 65536, 512, 512, 65536, 65536,
        65536, 65536, 65536, 512, 65536, 256, 65536, 256, 1, 1,
        400000, 400000, 400000, 400000, 400000, 400000};
    float marker = 0.f;
    if (n_in != 24) marker = 500.f;
    else {
        for (int i = 0; i < 24; ++i)
            if (in_sizes[i] != expected[i]) { marker = 200.f + 8.f * i; break; }
    }
    if (marker == 0.f && out_size != 25600000) marker = 600.f + (float)(out_size / 1000000);
    if (marker == 0.f && ws_size < 51200000ull) marker = 1000.f + (float)(ws_size / 1000000ull);
    if (marker != 0.f) {
        fill_marker<<<(out_size + 255) / 256, 256, 0, stream>>>((float*)d_out, out_size, marker);
        return;
    }

    const float* feats_a  = (const float*)d_in[0];
    const float* feats_p  = (const float*)d_in[1];
    const float* W_mic_a  = (const float*)d_in[2];
    const float* W_mic_p  = (const float*)d_in[3];
    const float* attn_a   = (const float*)d_in[4];
    const float* attn_p   = (const float*)d_in[5];
    const float* W_node_p = (const float*)d_in[7];
    const float* W_rel_w  = (const float*)d_in[8];
    const float* W_rel_wb = (const float*)d_in[9];
    const float* W_rel_c  = (const float*)d_in[10];
    const float* attn_mac = (const float*)d_in[11];
    const float* W_res_a  = (const float*)d_in[12];
    const float* b_res_a  = (const float*)d_in[13];
    const float* W_res_p  = (const float*)d_in[14];
    const float* b_res_p  = (const float*)d_in[15];
    const float* rw_a     = (const float*)d_in[16];
    const float* rw_p     = (const float*)d_in[17];
    const int* w_src  = (const int*)d_in[18];
    const int* w_dst  = (const int*)d_in[19];
    const int* wb_src = (const int*)d_in[20];
    const int* wb_dst = (const int*)d_in[21];
    const int* c_src  = (const int*)d_in[22];
    const int* c_dst  = (const int*)d_in[23];

    const int NB = N_PAPER * KDIM;            // 12.8M elems
    // ---- d_out (f32, 102.4MB): [author 51.2MB][paper 51.2MB] ----
    float* Oa_f = (float*)d_out;
    float* Op_f = Oa_f + NB;
    bf16* Oa_b = (bf16*)d_out;                // P_a -> r_written_by (author lower)
    bf16* Op_b = (bf16*)Op_f;                 // P_p -> rf_writes    (paper lower)
    char* au_up = (char*)d_out + 25600000;    // author upper 25.6MB
    bf16*  Cslot = (bf16*)au_up;              // r_cites
    bf16*  BTa0  = (bf16*)au_up;              // later: W_res_p BT (Cslot dead)
    bf16*  BTa1  = BTa0 + 65536;              //        W_rel_wb BT
    char* pu = (char*)d_out + 76800000;       // paper upper 25.6MB
    float* dotW = (float*)pu;
    float* dotC = dotW + 400000;
    float* dotL = dotW + 800000;
    float* sc_w = dotW + 1200000;
    float* sc_c = dotW + 1600000;
    float* vbuf = dotW + 2000000;             // 6144 f32
    bf16* BT0 = (bf16*)(pu + 10000000);       // early BT slots (128KB each)
    bf16* BT1 = BT0 + 65536;
    bf16* BT2 = BT1 + 65536;
    bf16* BT3 = BT2 + 65536;
    // ---- d_ws (51.2e6 B): [A_ws 25.6MB][X 25.6MB] ----
    bf16* A_ws = (bf16*)d_ws;                 // r_writes -> fused_paper
    bf16* BTw  = (bf16*)d_ws;                 // W_res_a BT (after fused dead)
    char* Xb   = (char*)d_ws + 25600000;
    float* el_w  = (float*)Xb;                // 5 x 400,000 f32 (8MB)
    float* er_w  = el_w + 400000;
    float* el_p  = el_w + 800000;
    float* er_wb = el_w + 1200000;
    float* er_c  = el_w + 1600000;
    int*  csr    = (int*)(el_w + 2000000);    // 3 x 450004 ints, 16B-aligned
    int*  Tbuf   = csr + 3 * CSR_STRIDE;      // 3 x 400000 ints (bucket-major temp)
    int*  meta   = Tbuf + 3 * NEDGE;          // 885 ints (gbcnt/bbase/grank)
    bf16* Xslot  = (bf16*)Xb;                 // later: rf_written_by (25.6MB)

    dim3 mg(2, (N_PAPER + 127) / 128);
    int hdB = (N_PAPER * NHEAD + 255) / 256;
    int gB  = (N_PAPER + 3) / 4;

    // ---- 1: micro projections (MFMA) ----
    prep_bt<<<256, 256, 0, stream>>>(W_mic_a, BT0);
    prep_bt<<<256, 256, 0, stream>>>(W_mic_p, BT1);
    mfma_gemm<0, float><<<mg, 256, 0, stream>>>(feats_a, BT0, N_AUTHOR, Oa_b,
        nullptr, nullptr, nullptr, nullptr, nullptr, nullptr);
    mfma_gemm<0, float><<<mg, 256, 0, stream>>>(feats_p, BT1, N_PAPER, Op_b,
        nullptr, nullptr, nullptr, nullptr, nullptr, nullptr);

    // ---- 2: micro attention dots (fused per projection read) ----
    head_dot2<<<hdB, 256, 0, stream>>>(Oa_b, attn_a, 0, el_w,
                                       attn_p, 32, er_wb, N_AUTHOR);
    head_dot3<<<hdB, 256, 0, stream>>>(Op_b, attn_a, 32, er_w,
                                       attn_p, 0, el_p,
                                       attn_p, 32, er_c, N_PAPER);

    // ---- 3: bucketed CSR build + GAT gathers (dot epilogues for r0/r2).
    // r0 writes: feat P_a(Oa_b) -> A_ws        (+ dotW epilogue)
    // r1 written_by: feat P_p(Op_b) -> Oa_b (P_a dead after r0 gather)
    // r2 cites: feat P_p(Op_b) -> Cslot        (+ dotC epilogue)
    zero_meta<<<2, 256, 0, stream>>>(meta);
    bucket_count<<<dim3(64, 3), 256, 0, stream>>>(w_dst, wb_dst, c_dst, meta, NEDGE);
    bucket_scan<<<1, 192, 0, stream>>>(meta);
    bucket_scatter<<<dim3(64, 3), 256, 0, stream>>>(w_src, wb_src, c_src,
                                                    w_dst, wb_dst, c_dst,
                                                    meta, Tbuf, NEDGE);
    csr_build<<<dim3(NBUCK, 3), 256, 0, stream>>>(meta, Tbuf, csr);
    prep_v<<<24, 256, 0, stream>>>(W_rel_w, W_rel_c, W_node_p, attn_mac, vbuf);
    {
        const float* rel_el[3] = {el_w, el_p, el_p};
        const float* rel_er[3] = {er_w, er_wb, er_c};
        const bf16* rfeat[3]   = {Oa_b, Op_b, Op_b};
        bf16* rout[3]          = {A_ws, Oa_b, Cslot};
        const float* rdv[3]    = {vbuf, nullptr, vbuf + 2048};
        float* rdo[3]          = {dotW, nullptr, dotC};
        for (int r = 0; r < 3; ++r) {
            int* off  = csr + r * CSR_STRIDE;
            int* gsrc = off + CSR_GSRC;
            gat_gather<<<gB, 256, 0, stream>>>(off, gsrc, rel_el[r], rel_er[r],
                                               rfeat[r], rout[r],
                                               rdv[r], rdo[r], N_PAPER);
        }
    }
    // A_ws=r_writes, Oa_b=r_written_by, Cslot=r_cites; P_p (Op_b) dead.

    // ---- 4: dotL (nontemporal feats_p stream) + relation softmax ----
    macro_dotL<<<gB, 256, 0, stream>>>(feats_p, vbuf + 4096, dotL, N_PAPER);
    score_kernel<<<hdB, 256, 0, stream>>>(dotL, dotW, dotC, sc_w, sc_c, N_PAPER * NHEAD);

    // ---- 5: rf_writes = r_writes(A_ws) @ W_rel_w -> Op_b (P_p dead) ----
    prep_bt<<<256, 256, 0, stream>>>(W_rel_w, BT2);
    mfma_gemm<0, bf16><<<mg, 256, 0, stream>>>(A_ws, BT2, N_PAPER, Op_b,
        nullptr, nullptr, nullptr, nullptr, nullptr, nullptr);
    // ---- 6: fused = sc_w*rf_writes(Op_b) + sc_c*(r_cites(Cslot) @ W_rel_c) -> A_ws ----
    prep_bt<<<256, 256, 0, stream>>>(W_rel_c, BT3);
    mfma_gemm<1, bf16><<<mg, 256, 0, stream>>>(Cslot, BT3, N_PAPER, A_ws,
        nullptr, nullptr, nullptr, Op_b, sc_w, sc_c);
    // ---- 7: paper gated residual -> Op_f FINAL (BT in au_up; Cslot dead) ----
    prep_bt<<<256, 256, 0, stream>>>(W_res_p, BTa0);
    mfma_gemm<2, float><<<mg, 256, 0, stream>>>(feats_p, BTa0, N_PAPER, Op_f,
        b_res_p, A_ws, rw_p, nullptr, nullptr, nullptr);
    // ---- 8: rf_written_by = r_written_by(Oa_b) @ W_rel_wb -> Xslot (CSR dead) ----
    prep_bt<<<256, 256, 0, stream>>>(W_rel_wb, BTa1);
    mfma_gemm<0, bf16><<<mg, 256, 0, stream>>>(Oa_b, BTa1, N_AUTHOR, Xslot,
        nullptr, nullptr, nullptr, nullptr, nullptr, nullptr);
    // ---- 9: author gated residual -> Oa_f FINAL (BT in A_ws; fused dead) ----
    prep_bt<<<256, 256, 0, stream>>>(W_res_a, BTw);
    mfma_gemm<2, float><<<mg, 256, 0, stream>>>(feats_a, BTw, N_AUTHOR, Oa_f,
        b_res_a, Xslot, rw_a, nullptr, nullptr, nullptr);
}

// Round 7
// 771.255 us; speedup vs baseline: 1.7009x; 1.0531x over previous
//
#include <hip/hip_runtime.h>
#include <hip/hip_bf16.h>
#include <type_traits>

// HGConv layer: micro (per-relation GAT) + macro (semantic attention) + gated residual.
// I/O: float32 (verified round 6). Internals: bf16 matrices, f32 accumulation.
// Round 8-10: on-device bucketed CSR build + gather-based edge stage.
// Round 11-12: macro scores via gather epilogues + nt dotL pass.
// Round 14: gat_gather 8-edge chunked metadata phase (8x MLP).
// Round 15: GEMM stage restructure. Was 8 dispatches x ~66us at MfmaUtil 3.5%,
// FETCH 63MB each (128x128 tiles read A twice; chains materialized rf_* to HBM).
// Now: 64x256 tiles (A read once, B L2-resident), steps 5+6+7 fused into one
// 3-pass register-resident gemm_paper (rf_writes never hits HBM), steps 8+9 via
// d_ws staging. Late BTs + sc_w/sc_c relocated to d_ws upper so gemm_paper's
// f32 output (which spans the old pu scratch) clobbers only dead data.

#define N_AUTHOR 50000
#define N_PAPER  50000
#define NEDGE    400000
#define KDIM     256
#define NHEAD    8
#define SLOPE    0.2f

#define BUCK_W   512                    // dsts per bucket (shift 9)
#define NBUCK    98                     // ceil(50000/512)
#define SBUF_CAP 6144                   // LDS staging cap (span ~4096+-64)

// CSR slab (ints): off@0 (50001 used, pad 50004), gsrc@50004 (400000).
#define CSR_STRIDE 450004
#define CSR_GSRC   50004

using bf16 = __hip_bfloat16;
typedef __attribute__((ext_vector_type(8))) short short8;
typedef __attribute__((ext_vector_type(4))) float float4e;

__device__ __forceinline__ float us2f(unsigned short u) {
    return __uint_as_float(((unsigned int)u) << 16);
}
__device__ __forceinline__ float fin(float v) {   // 0 if NaN/Inf
    return (((__float_as_uint(v) >> 23) & 0xFF) != 0xFF) ? v : 0.f;
}
__device__ __forceinline__ unsigned short f2bu(float f) {
    f = fin(f);
    bf16 h = __float2bfloat16(f);
    return *reinterpret_cast<unsigned short*>(&h);
}
__device__ __forceinline__ int clampi(int v, int hi) {
    return v < 0 ? 0 : (v >= hi ? hi - 1 : v);
}

__global__ void fill_marker(float* __restrict__ out, int total, float c)
{
    int i = blockIdx.x * blockDim.x + threadIdx.x;
    if (i < total) out[i] = c;
}

// ---------------------------------------------------------------------------
// Shuffle-tree head reduce (8-lane col group per head).
// ---------------------------------------------------------------------------
__device__ __forceinline__ float sel8(const float p[8], int j)
{
    float q = p[0];
    q = j == 1 ? p[1] : q; q = j == 2 ? p[2] : q; q = j == 3 ? p[3] : q;
    q = j == 4 ? p[4] : q; q = j == 5 ? p[5] : q; q = j == 6 ? p[6] : q;
    q = j == 7 ? p[7] : q;
    return q;
}

__device__ __forceinline__ float head_reduce(float p[8], int lane)
{
    #pragma unroll
    for (int h = 0; h < 8; ++h) {
        p[h] += __shfl_xor(p[h], 1);
        p[h] += __shfl_xor(p[h], 2);
        p[h] += __shfl_xor(p[h], 4);
    }
    float q = sel8(p, lane & 7);
    q += __shfl_xor(q, 8);
    q += __shfl_xor(q, 16);
    q += __shfl_xor(q, 32);
    return q;
}

// ---------------------------------------------------------------------------
// W[256k][256n] f32  ->  BT[256n][256k] bf16  (pre-transpose for MFMA B-frags)
// ---------------------------------------------------------------------------
__global__ void prep_bt(const float* __restrict__ W, bf16* __restrict__ BT)
{
    int n = blockIdx.x, k = threadIdx.x;
    reinterpret_cast<unsigned short*>(BT)[n * KDIM + k] = f2bu(W[k * KDIM + n]);
}

// ---------------------------------------------------------------------------
// GEMM core: one K-sweep accumulating a 64x256 tile (256 thr = 4 waves, each
// wave a 64x64 quadrant, 4x4 frags). A read once per tile (BN=256, grid.x=1).
// ---------------------------------------------------------------------------
template<typename TA>
__device__ __forceinline__ void gemm_pass(
    const TA* __restrict__ A, const bf16* __restrict__ BT, int M, int rowBase,
    short* As, short* Bs, float4e acc[4][4], int tid, int lane, int wn)
{
    const int srow = tid >> 2;          // 0..63
    const int sq = (tid & 3) << 3;      // 0,8,16,24
    #pragma unroll
    for (int i = 0; i < 4; ++i)
        #pragma unroll
        for (int j = 0; j < 4; ++j) {
            float4e z = {0.f, 0.f, 0.f, 0.f};
            acc[i][j] = z;
        }
    for (int kt = 0; kt < KDIM; kt += 32) {
        {
            int gr = rowBase + srow;
            short8 v = {0, 0, 0, 0, 0, 0, 0, 0};
            if (gr < M) {
                if constexpr (std::is_same<TA, float>::value) {
                    const float* ap = A + (size_t)gr * KDIM + kt + sq;
                    float4 x = *reinterpret_cast<const float4*>(ap);
                    float4 y = *reinterpret_cast<const float4*>(ap + 4);
                    v[0] = (short)f2bu(x.x); v[1] = (short)f2bu(x.y);
                    v[2] = (short)f2bu(x.z); v[3] = (short)f2bu(x.w);
                    v[4] = (short)f2bu(y.x); v[5] = (short)f2bu(y.y);
                    v[6] = (short)f2bu(y.z); v[7] = (short)f2bu(y.w);
                } else {
                    v = *reinterpret_cast<const short8*>(
                        reinterpret_cast<const short*>(A) + (size_t)gr * KDIM + kt + sq);
                }
            }
            *reinterpret_cast<short8*>(&As[srow * 40 + sq]) = v;
        }
        #pragma unroll
        for (int p = 0; p < 4; ++p) {
            int n = srow + p * 64;
            short8 v = *reinterpret_cast<const short8*>(
                reinterpret_cast<const short*>(BT) + (size_t)n * KDIM + kt + sq);
            *reinterpret_cast<short8*>(&Bs[n * 40 + sq]) = v;
        }
        __syncthreads();
        short8 af[4], bg[4];
        #pragma unroll
        for (int i = 0; i < 4; ++i)
            af[i] = *reinterpret_cast<const short8*>(
                &As[(i * 16 + (lane & 15)) * 40 + ((lane >> 4) << 3)]);
        #pragma unroll
        for (int j = 0; j < 4; ++j)
            bg[j] = *reinterpret_cast<const short8*>(
                &Bs[(wn * 64 + j * 16 + (lane & 15)) * 40 + ((lane >> 4) << 3)]);
        #pragma unroll
        for (int i = 0; i < 4; ++i)
            #pragma unroll
            for (int j = 0; j < 4; ++j)
                acc[i][j] = __builtin_amdgcn_mfma_f32_16x16x32_bf16(
                    af[i], bg[j], acc[i][j], 0, 0, 0);
        __syncthreads();
    }
}

// C(bf16) = A @ B
template<typename TA>
__global__ __launch_bounds__(256) void gemm_c16(
    const TA* __restrict__ A, const bf16* __restrict__ BT, int M,
    bf16* __restrict__ C)
{
    __shared__ short As[64 * 40];
    __shared__ short Bs[256 * 40];
    const int tid = threadIdx.x, lane = tid & 63, wn = tid >> 6;
    const int rowBase = blockIdx.x * 64;
    float4e acc[4][4];
    gemm_pass(A, BT, M, rowBase, As, Bs, acc, tid, lane, wn);
    #pragma unroll
    for (int i = 0; i < 4; ++i) {
        int r0 = rowBase + i * 16 + ((lane >> 4) << 2);
        #pragma unroll
        for (int j = 0; j < 4; ++j) {
            int col = wn * 64 + j * 16 + (lane & 15);
            #pragma unroll
            for (int reg = 0; reg < 4; ++reg) {
                int row = r0 + reg;
                if (row < M)
                    reinterpret_cast<unsigned short*>(C)[(size_t)row * KDIM + col] =
                        f2bu(acc[i][j][reg]);
            }
        }
    }
}

// Paper fusion (old steps 5+6+7 in one kernel, rf_* stay in registers):
// C(f32) = al*(sc_w*(A1@B1) + sc_c*(A2@B2)) + (1-al)*((A3@B3) + bias)
__global__ __launch_bounds__(256) void gemm_paper(
    const bf16* __restrict__ A1, const bf16* __restrict__ BT1,
    const bf16* __restrict__ A2, const bf16* __restrict__ BT2,
    const float* __restrict__ A3, const bf16* __restrict__ BT3, int M,
    const float* __restrict__ sc_w, const float* __restrict__ sc_c,
    const float* __restrict__ gate, const float* __restrict__ bias,
    float* __restrict__ C)
{
    __shared__ short As[64 * 40];
    __shared__ short Bs[256 * 40];
    const int tid = threadIdx.x, lane = tid & 63, wn = tid >> 6;
    const int rowBase = blockIdx.x * 64;
    float4e accA[4][4], accB[4][4];
    gemm_pass(A1, BT1, M, rowBase, As, Bs, accA, tid, lane, wn);
    gemm_pass(A2, BT2, M, rowBase, As, Bs, accB, tid, lane, wn);
    #pragma unroll
    for (int i = 0; i < 4; ++i) {
        int r0 = rowBase + i * 16 + ((lane >> 4) << 2);
        #pragma unroll
        for (int j = 0; j < 4; ++j) {
            int h = (wn * 64 + j * 16 + (lane & 15)) >> 5;
            #pragma unroll
            for (int reg = 0; reg < 4; ++reg) {
                int row = r0 + reg;
                int rc = row < M ? row : M - 1;
                size_t si = (size_t)rc * NHEAD + h;
                accA[i][j][reg] = sc_w[si] * accA[i][j][reg]
                                + sc_c[si] * accB[i][j][reg];
            }
        }
    }
    gemm_pass(A3, BT3, M, rowBase, As, Bs, accB, tid, lane, wn);
    float al = 1.f / (1.f + expf(-gate[0]));
    #pragma unroll
    for (int i = 0; i < 4; ++i) {
        int r0 = rowBase + i * 16 + ((lane >> 4) << 2);
        #pragma unroll
        for (int j = 0; j < 4; ++j) {
            int col = wn * 64 + j * 16 + (lane & 15);
            #pragma unroll
            for (int reg = 0; reg < 4; ++reg) {
                int row = r0 + reg;
                if (row < M)
                    C[(size_t)row * KDIM + col] =
                        fin(al * accA[i][j][reg]
                            + (1.f - al) * (accB[i][j][reg] + bias[col]));
            }
        }
    }
}

// Gated residual: C(f32) = al*other(bf16) + (1-al)*((A@B) + bias)
__global__ __launch_bounds__(256) void gemm_resid(
    const float* __restrict__ A, const bf16* __restrict__ BT, int M,
    const bf16* __restrict__ other, const float* __restrict__ gate,
    const float* __restrict__ bias, float* __restrict__ C)
{
    __shared__ short As[64 * 40];
    __shared__ short Bs[256 * 40];
    const int tid = threadIdx.x, lane = tid & 63, wn = tid >> 6;
    const int rowBase = blockIdx.x * 64;
    float4e acc[4][4];
    gemm_pass(A, BT, M, rowBase, As, Bs, acc, tid, lane, wn);
    float al = 1.f / (1.f + expf(-gate[0]));
    #pragma unroll
    for (int i = 0; i < 4; ++i) {
        int r0 = rowBase + i * 16 + ((lane >> 4) << 2);
        #pragma unroll
        for (int j = 0; j < 4; ++j) {
            int col = wn * 64 + j * 16 + (lane & 15);
            #pragma unroll
            for (int reg = 0; reg < 4; ++reg) {
                int row = r0 + reg;
                if (row < M) {
                    size_t idx = (size_t)row * KDIM + col;
                    float of = us2f(reinterpret_cast<const unsigned short*>(other)[idx]);
                    C[idx] = fin(al * of + (1.f - al) * (acc[i][j][reg] + bias[col]));
                }
            }
        }
    }
}

// ---------------------------------------------------------------------------
// Per-node per-head attention dots (micro): one projection-row read, 2-3 dots.
// ---------------------------------------------------------------------------
__global__ void head_dot2(const bf16* __restrict__ proj,
                          const float* __restrict__ aA, int offA, float* __restrict__ oA,
                          const float* __restrict__ aB, int offB, float* __restrict__ oB,
                          int N)
{
    int gid = blockIdx.x * blockDim.x + threadIdx.x;
    if (gid >= N * NHEAD) return;
    int n = gid >> 3, k = gid & 7;
    const unsigned short* p =
        reinterpret_cast<const unsigned short*>(proj) + (size_t)n * KDIM + k * 32;
    const float* a = aA + k * 64 + offA;
    const float* b = aB + k * 64 + offB;
    float sA = 0.f, sB = 0.f;
    #pragma unroll
    for (int d0 = 0; d0 < 32; d0 += 4) {
        ushort4 pv = *reinterpret_cast<const ushort4*>(p + d0);
        float4 av = *reinterpret_cast<const float4*>(a + d0);
        float4 bv = *reinterpret_cast<const float4*>(b + d0);
        float f0 = us2f(pv.x), f1 = us2f(pv.y), f2 = us2f(pv.z), f3 = us2f(pv.w);
        sA += f0 * av.x + f1 * av.y + f2 * av.z + f3 * av.w;
        sB += f0 * bv.x + f1 * bv.y + f2 * bv.z + f3 * bv.w;
    }
    oA[gid] = fin(sA);
    oB[gid] = fin(sB);
}

__global__ void head_dot3(const bf16* __restrict__ proj,
                          const float* __restrict__ aA, int offA, float* __restrict__ oA,
                          const float* __restrict__ aB, int offB, float* __restrict__ oB,
                          const float* __restrict__ aC, int offC, float* __restrict__ oC,
                          int N)
{
    int gid = blockIdx.x * blockDim.x + threadIdx.x;
    if (gid >= N * NHEAD) return;
    int n = gid >> 3, k = gid & 7;
    const unsigned short* p =
        reinterpret_cast<const unsigned short*>(proj) + (size_t)n * KDIM + k * 32;
    const float* a = aA + k * 64 + offA;
    const float* b = aB + k * 64 + offB;
    const float* c = aC + k * 64 + offC;
    float sA = 0.f, sB = 0.f, sC = 0.f;
    #pragma unroll
    for (int d0 = 0; d0 < 32; d0 += 4) {
        ushort4 pv = *reinterpret_cast<const ushort4*>(p + d0);
        float4 av = *reinterpret_cast<const float4*>(a + d0);
        float4 bv = *reinterpret_cast<const float4*>(b + d0);
        float4 cv = *reinterpret_cast<const float4*>(c + d0);
        float f0 = us2f(pv.x), f1 = us2f(pv.y), f2 = us2f(pv.z), f3 = us2f(pv.w);
        sA += f0 * av.x + f1 * av.y + f2 * av.z + f3 * av.w;
        sB += f0 * bv.x + f1 * bv.y + f2 * bv.z + f3 * bv.w;
        sC += f0 * cv.x + f1 * cv.y + f2 * cv.z + f3 * cv.w;
    }
    oA[gid] = fin(sA);
    oB[gid] = fin(sB);
    oC[gid] = fin(sC);
}

// ---------------------------------------------------------------------------
// Bucketed CSR build (relation = blockIdx.y).
// meta layout (ints): gbcnt[3][NBUCK] @0, bbase[3][NBUCK+1] @294, grank[3][NBUCK] @591
// ---------------------------------------------------------------------------
__global__ void zero_meta(int* __restrict__ meta)
{
    int i = threadIdx.x + blockIdx.x * blockDim.x;
    if (i < 3 * NBUCK) meta[i] = 0;                       // gbcnt
    if (i < 3 * NBUCK) meta[591 + i] = 0;                 // grank
}

__global__ __launch_bounds__(256) void bucket_count(
    const int* __restrict__ d0, const int* __restrict__ d1,
    const int* __restrict__ d2, int* __restrict__ meta, int E)
{
    __shared__ int cnt[NBUCK];
    for (int i = threadIdx.x; i < NBUCK; i += 256) cnt[i] = 0;
    __syncthreads();
    int r = blockIdx.y;
    const int* d = r == 0 ? d0 : (r == 1 ? d1 : d2);
    for (int e = blockIdx.x * 256 + threadIdx.x; e < E; e += gridDim.x * 256)
        atomicAdd(&cnt[clampi(d[e], N_PAPER) >> 9], 1);
    __syncthreads();
    for (int i = threadIdx.x; i < NBUCK; i += 256)
        if (cnt[i]) atomicAdd(&meta[r * NBUCK + i], cnt[i]);
}

// 3 waves, one per relation: shuffle-scan NBUCK bucket counts -> bases.
__global__ void bucket_scan(int* __restrict__ meta)
{
    int r = threadIdx.x >> 6, lane = threadIdx.x & 63;
    if (r >= 3) return;
    const int* gbcnt = meta + r * NBUCK;
    int* bbase = meta + 294 + r * (NBUCK + 1);
    int carry = 0;
    for (int base = 0; base < NBUCK; base += 64) {
        int i = base + lane;
        int v = (i < NBUCK) ? gbcnt[i] : 0;
        int x = v;
        #pragma unroll
        for (int o = 1; o < 64; o <<= 1) {
            int t = __shfl_up(x, o, 64);
            if (lane >= o) x += t;
        }
        if (i < NBUCK) bbase[i] = carry + x - v;
        carry += __shfl(x, 63, 64);
    }
    if (lane == 0) bbase[NBUCK] = carry;
}

// Scatter edges into bucket-major temp T, packed (src<<9)|dlocal (25 bits).
__global__ __launch_bounds__(256) void bucket_scatter(
    const int* __restrict__ s0, const int* __restrict__ s1,
    const int* __restrict__ s2,
    const int* __restrict__ d0, const int* __restrict__ d1,
    const int* __restrict__ d2,
    int* __restrict__ meta, int* __restrict__ T, int E)
{
    __shared__ int cnt[NBUCK];
    __shared__ int base[NBUCK];
    int r = blockIdx.y;
    const int* s = r == 0 ? s0 : (r == 1 ? s1 : s2);
    const int* d = r == 0 ? d0 : (r == 1 ? d1 : d2);
    const int* bbase = meta + 294 + r * (NBUCK + 1);
    int* grank = meta + 591 + r * NBUCK;
    int* Tr = T + r * NEDGE;

    for (int i = threadIdx.x; i < NBUCK; i += 256) cnt[i] = 0;
    __syncthreads();

    const int CH = (E + gridDim.x - 1) / gridDim.x;
    int e0 = blockIdx.x * CH;
    int e1 = min(e0 + CH, E);
    for (int e = e0 + threadIdx.x; e < e1; e += 256)
        atomicAdd(&cnt[clampi(d[e], N_PAPER) >> 9], 1);
    __syncthreads();
    if (threadIdx.x < NBUCK) {
        int c = cnt[threadIdx.x];
        base[threadIdx.x] = c ? bbase[threadIdx.x] + atomicAdd(&grank[threadIdx.x], c) : 0;
        cnt[threadIdx.x] = 0;            // reuse as local rank
    }
    __syncthreads();
    for (int e = e0 + threadIdx.x; e < e1; e += 256) {
        int dc = clampi(d[e], N_PAPER);
        int b = dc >> 9, dl = dc & 511;
        int l = atomicAdd(&cnt[b], 1);
        Tr[base[b] + l] = (clampi(s[e], N_PAPER) << 9) | dl;
    }
}

// Per (bucket, relation): LDS per-dst hist + scan -> off[] (coalesced), then
// LDS scatter + coalesced gsrc stream-out.
__global__ __launch_bounds__(256) void csr_build(
    const int* __restrict__ meta, const int* __restrict__ T,
    int* __restrict__ csr)
{
    __shared__ int cnt[512];
    __shared__ int loc[512];
    __shared__ int sbuf[SBUF_CAP];
    __shared__ int wtot[4];
    int b = blockIdx.x, r = blockIdx.y;
    const int* bbase = meta + 294 + r * (NBUCK + 1);
    const int* Tr = T + r * NEDGE;
    int* off = csr + r * CSR_STRIDE;
    int* gsrc = off + CSR_GSRC;
    const int tid = threadIdx.x, lane = tid & 63, wv = tid >> 6;

    int dstbase = b << 9;
    int nd = min(512, N_PAPER - dstbase);
    int cbase = bbase[b], cend = bbase[b + 1];
    int span = cend - cbase;

    cnt[2 * tid] = 0; cnt[2 * tid + 1] = 0;
    __syncthreads();
    for (int t = tid; t < span; t += 256)
        atomicAdd(&cnt[Tr[cbase + t] & 511], 1);
    __syncthreads();

    int v0 = cnt[2 * tid], v1 = cnt[2 * tid + 1];
    int sthr = v0 + v1;
    int x = sthr;
    #pragma unroll
    for (int o = 1; o < 64; o <<= 1) {
        int t = __shfl_up(x, o, 64);
        if (lane >= o) x += t;
    }
    if (lane == 63) wtot[wv] = x;
    __syncthreads();
    int wexc = 0;
    #pragma unroll
    for (int w = 0; w < 4; ++w)
        if (w < wv) wexc += wtot[w];
    int exc = wexc + x - sthr;
    loc[2 * tid] = exc;
    loc[2 * tid + 1] = exc + v0;
    int i0 = 2 * tid, i1 = 2 * tid + 1;
    if (i0 < nd) off[dstbase + i0] = cbase + exc;
    if (i1 < nd) off[dstbase + i1] = cbase + exc + v0;
    if (b == NBUCK - 1 && tid == 0) off[N_PAPER] = cend;
    cnt[i0] = 0; cnt[i1] = 0;            // reuse as per-dst rank
    __syncthreads();

    if (span <= SBUF_CAP) {
        for (int t = tid; t < span; t += 256) {
            int v = Tr[cbase + t];
            int dl = v & 511;
            int pos = loc[dl] + atomicAdd(&cnt[dl], 1);
            sbuf[pos] = v >> 9;
        }
        __syncthreads();
        for (int t = tid; t < span; t += 256)
            gsrc[cbase + t] = sbuf[t];
    } else {                              // never expected; correctness fallback
        for (int t = tid; t < span; t += 256) {
            int v = Tr[cbase + t];
            int dl = v & 511;
            int pos = loc[dl] + atomicAdd(&cnt[dl], 1);
            gsrc[cbase + pos] = v >> 9;
        }
    }
}

// ---------------------------------------------------------------------------
// GAT gather: one wave per dst node; 8-edge chunked metadata phase (round 14).
// Optional epilogue (dv != null): macro head-dot of the relu'd output row.
// ---------------------------------------------------------------------------
__global__ __launch_bounds__(256) void gat_gather(
    const int* __restrict__ off, const int* __restrict__ gsrc,
    const float* __restrict__ el, const float* __restrict__ er,
    const bf16* __restrict__ feat, bf16* __restrict__ out,
    const float* __restrict__ dv, float* __restrict__ dout, int N)
{
    __shared__ float vlds[2048];
    if (dv) {
        #pragma unroll
        for (int i = 0; i < 2; ++i) {
            int idx = (i * 256 + threadIdx.x) * 4;
            *reinterpret_cast<float4*>(&vlds[idx]) =
                *reinterpret_cast<const float4*>(&dv[idx]);
        }
        __syncthreads();
    }
    int d = blockIdx.x * 4 + (threadIdx.x >> 6);
    if (d >= N) return;
    int lane = threadIdx.x & 63;
    int hL = lane >> 3;
    int col = lane * 4;
    int ep = lane >> 3, hM = lane & 7;
    float erdM = er[d * NHEAD + hM];
    int e0 = off[d], e1 = off[d + 1];
    float denom = 0.f, a0 = 0.f, a1 = 0.f, a2 = 0.f, a3 = 0.f;
    for (int e = e0; e < e1; e += 8) {
        int nc = e1 - e; nc = nc > 8 ? 8 : nc;
        int sM = 0; float exM = 0.f;
        if (ep < nc) {
            sM = gsrc[e + ep];
            float v = el[sM * NHEAD + hM] + erdM;
            v = v > 0.f ? v : SLOPE * v;
            exM = expf(fminf(v, 30.f));
        }
        #pragma unroll
        for (int q = 0; q < 8; ++q) {
            if (q < nc) {
                float ex = __shfl(exM, q * 8 + hL);
                int s = __shfl(sM, q * 8);
                denom += ex;
                ushort4 fv = *reinterpret_cast<const ushort4*>(
                    reinterpret_cast<const unsigned short*>(feat) + (size_t)s * KDIM + col);
                a0 = fmaf(us2f(fv.x), ex, a0); a1 = fmaf(us2f(fv.y), ex, a1);
                a2 = fmaf(us2f(fv.z), ex, a2); a3 = fmaf(us2f(fv.w), ex, a3);
            }
        }
    }
    float inv = 1.f / fmaxf(denom, 1e-20f);
    float o0 = fmaxf(a0 * inv, 0.f), o1 = fmaxf(a1 * inv, 0.f);
    float o2 = fmaxf(a2 * inv, 0.f), o3 = fmaxf(a3 * inv, 0.f);
    ushort4 o;
    o.x = f2bu(o0); o.y = f2bu(o1); o.z = f2bu(o2); o.w = f2bu(o3);
    *reinterpret_cast<ushort4*>(
        reinterpret_cast<unsigned short*>(out) + (size_t)d * KDIM + col) = o;
    if (dv) {
        float p[8];
        #pragma unroll
        for (int hh = 0; hh < 8; ++hh) {
            float4 vv = *reinterpret_cast<const float4*>(&vlds[hh * 256 + col]);
            p[hh] = o0 * vv.x + o1 * vv.y + o2 * vv.z + o3 * vv.w;
        }
        float q = head_reduce(p, lane);
        if (lane < 8) dout[d * NHEAD + lane] = fin(q);
    }
}

// ---------------------------------------------------------------------------
// Macro score vectors + dotL pass + relation softmax
// ---------------------------------------------------------------------------
__global__ void prep_v(const float* __restrict__ Ww, const float* __restrict__ Wc,
                       const float* __restrict__ Wn, const float* __restrict__ attn,
                       float* __restrict__ vbuf)
{
    int id = blockIdx.x * blockDim.x + threadIdx.x;
    if (id >= 3 * 2048) return;
    int which = id >> 11;
    int rem = id & 2047;
    int h = rem >> 8, k = rem & 255;
    const float* Wsrc = which == 0 ? Ww : (which == 1 ? Wc : Wn);
    int aoff = which == 2 ? 0 : 32;
    float s = 0.f;
    #pragma unroll 8
    for (int d = 0; d < 32; ++d)
        s += Wsrc[(size_t)k * KDIM + h * 32 + d] * attn[h * 64 + aoff + d];
    vbuf[which * 2048 + h * 256 + k] = fin(s);
}

// One wave per paper row: dotL[n,h] = feats_p[n,:] . vL[h,:]; nt loads.
__global__ __launch_bounds__(256) void macro_dotL(
    const float* __restrict__ Af, const float* __restrict__ vL,
    float* __restrict__ dout, int N)
{
    __shared__ float vlds[2048];
    #pragma unroll
    for (int i = 0; i < 2; ++i) {
        int idx = (i * 256 + threadIdx.x) * 4;
        *reinterpret_cast<float4*>(&vlds[idx]) =
            *reinterpret_cast<const float4*>(&vL[idx]);
    }
    __syncthreads();
    int n = blockIdx.x * 4 + (threadIdx.x >> 6);
    if (n >= N) return;
    int lane = threadIdx.x & 63;
    int col = lane * 4;
    float4e afv = __builtin_nontemporal_load(
        reinterpret_cast<const float4e*>(Af + (size_t)n * KDIM + col));
    float p[8];
    #pragma unroll
    for (int h = 0; h < 8; ++h) {
        float4 vv = *reinterpret_cast<const float4*>(&vlds[h * 256 + col]);
        p[h] = afv.x * vv.x + afv.y * vv.y + afv.z * vv.z + afv.w * vv.w;
    }
    float q = head_reduce(p, lane);
    if (lane < 8) dout[n * NHEAD + lane] = fin(q);
}

__global__ void score_kernel(const float* __restrict__ dotL, const float* __restrict__ dotW,
                             const float* __restrict__ dotC,
                             float* __restrict__ ow, float* __restrict__ oc, int total)
{
    int i = blockIdx.x * blockDim.x + threadIdx.x;
    if (i >= total) return;
    float sw = dotL[i] + dotW[i]; sw = sw > 0.f ? sw : SLOPE * sw;
    float sc = dotL[i] + dotC[i]; sc = sc > 0.f ? sc : SLOPE * sc;
    float m = fmaxf(sw, sc);
    float ew = expf(sw - m), ec = expf(sc - m);
    float inv = 1.f / (ew + ec);
    ow[i] = fin(ew * inv);
    oc[i] = fin(ec * inv);
}

// ---------------------------------------------------------------------------
extern "C" void kernel_launch(void* const* d_in, const int* in_sizes, int n_in,
                              void* d_out, int out_size, void* d_ws, size_t ws_size,
                              hipStream_t stream)
{
    static const int expected[24] = {
        12800000, 12800000, 65536, 65536, 512, 512, 65536, 65536,
        65536, 65536, 65536, 512, 65536, 256, 65536, 256, 1, 1,
        400000, 400000, 400000, 400000, 400000, 400000};
    float marker = 0.f;
    if (n_in != 24) marker = 500.f;
    else {
        for (int i = 0; i < 24; ++i)
            if (in_sizes[i] != expected[i]) { marker = 200.f + 8.f * i; break; }
    }
    if (marker == 0.f && out_size != 25600000) marker = 600.f + (float)(out_size / 1000000);
    if (marker == 0.f && ws_size < 51200000ull) marker = 1000.f + (float)(ws_size / 1000000ull);
    if (marker != 0.f) {
        fill_marker<<<(out_size + 255) / 256, 256, 0, stream>>>((float*)d_out, out_size, marker);
        return;
    }

    const float* feats_a  = (const float*)d_in[0];
    const float* feats_p  = (const float*)d_in[1];
    const float* W_mic_a  = (const float*)d_in[2];
    const float* W_mic_p  = (const float*)d_in[3];
    const float* attn_a   = (const float*)d_in[4];
    const float* attn_p   = (const float*)d_in[5];
    const float* W_node_p = (const float*)d_in[7];
    const float* W_rel_w  = (const float*)d_in[8];
    const float* W_rel_wb = (const float*)d_in[9];
    const float* W_rel_c  = (const float*)d_in[10];
    const float* attn_mac = (const float*)d_in[11];
    const float* W_res_a  = (const float*)d_in[12];
    const float* b_res_a  = (const float*)d_in[13];
    const float* W_res_p  = (const float*)d_in[14];
    const float* b_res_p  = (const float*)d_in[15];
    const float* rw_a     = (const float*)d_in[16];
    const float* rw_p     = (const float*)d_in[17];
    const int* w_src  = (const int*)d_in[18];
    const int* w_dst  = (const int*)d_in[19];
    const int* wb_src = (const int*)d_in[20];
    const int* wb_dst = (const int*)d_in[21];
    const int* c_src  = (const int*)d_in[22];
    const int* c_dst  = (const int*)d_in[23];

    const int NB = N_PAPER * KDIM;            // 12.8M elems
    // ---- d_out (f32, 102.4MB): [author 51.2MB][paper 51.2MB] ----
    // Oa_f spans [0,51.2M) = author-lower + au_up; Op_f spans [51.2,102.4M) =
    // paper-lower + pu. Final f32 writes clobber au_up/pu -> everything live at
    // that point must be in d_ws or inputs.
    float* Oa_f = (float*)d_out;
    float* Op_f = Oa_f + NB;
    bf16* Oa_b = (bf16*)d_out;                // P_a -> r_written_by (author lower)
    bf16* Op_b = (bf16*)Op_f;                 // P_p (paper lower)
    char* au_up = (char*)d_out + 25600000;    // author upper 25.6MB
    bf16*  Cslot = (bf16*)au_up;              // r_cites (dead before Oa_f write)
    char* pu = (char*)d_out + 76800000;       // paper upper 25.6MB (scratch, dead
                                              // before Op_f write)
    float* dotW = (float*)pu;
    float* dotC = dotW + 400000;
    float* dotL = dotW + 800000;
    float* vbuf = dotW + 1200000;             // 6144 f32
    bf16* BT0 = (bf16*)(pu + 10000000);       // early BTs (consumed by projections)
    bf16* BT1 = BT0 + 65536;
    // ---- d_ws (51.2e6 B): [A_ws 25.6MB][Xb 25.6MB] ----
    bf16* A_ws = (bf16*)d_ws;                 // r_writes -> (later) rf_written_by
    char* Xb   = (char*)d_ws + 25600000;
    float* el_w  = (float*)Xb;                // 5 x 400,000 f32 (8MB) [edge phase]
    float* er_w  = el_w + 400000;
    float* el_p  = el_w + 800000;
    float* er_wb = el_w + 1200000;
    float* er_c  = el_w + 1600000;
    int*  csr    = (int*)(el_w + 2000000);    // 3 x 450004 ints [edge phase]
    int*  Tbuf   = csr + 3 * CSR_STRIDE;      // 3 x 400000 ints
    int*  meta   = Tbuf + 3 * NEDGE;          // 885 ints
    // after gathers (el/csr dead): sc + late BTs live in Xb
    float* sc_w = (float*)Xb;                 // 1.6MB (over dead el_w)
    float* sc_c = sc_w + 400000;              // 1.6MB (over dead er_w)
    bf16* BT2 = (bf16*)(Xb + 8000000);        // over dead csr region
    bf16* BT3 = BT2 + 65536;
    bf16* BT4 = BT3 + 65536;
    bf16* BT5 = BT4 + 65536;
    bf16* BT6 = BT5 + 65536;

    int gemB = (N_PAPER + 63) / 64;           // 782
    int hdB = (N_PAPER * NHEAD + 255) / 256;
    int gB  = (N_PAPER + 3) / 4;

    // ---- 1: micro projections (MFMA, 64x256 tiles) ----
    prep_bt<<<256, 256, 0, stream>>>(W_mic_a, BT0);
    prep_bt<<<256, 256, 0, stream>>>(W_mic_p, BT1);
    gemm_c16<float><<<gemB, 256, 0, stream>>>(feats_a, BT0, N_AUTHOR, Oa_b);
    gemm_c16<float><<<gemB, 256, 0, stream>>>(feats_p, BT1, N_PAPER, Op_b);

    // ---- 2: micro attention dots (fused per projection read) ----
    head_dot2<<<hdB, 256, 0, stream>>>(Oa_b, attn_a, 0, el_w,
                                       attn_p, 32, er_wb, N_AUTHOR);
    head_dot3<<<hdB, 256, 0, stream>>>(Op_b, attn_a, 32, er_w,
                                       attn_p, 0, el_p,
                                       attn_p, 32, er_c, N_PAPER);

    // ---- 3: bucketed CSR build + GAT gathers (dot epilogues for r0/r2) ----
    zero_meta<<<2, 256, 0, stream>>>(meta);
    bucket_count<<<dim3(64, 3), 256, 0, stream>>>(w_dst, wb_dst, c_dst, meta, NEDGE);
    bucket_scan<<<1, 192, 0, stream>>>(meta);
    bucket_scatter<<<dim3(64, 3), 256, 0, stream>>>(w_src, wb_src, c_src,
                                                    w_dst, wb_dst, c_dst,
                                                    meta, Tbuf, NEDGE);
    csr_build<<<dim3(NBUCK, 3), 256, 0, stream>>>(meta, Tbuf, csr);
    prep_v<<<24, 256, 0, stream>>>(W_rel_w, W_rel_c, W_node_p, attn_mac, vbuf);
    {
        const float* rel_el[3] = {el_w, el_p, el_p};
        const float* rel_er[3] = {er_w, er_wb, er_c};
        const bf16* rfeat[3]   = {Oa_b, Op_b, Op_b};
        bf16* rout[3]          = {A_ws, Oa_b, Cslot};
        const float* rdv[3]    = {vbuf, nullptr, vbuf + 2048};
        float* rdo[3]          = {dotW, nullptr, dotC};
        for (int r = 0; r < 3; ++r) {
            int* off  = csr + r * CSR_STRIDE;
            int* gsrc = off + CSR_GSRC;
            gat_gather<<<gB, 256, 0, stream>>>(off, gsrc, rel_el[r], rel_er[r],
                                               rfeat[r], rout[r],
                                               rdv[r], rdo[r], N_PAPER);
        }
    }
    // A_ws=r_writes, Oa_b=r_written_by, Cslot=r_cites; el/csr dead.

    // ---- 4: late BTs (into dead csr space), dotL, relation softmax ----
    prep_bt<<<256, 256, 0, stream>>>(W_rel_w,  BT2);
    prep_bt<<<256, 256, 0, stream>>>(W_rel_c,  BT3);
    prep_bt<<<256, 256, 0, stream>>>(W_res_p,  BT4);
    prep_bt<<<256, 256, 0, stream>>>(W_rel_wb, BT5);
    prep_bt<<<256, 256, 0, stream>>>(W_res_a,  BT6);
    macro_dotL<<<gB, 256, 0, stream>>>(feats_p, vbuf + 4096, dotL, N_PAPER);
    score_kernel<<<hdB, 256, 0, stream>>>(dotL, dotW, dotC, sc_w, sc_c, N_PAPER * NHEAD);

    // ---- 5: paper side, single fused kernel -> Op_f FINAL ----
    gemm_paper<<<gemB, 256, 0, stream>>>(A_ws, BT2, Cslot, BT3, feats_p, BT4,
                                         N_PAPER, sc_w, sc_c, rw_p, b_res_p, Op_f);
    // ---- 6: rf_written_by = r_written_by(Oa_b) @ W_rel_wb -> A_ws (free) ----
    gemm_c16<bf16><<<gemB, 256, 0, stream>>>(Oa_b, BT5, N_AUTHOR, A_ws);
    // ---- 7: author gated residual -> Oa_f FINAL ----
    gemm_resid<<<gemB, 256, 0, stream>>>(feats_a, BT6, N_AUTHOR, A_ws,
                                         rw_a, b_res_a, Oa_f);
}